// Round 1
// baseline (2288.899 us; speedup 1.0000x reference)
//
#include <hip/hip_runtime.h>

#define DEV static __device__ __forceinline__

typedef float f32x4 __attribute__((ext_vector_type(4)));
typedef __bf16 bf16x8 __attribute__((ext_vector_type(8)));
typedef unsigned int u32x4 __attribute__((ext_vector_type(4)));
typedef unsigned int u32x2 __attribute__((ext_vector_type(2)));

#define NNODE 32768
#define NEDGE 393216

DEV unsigned short f2bf(float f) {
    unsigned int u = __builtin_bit_cast(unsigned int, f);
    u += 0x7FFFu + ((u >> 16) & 1u);
    return (unsigned short)(u >> 16);
}
DEV float bf2f(unsigned int b) {
    unsigned int u = b << 16;
    return __builtin_bit_cast(float, u);
}
DEV unsigned int pk2(float a, float b) {
    return (unsigned int)f2bf(a) | ((unsigned int)f2bf(b) << 16);
}
DEV float sigf(float x) { return 1.f / (1.f + __expf(-x)); }

// ---------------- setup kernels ----------------

__global__ __launch_bounds__(256) void init_k(
    const float* __restrict__ feat, float* __restrict__ h,
    unsigned short* __restrict__ hb, unsigned short* __restrict__ fb,
    unsigned short* __restrict__ A2)
{
    int idx = blockIdx.x * 256 + threadIdx.x;   // (NNODE+8)*256
    int r = idx >> 8, c = idx & 255;
    float f = 0.f;
    if (r < NNODE && c < 128) f = feat[(size_t)r * 128 + c];
    unsigned short v = f2bf(f);
    hb[(size_t)r * 256 + c] = v;
    if (c < 128) fb[(size_t)r * 128 + c] = v;
    if (r < NNODE) {
        h[(size_t)r * 256 + c] = f;
        A2[(size_t)r * 512 + 256 + c] = v;
    }
}

__global__ __launch_bounds__(256) void prep_wmsg_k(
    const float* __restrict__ Wm, const float* __restrict__ bm,
    unsigned short* __restrict__ WT)
{
    int idx = blockIdx.x * 256 + threadIdx.x;   // 256*1056
    int o = idx / 1056, j = idx - o * 1056;
    float v = 0.f;
    if (j < 1024) { int t = j >> 8, d = j & 255; v = Wm[t * 65536 + d * 256 + o]; }
    else if (j < 1028) v = bm[(j - 1024) * 256 + o];
    WT[idx] = f2bf(v);
}

__global__ __launch_bounds__(256) void prep_gru_k(
    const float* __restrict__ Wi, const float* __restrict__ Wh,
    unsigned short* __restrict__ B2T)
{
    int idx = blockIdx.x * 256 + threadIdx.x;   // 1024*512
    int j = idx >> 9, k = idx & 511;
    float v = 0.f;
    if (k < 256) { if (j < 768) v = Wi[k * 768 + j]; }
    else {
        int kk = k - 256;
        if (j < 512) v = Wh[kk * 768 + j];
        else if (j >= 768) v = Wh[kk * 768 + (j - 256)];
    }
    B2T[idx] = f2bf(v);
}

__global__ __launch_bounds__(256) void prep_bias2_k(
    const float* __restrict__ bi, const float* __restrict__ bh,
    float* __restrict__ b2)
{
    int j = blockIdx.x * 256 + threadIdx.x;     // 1024
    b2[j] = (j < 512) ? bi[j] + bh[j] : (j < 768 ? bi[j] : bh[j - 256]);
}

__global__ __launch_bounds__(256) void prep_conv_k(
    const float* __restrict__ c1w, const float* __restrict__ c2w,
    const float* __restrict__ cc1w, const float* __restrict__ cc2w,
    unsigned short* __restrict__ BT1, unsigned short* __restrict__ BT2,
    unsigned short* __restrict__ BTc1h, unsigned short* __restrict__ BTc1f,
    unsigned short* __restrict__ BTc2)
{
    int idx = blockIdx.x * 256 + threadIdx.x;   // 851968 total
    if (idx < 196608) {                                     // BT1 [k][o][c] 3*256*256
        int k = idx / 65536, r = idx - k * 65536, o = r >> 8, c = r & 255;
        BT1[idx] = f2bf(c1w[o * 768 + c * 3 + k]);
    } else if (idx < 262144) {                              // BT2 [o][c] 256*256
        int r = idx - 196608, o = r >> 8, c = r & 255;
        BT2[r] = f2bf(c2w[o * 256 + c]);
    } else if (idx < 557056) {                              // BTc1h [k][o][c<256] 3*384*256
        int jx = idx - 262144, k = jx / 98304, r = jx - k * 98304, o = r >> 8, c = r & 255;
        BTc1h[jx] = f2bf(cc1w[o * 1152 + c * 3 + k]);
    } else if (idx < 704512) {                              // BTc1f [k][o][cf<128] 3*384*128
        int jx = idx - 557056, k = jx / 49152, r = jx - k * 49152, o = r >> 7, cf = r & 127;
        BTc1f[jx] = f2bf(cc1w[o * 1152 + (256 + cf) * 3 + k]);
    } else if (idx < 851968) {                              // BTc2 [o][c] 384*384
        int r = idx - 704512, o = r / 384, c = r - o * 384;
        BTc2[r] = f2bf(cc2w[o * 384 + c]);
    }
}

// ---------------- CSR build ----------------

__global__ __launch_bounds__(256) void count_k(
    const int* __restrict__ dst, const int* __restrict__ et,
    int* __restrict__ cnt_nt)
{
    int e = blockIdx.x * 256 + threadIdx.x;
    atomicAdd(&cnt_nt[dst[e] * 4 + et[e]], 1);
}

__global__ __launch_bounds__(1024) void scan_k(
    const int* __restrict__ cnt_nt, int* __restrict__ rp)
{
    __shared__ int buf[1024];
    int tid = threadIdx.x;
    int base = 0;
    for (int chunk = 0; chunk < 32; chunk++) {
        int n = chunk * 1024 + tid;
        int v = cnt_nt[n * 4] + cnt_nt[n * 4 + 1] + cnt_nt[n * 4 + 2] + cnt_nt[n * 4 + 3];
        buf[tid] = v;
        __syncthreads();
        for (int off = 1; off < 1024; off <<= 1) {
            int x = (tid >= off) ? buf[tid - off] : 0;
            __syncthreads();
            buf[tid] += x;
            __syncthreads();
        }
        rp[n] = base + buf[tid] - v;
        base += buf[1023];
        __syncthreads();
    }
    if (tid == 0) rp[NNODE] = base;
}

__global__ __launch_bounds__(256) void fill_k(
    const int* __restrict__ src, const int* __restrict__ dst,
    const int* __restrict__ et, const int* __restrict__ rp,
    int* __restrict__ pos, int* __restrict__ edat)
{
    int e = blockIdx.x * 256 + threadIdx.x;
    int d = dst[e];
    int p = atomicAdd(&pos[d], 1);
    edat[rp[d] + p] = src[e] | (et[e] << 20);
}

// ---------------- per-step kernels ----------------

// one wave per node: gather h[src] rows, accumulate per etype, write s[Nn,1056]
__global__ __launch_bounds__(256) void agg_k(
    const int* __restrict__ rp, const int* __restrict__ edat,
    const unsigned short* __restrict__ hb, unsigned short* __restrict__ s)
{
    int wave = threadIdx.x >> 6, lane = threadIdx.x & 63;
    int n = (blockIdx.x << 2) + wave;
    int e0 = rp[n], e1 = rp[n + 1];
    float a00=0,a01=0,a02=0,a03=0, a10=0,a11=0,a12=0,a13=0;
    float a20=0,a21=0,a22=0,a23=0, a30=0,a31=0,a32=0,a33=0;
    int c0=0,c1=0,c2=0,c3=0;
    int colb = lane << 2;
    const unsigned short* hbc = hb + colb;
    for (int e = e0; e < e1; e++) {
        int d = edat[e];
        int sn = d & 0xFFFFF, t = d >> 20;     // t is wave-uniform
        u32x2 v = *(const u32x2*)(hbc + (size_t)sn * 256);
        float f0 = bf2f(v.x & 0xFFFFu), f1 = bf2f(v.x >> 16);
        float f2 = bf2f(v.y & 0xFFFFu), f3 = bf2f(v.y >> 16);
        if (t == 0)      { a00+=f0; a01+=f1; a02+=f2; a03+=f3; c0++; }
        else if (t == 1) { a10+=f0; a11+=f1; a12+=f2; a13+=f3; c1++; }
        else if (t == 2) { a20+=f0; a21+=f1; a22+=f2; a23+=f3; c2++; }
        else             { a30+=f0; a31+=f1; a32+=f2; a33+=f3; c3++; }
    }
    unsigned short* srow = s + (size_t)n * 1056 + colb;
    u32x2 p;
    p.x = pk2(a00,a01); p.y = pk2(a02,a03); *(u32x2*)(srow      ) = p;
    p.x = pk2(a10,a11); p.y = pk2(a12,a13); *(u32x2*)(srow + 256) = p;
    p.x = pk2(a20,a21); p.y = pk2(a22,a23); *(u32x2*)(srow + 512) = p;
    p.x = pk2(a30,a31); p.y = pk2(a32,a33); *(u32x2*)(srow + 768) = p;
    unsigned short* sc = s + (size_t)n * 1056 + 1024;
    if (lane == 0) { sc[0]=f2bf((float)c0); sc[1]=f2bf((float)c1);
                     sc[2]=f2bf((float)c2); sc[3]=f2bf((float)c3); }
    if (lane >= 4 && lane < 32) sc[lane] = 0;   // zero K-padding cols 1028..1055
}

// generic bf16 GEMM, B pre-transposed [N,K]; 128x128 tile, BK=32, 4 waves
__global__ __launch_bounds__(256) void gemm_bt(
    const unsigned short* __restrict__ A, int lda,
    const unsigned short* __restrict__ Bt,
    float* __restrict__ Cf, int ldc, int accum,
    unsigned short* __restrict__ Cb, int ldcb,
    const float* __restrict__ bias,
    int M, int N, int K)
{
    __shared__ __align__(16) unsigned short As[128 * 32];
    __shared__ __align__(16) unsigned short Bs[128 * 32];
    const int tid = threadIdx.x;
    const int nb = N >> 7;
    const int bm = blockIdx.x / nb;
    const int bn = blockIdx.x - bm * nb;
    const int srow = tid >> 1;
    const int scol = (tid & 1) << 4;
    const unsigned short* Ag = A + (size_t)(bm * 128 + srow) * lda + scol;
    const unsigned short* Bg = Bt + (size_t)(bn * 128 + srow) * K + scol;
    unsigned short* Asw = &As[srow * 32 + scol];
    unsigned short* Bsw = &Bs[srow * 32 + scol];

    const int wave = tid >> 6, lane = tid & 63;
    const int qm = (wave & 1) << 6, qn = (wave >> 1) << 6;
    const int fm = lane & 15, fkv = lane >> 4;

    f32x4 acc[4][4] = {};

    for (int kb = 0; kb < K; kb += 32) {
        u32x4 a0 = *(const u32x4*)(Ag + kb);
        u32x4 a1 = *(const u32x4*)(Ag + kb + 8);
        u32x4 b0 = *(const u32x4*)(Bg + kb);
        u32x4 b1 = *(const u32x4*)(Bg + kb + 8);
        __syncthreads();
        *(u32x4*)(Asw) = a0; *(u32x4*)(Asw + 8) = a1;
        *(u32x4*)(Bsw) = b0; *(u32x4*)(Bsw + 8) = b1;
        __syncthreads();
        bf16x8 af[4], bfr[4];
        #pragma unroll
        for (int i = 0; i < 4; i++)
            af[i] = *(const bf16x8*)(&As[(qm + i * 16 + fm) * 32 + fkv * 8]);
        #pragma unroll
        for (int i = 0; i < 4; i++)
            bfr[i] = *(const bf16x8*)(&Bs[(qn + i * 16 + fm) * 32 + fkv * 8]);
        #pragma unroll
        for (int i = 0; i < 4; i++)
            #pragma unroll
            for (int j = 0; j < 4; j++)
                acc[i][j] = __builtin_amdgcn_mfma_f32_16x16x32_bf16(af[i], bfr[j], acc[i][j], 0, 0, 0);
    }

    const int r0 = bm * 128 + qm + (lane >> 4) * 4;
    const int c0 = bn * 128 + qn + fm;
    #pragma unroll
    for (int j = 0; j < 4; j++) {
        int col = c0 + j * 16;
        float bv = bias ? bias[col] : 0.f;
        #pragma unroll
        for (int i = 0; i < 4; i++) {
            int row = r0 + i * 16;
            #pragma unroll
            for (int r = 0; r < 4; r++) {
                float v = acc[i][j][r] + bv;
                if (Cf) {
                    size_t o = (size_t)(row + r) * ldc + col;
                    if (accum) v += Cf[o];
                    Cf[o] = v;
                }
                if (Cb) Cb[(size_t)(row + r) * ldcb + col] = f2bf(v);
            }
        }
    }
}

__global__ __launch_bounds__(256) void gate_k(
    const float* __restrict__ G, float* __restrict__ h,
    unsigned short* __restrict__ hb, unsigned short* __restrict__ A2)
{
    int idx = blockIdx.x * 256 + threadIdx.x;
    int n = idx >> 6, c4 = (idx & 63) << 2;
    const float* g = G + (size_t)n * 1024 + c4;
    float4 g0 = *(const float4*)(g);
    float4 g1 = *(const float4*)(g + 256);
    float4 g2 = *(const float4*)(g + 512);
    float4 g3 = *(const float4*)(g + 768);
    float* hp = h + (size_t)n * 256 + c4;
    float4 hv = *(const float4*)(hp);
    float z0 = sigf(g1.x), z1 = sigf(g1.y), z2 = sigf(g1.z), z3 = sigf(g1.w);
    float q0 = tanhf(g2.x + sigf(g0.x) * g3.x);
    float q1 = tanhf(g2.y + sigf(g0.y) * g3.y);
    float q2 = tanhf(g2.z + sigf(g0.z) * g3.z);
    float q3 = tanhf(g2.w + sigf(g0.w) * g3.w);
    float n0 = (1.f - z0) * q0 + z0 * hv.x;
    float n1 = (1.f - z1) * q1 + z1 * hv.y;
    float n2 = (1.f - z2) * q2 + z2 * hv.z;
    float n3 = (1.f - z3) * q3 + z3 * hv.w;
    float4 hn = {n0, n1, n2, n3};
    *(float4*)hp = hn;
    u32x2 pk; pk.x = pk2(n0, n1); pk.y = pk2(n2, n3);
    *(u32x2*)(hb + (size_t)n * 256 + c4) = pk;
    *(u32x2*)(A2 + (size_t)n * 512 + 256 + c4) = pk;
}

// relu + maxpool over l (window win, stride 2)
__global__ __launch_bounds__(256) void pool_k(
    const float* __restrict__ in, int ldin, int Lb_in, int L_out, int win, int C,
    unsigned short* __restrict__ ob, float* __restrict__ of, int ldo)
{
    int idx = blockIdx.x * 256 + threadIdx.x;
    int c = idx % C;
    int row = idx / C;
    int b = row / L_out, lp = row - b * L_out;
    const float* p = in + (size_t)(b * Lb_in + 2 * lp) * ldin + c;
    float m = p[0];
    for (int d = 1; d < win; d++) m = fmaxf(m, p[(size_t)d * ldin]);
    m = fmaxf(m, 0.f);
    if (ob) ob[(size_t)row * ldo + c] = f2bf(m);
    else    of[(size_t)row * ldo + c] = m;
}

__global__ __launch_bounds__(64) void final_k(
    const float* __restrict__ Y2, const float* __restrict__ Z2,
    const float* __restrict__ wy, const float* __restrict__ by,
    const float* __restrict__ wz, const float* __restrict__ bz,
    float* __restrict__ out)
{
    int b = blockIdx.x, lane = threadIdx.x;
    float val = 0.f;
    if (lane < 63) {
        const float* yr = Y2 + (size_t)(b * 63 + lane) * 256;
        float y = 0.f;
        for (int o = 0; o < 256; o += 4) {
            float4 a = *(const float4*)(yr + o);
            float4 wv = *(const float4*)(wy + o);
            y += a.x * wv.x + a.y * wv.y + a.z * wv.z + a.w * wv.w;
        }
        y += by[0];
        const float* zr = Z2 + (size_t)(b * 63 + lane) * 384;
        float z = 0.f;
        for (int o = 0; o < 384; o += 4) {
            float4 a = *(const float4*)(zr + o);
            float4 wv = *(const float4*)(wz + o);
            z += a.x * wv.x + a.y * wv.y + a.z * wv.z + a.w * wv.w;
        }
        z += bz[0];
        val = y * z;
    }
    for (int off = 32; off > 0; off >>= 1) val += __shfl_down(val, off, 64);
    if (lane == 0) out[b] = sigf(val * (1.f / 63.f));
}

// ---------------- launch ----------------

extern "C" void kernel_launch(void* const* d_in, const int* in_sizes, int n_in,
                              void* d_out, int out_size, void* d_ws, size_t ws_size,
                              hipStream_t stream)
{
    const float* feat = (const float*)d_in[0];
    const int* src = (const int*)d_in[1];
    const int* dst = (const int*)d_in[2];
    const int* et  = (const int*)d_in[3];
    const float* Wm  = (const float*)d_in[4];
    const float* bm  = (const float*)d_in[5];
    const float* Wi  = (const float*)d_in[6];
    const float* Wh  = (const float*)d_in[7];
    const float* bi  = (const float*)d_in[8];
    const float* bh  = (const float*)d_in[9];
    const float* c1w = (const float*)d_in[10];
    const float* c1b = (const float*)d_in[11];
    const float* c2w = (const float*)d_in[12];
    const float* c2b = (const float*)d_in[13];
    const float* cc1w = (const float*)d_in[14];
    const float* cc1b = (const float*)d_in[15];
    const float* cc2w = (const float*)d_in[16];
    const float* cc2b = (const float*)d_in[17];
    const float* wy = (const float*)d_in[18];
    const float* by = (const float*)d_in[19];
    const float* wz = (const float*)d_in[20];
    const float* bz = (const float*)d_in[21];
    float* out = (float*)d_out;

    char* w = (char*)d_ws;
    size_t off = 0;
    auto alloc = [&](size_t bytes) -> char* {
        char* p = w + off; off += (bytes + 255) & ~(size_t)255; return p;
    };
    float* h           = (float*)alloc((size_t)NNODE * 256 * 4);
    unsigned short* hb = (unsigned short*)alloc((size_t)(NNODE + 8) * 256 * 2);
    unsigned short* fb = (unsigned short*)alloc((size_t)(NNODE + 8) * 128 * 2);
    unsigned short* A2 = (unsigned short*)alloc((size_t)NNODE * 512 * 2);
    char* R = alloc((size_t)NNODE * 1024 * 4);          // s / G / readout overlay
    unsigned short* s = (unsigned short*)R;             // [Nn,1056] bf16
    float* G    = (float*)R;                            // [Nn,1024] f32
    float* Cbuf = (float*)R;                            // [Nn,384] f32 (readout)
    unsigned short* P = (unsigned short*)(R + 50331648);// [16128,384] bf16
    float* Y2 = (float*)(R + 62717952);                 // [8064,256] f32
    float* Z2 = (float*)(R + 70975488);                 // [8064,384] f32
    unsigned short* WT    = (unsigned short*)alloc(256 * 1056 * 2);
    unsigned short* B2T   = (unsigned short*)alloc(1024 * 512 * 2);
    float* b2             = (float*)alloc(1024 * 4);
    unsigned short* BT1   = (unsigned short*)alloc(3 * 65536 * 2);
    unsigned short* BT2   = (unsigned short*)alloc(65536 * 2);
    unsigned short* BTc1h = (unsigned short*)alloc(3 * 98304 * 2);
    unsigned short* BTc1f = (unsigned short*)alloc(3 * 49152 * 2);
    unsigned short* BTc2  = (unsigned short*)alloc(147456 * 2);
    int* rp     = (int*)alloc((NNODE + 1) * 4);
    int* pos    = (int*)alloc(NNODE * 4);
    int* cnt_nt = (int*)alloc(NNODE * 16);
    int* edat   = (int*)alloc(NEDGE * 4);

    // setup
    hipLaunchKernelGGL(init_k, dim3(NNODE / 256 * 256 / 256 * 256 == 0 ? 1 : (NNODE + 8)), dim3(256), 0, stream, feat, h, hb, fb, A2);
    hipLaunchKernelGGL(prep_wmsg_k, dim3(1056), dim3(256), 0, stream, Wm, bm, WT);
    hipLaunchKernelGGL(prep_gru_k, dim3(2048), dim3(256), 0, stream, Wi, Wh, B2T);
    hipLaunchKernelGGL(prep_bias2_k, dim3(4), dim3(256), 0, stream, bi, bh, b2);
    hipLaunchKernelGGL(prep_conv_k, dim3(3328), dim3(256), 0, stream,
                       c1w, c2w, cc1w, cc2w, BT1, BT2, BTc1h, BTc1f, BTc2);
    hipMemsetAsync(pos, 0, NNODE * 4, stream);
    hipMemsetAsync(cnt_nt, 0, NNODE * 16, stream);
    hipLaunchKernelGGL(count_k, dim3(NEDGE / 256), dim3(256), 0, stream, dst, et, cnt_nt);
    hipLaunchKernelGGL(scan_k, dim3(1), dim3(1024), 0, stream, cnt_nt, rp);
    hipLaunchKernelGGL(fill_k, dim3(NEDGE / 256), dim3(256), 0, stream, src, dst, et, rp, pos, edat);

    // 8 GGNN steps
    for (int step = 0; step < 8; step++) {
        hipLaunchKernelGGL(agg_k, dim3(NNODE / 4), dim3(256), 0, stream, rp, edat, hb, s);
        hipLaunchKernelGGL(gemm_bt, dim3(512), dim3(256), 0, stream,
            s, 1056, WT, (float*)nullptr, 0, 0, A2, 512, (const float*)nullptr,
            NNODE, 256, 1056);
        hipLaunchKernelGGL(gemm_bt, dim3(2048), dim3(256), 0, stream,
            A2, 512, B2T, G, 1024, 0, (unsigned short*)nullptr, 0, b2,
            NNODE, 1024, 512);
        hipLaunchKernelGGL(gate_k, dim3(NNODE / 4), dim3(256), 0, stream, G, h, hb, A2);
    }

    // readout: Y path (conv1 k=3 as 3 accumulated shifted GEMMs)
    for (int k = 0; k < 3; k++)
        hipLaunchKernelGGL(gemm_bt, dim3(512), dim3(256), 0, stream,
            hb + k * 256, 256, BT1 + k * 65536, Cbuf, 256, (k > 0),
            (unsigned short*)nullptr, 0, (k == 0) ? c1b : (const float*)nullptr,
            NNODE, 256, 256);
    hipLaunchKernelGGL(pool_k, dim3(16128), dim3(256), 0, stream,
        Cbuf, 256, 256, 126, 3, 256, P, (float*)nullptr, 256);
    hipLaunchKernelGGL(gemm_bt, dim3(252), dim3(256), 0, stream,
        P, 256, BT2, Cbuf, 256, 0, (unsigned short*)nullptr, 0, c2b, 16128, 256, 256);
    hipLaunchKernelGGL(pool_k, dim3(8064), dim3(256), 0, stream,
        Cbuf, 256, 126, 63, 2, 256, (unsigned short*)nullptr, Y2, 256);

    // Z path (concat conv: 3 h-part GEMMs K=256 + 3 feature-part GEMMs K=128)
    for (int k = 0; k < 3; k++)
        hipLaunchKernelGGL(gemm_bt, dim3(768), dim3(256), 0, stream,
            hb + k * 256, 256, BTc1h + k * 98304, Cbuf, 384, (k > 0),
            (unsigned short*)nullptr, 0, (k == 0) ? cc1b : (const float*)nullptr,
            NNODE, 384, 256);
    for (int k = 0; k < 3; k++)
        hipLaunchKernelGGL(gemm_bt, dim3(768), dim3(256), 0, stream,
            fb + k * 128, 128, BTc1f + k * 49152, Cbuf, 384, 1,
            (unsigned short*)nullptr, 0, (const float*)nullptr,
            NNODE, 384, 128);
    hipLaunchKernelGGL(pool_k, dim3(24192), dim3(256), 0, stream,
        Cbuf, 384, 256, 126, 3, 384, P, (float*)nullptr, 384);
    hipLaunchKernelGGL(gemm_bt, dim3(378), dim3(256), 0, stream,
        P, 384, BTc2, Cbuf, 384, 0, (unsigned short*)nullptr, 0, cc2b, 16128, 384, 384);
    hipLaunchKernelGGL(pool_k, dim3(12096), dim3(256), 0, stream,
        Cbuf, 384, 126, 63, 2, 384, (unsigned short*)nullptr, Z2, 384);

    hipLaunchKernelGGL(final_k, dim3(128), dim3(64), 0, stream, Y2, Z2, wy, by, wz, bz, out);
}

// Round 2
// 1928.223 us; speedup vs baseline: 1.1871x; 1.1871x over previous
//
#include <hip/hip_runtime.h>

#define DEV static __device__ __forceinline__

typedef float f32x4 __attribute__((ext_vector_type(4)));
typedef __bf16 bf16x8 __attribute__((ext_vector_type(8)));
typedef unsigned int u32x4 __attribute__((ext_vector_type(4)));
typedef unsigned int u32x2 __attribute__((ext_vector_type(2)));

#define NNODE 32768
#define NEDGE 393216

DEV unsigned short f2bf(float f) {
    unsigned int u = __builtin_bit_cast(unsigned int, f);
    u += 0x7FFFu + ((u >> 16) & 1u);
    return (unsigned short)(u >> 16);
}
DEV float bf2f(unsigned int b) {
    unsigned int u = b << 16;
    return __builtin_bit_cast(float, u);
}
DEV unsigned int pk2(float a, float b) {
    return (unsigned int)f2bf(a) | ((unsigned int)f2bf(b) << 16);
}
DEV float sigf(float x) { return 1.f / (1.f + __expf(-x)); }

// ---------------- setup kernels ----------------

__global__ __launch_bounds__(256) void init_k(
    const float* __restrict__ feat, float* __restrict__ h,
    unsigned short* __restrict__ hb, unsigned short* __restrict__ fb,
    unsigned short* __restrict__ A2)
{
    int idx = blockIdx.x * 256 + threadIdx.x;   // (NNODE+8)*256
    int r = idx >> 8, c = idx & 255;
    float f = 0.f;
    if (r < NNODE && c < 128) f = feat[(size_t)r * 128 + c];
    unsigned short v = f2bf(f);
    hb[(size_t)r * 256 + c] = v;
    if (c < 128) fb[(size_t)r * 128 + c] = v;
    if (r < NNODE) {
        h[(size_t)r * 256 + c] = f;
        A2[(size_t)r * 512 + 256 + c] = v;
    }
}

__global__ __launch_bounds__(256) void prep_wmsg_k(
    const float* __restrict__ Wm, const float* __restrict__ bm,
    unsigned short* __restrict__ WT)
{
    int idx = blockIdx.x * 256 + threadIdx.x;   // 256*1056
    int o = idx / 1056, j = idx - o * 1056;
    float v = 0.f;
    if (j < 1024) { int t = j >> 8, d = j & 255; v = Wm[t * 65536 + d * 256 + o]; }
    else if (j < 1028) v = bm[(j - 1024) * 256 + o];
    WT[idx] = f2bf(v);
}

// GRU weights in gate-interleaved layout: col' = band*64 + g*16 + ch_low,
// where ch = band*16 + ch_low, g in {0:r, 1:z, 2:ig, 3:hg}.
// K layout: k<256 -> a (Wi), k>=256 -> h (Wh).
__global__ __launch_bounds__(256) void prep_gru_k(
    const float* __restrict__ Wi, const float* __restrict__ Wh,
    unsigned short* __restrict__ B2T)
{
    int idx = blockIdx.x * 256 + threadIdx.x;   // 1024*512
    int j = idx >> 9, k = idx & 511;
    int band = j >> 6, g = (j >> 4) & 3, ch = (band << 4) + (j & 15);
    float v = 0.f;
    if (g == 0) v = (k < 256) ? Wi[k * 768 + ch] : Wh[(k - 256) * 768 + ch];
    else if (g == 1) v = (k < 256) ? Wi[k * 768 + 256 + ch] : Wh[(k - 256) * 768 + 256 + ch];
    else if (g == 2) { if (k < 256) v = Wi[k * 768 + 512 + ch]; }
    else { if (k >= 256) v = Wh[(k - 256) * 768 + 512 + ch]; }
    B2T[idx] = f2bf(v);
}

__global__ __launch_bounds__(256) void prep_bias2_k(
    const float* __restrict__ bi, const float* __restrict__ bh,
    float* __restrict__ b2)
{
    int j = blockIdx.x * 256 + threadIdx.x;     // 1024
    int band = j >> 6, g = (j >> 4) & 3, ch = (band << 4) + (j & 15);
    float v;
    if (g == 0) v = bi[ch] + bh[ch];
    else if (g == 1) v = bi[256 + ch] + bh[256 + ch];
    else if (g == 2) v = bi[512 + ch];
    else v = bh[512 + ch];
    b2[j] = v;
}

__global__ __launch_bounds__(256) void prep_conv_k(
    const float* __restrict__ c1w, const float* __restrict__ c2w,
    const float* __restrict__ cc1w, const float* __restrict__ cc2w,
    unsigned short* __restrict__ BT1, unsigned short* __restrict__ BT2,
    unsigned short* __restrict__ BTc1h, unsigned short* __restrict__ BTc1f,
    unsigned short* __restrict__ BTc2)
{
    int idx = blockIdx.x * 256 + threadIdx.x;   // 851968 total
    if (idx < 196608) {                                     // BT1 [k][o][c] 3*256*256
        int k = idx / 65536, r = idx - k * 65536, o = r >> 8, c = r & 255;
        BT1[idx] = f2bf(c1w[o * 768 + c * 3 + k]);
    } else if (idx < 262144) {                              // BT2 [o][c] 256*256
        int r = idx - 196608, o = r >> 8, c = r & 255;
        BT2[r] = f2bf(c2w[o * 256 + c]);
    } else if (idx < 557056) {                              // BTc1h [k][o][c<256] 3*384*256
        int jx = idx - 262144, k = jx / 98304, r = jx - k * 98304, o = r >> 8, c = r & 255;
        BTc1h[jx] = f2bf(cc1w[o * 1152 + c * 3 + k]);
    } else if (idx < 704512) {                              // BTc1f [k][o][cf<128] 3*384*128
        int jx = idx - 557056, k = jx / 49152, r = jx - k * 49152, o = r >> 7, cf = r & 127;
        BTc1f[jx] = f2bf(cc1w[o * 1152 + (256 + cf) * 3 + k]);
    } else if (idx < 851968) {                              // BTc2 [o][c] 384*384
        int r = idx - 704512, o = r / 384, c = r - o * 384;
        BTc2[r] = f2bf(cc2w[o * 384 + c]);
    }
}

// ---------------- CSR build ----------------

__global__ __launch_bounds__(256) void count_k(
    const int* __restrict__ dst, const int* __restrict__ et,
    int* __restrict__ cnt_nt)
{
    int e = blockIdx.x * 256 + threadIdx.x;
    atomicAdd(&cnt_nt[dst[e] * 4 + et[e]], 1);
}

__global__ __launch_bounds__(1024) void scan_k(
    const int* __restrict__ cnt_nt, int* __restrict__ rp)
{
    __shared__ int buf[1024];
    int tid = threadIdx.x;
    int base = 0;
    for (int chunk = 0; chunk < 32; chunk++) {
        int n = chunk * 1024 + tid;
        int v = cnt_nt[n * 4] + cnt_nt[n * 4 + 1] + cnt_nt[n * 4 + 2] + cnt_nt[n * 4 + 3];
        buf[tid] = v;
        __syncthreads();
        for (int off = 1; off < 1024; off <<= 1) {
            int x = (tid >= off) ? buf[tid - off] : 0;
            __syncthreads();
            buf[tid] += x;
            __syncthreads();
        }
        rp[n] = base + buf[tid] - v;
        base += buf[1023];
        __syncthreads();
    }
    if (tid == 0) rp[NNODE] = base;
}

__global__ __launch_bounds__(256) void fill_k(
    const int* __restrict__ src, const int* __restrict__ dst,
    const int* __restrict__ et, const int* __restrict__ rp,
    int* __restrict__ pos, int* __restrict__ edat)
{
    int e = blockIdx.x * 256 + threadIdx.x;
    int d = dst[e];
    int p = atomicAdd(&pos[d], 1);
    edat[rp[d] + p] = src[e] | (et[e] << 20);
}

// ---------------- per-step kernels ----------------

// one wave per node: gather h[src] rows, accumulate per etype, write s[Nn,1056]
__global__ __launch_bounds__(256) void agg_k(
    const int* __restrict__ rp, const int* __restrict__ edat,
    const unsigned short* __restrict__ hb, unsigned short* __restrict__ s)
{
    int wave = threadIdx.x >> 6, lane = threadIdx.x & 63;
    int n = (blockIdx.x << 2) + wave;
    int e0 = rp[n], e1 = rp[n + 1];
    float a00=0,a01=0,a02=0,a03=0, a10=0,a11=0,a12=0,a13=0;
    float a20=0,a21=0,a22=0,a23=0, a30=0,a31=0,a32=0,a33=0;
    int c0=0,c1=0,c2=0,c3=0;
    int colb = lane << 2;
    const unsigned short* hbc = hb + colb;
    for (int e = e0; e < e1; e++) {
        int d = edat[e];
        int sn = d & 0xFFFFF, t = d >> 20;     // t is wave-uniform
        u32x2 v = *(const u32x2*)(hbc + (size_t)sn * 256);
        float f0 = bf2f(v.x & 0xFFFFu), f1 = bf2f(v.x >> 16);
        float f2 = bf2f(v.y & 0xFFFFu), f3 = bf2f(v.y >> 16);
        if (t == 0)      { a00+=f0; a01+=f1; a02+=f2; a03+=f3; c0++; }
        else if (t == 1) { a10+=f0; a11+=f1; a12+=f2; a13+=f3; c1++; }
        else if (t == 2) { a20+=f0; a21+=f1; a22+=f2; a23+=f3; c2++; }
        else             { a30+=f0; a31+=f1; a32+=f2; a33+=f3; c3++; }
    }
    unsigned short* srow = s + (size_t)n * 1056 + colb;
    u32x2 p;
    p.x = pk2(a00,a01); p.y = pk2(a02,a03); *(u32x2*)(srow      ) = p;
    p.x = pk2(a10,a11); p.y = pk2(a12,a13); *(u32x2*)(srow + 256) = p;
    p.x = pk2(a20,a21); p.y = pk2(a22,a23); *(u32x2*)(srow + 512) = p;
    p.x = pk2(a30,a31); p.y = pk2(a32,a33); *(u32x2*)(srow + 768) = p;
    unsigned short* sc = s + (size_t)n * 1056 + 1024;
    if (lane == 0) { sc[0]=f2bf((float)c0); sc[1]=f2bf((float)c1);
                     sc[2]=f2bf((float)c2); sc[3]=f2bf((float)c3); }
    if (lane >= 4 && lane < 32) sc[lane] = 0;   // zero K-padding cols 1028..1055
}

// generic bf16 GEMM, B pre-transposed [N,K]; 128x128 tile, BK=32, 4 waves
// swz: XCD-aware block swizzle (requires grid % 8 == 0)
__global__ __launch_bounds__(256) void gemm_bt(
    const unsigned short* __restrict__ A, int lda,
    const unsigned short* __restrict__ Bt,
    float* __restrict__ Cf, int ldc, int accum,
    unsigned short* __restrict__ Cb, int ldcb,
    const float* __restrict__ bias,
    int M, int N, int K, int swz)
{
    __shared__ __align__(16) unsigned short As[128 * 32];
    __shared__ __align__(16) unsigned short Bs[128 * 32];
    const int tid = threadIdx.x;
    int id = blockIdx.x;
    if (swz) { int per = gridDim.x >> 3; id = (id & 7) * per + (id >> 3); }
    const int nb = N >> 7;
    const int bm = id / nb;
    const int bn = id - bm * nb;
    const int srow = tid >> 1;
    const int scol = (tid & 1) << 4;
    const unsigned short* Ag = A + (size_t)(bm * 128 + srow) * lda + scol;
    const unsigned short* Bg = Bt + (size_t)(bn * 128 + srow) * K + scol;
    unsigned short* Asw = &As[srow * 32 + scol];
    unsigned short* Bsw = &Bs[srow * 32 + scol];

    const int wave = tid >> 6, lane = tid & 63;
    const int qm = (wave & 1) << 6, qn = (wave >> 1) << 6;
    const int fm = lane & 15, fkv = lane >> 4;

    f32x4 acc[4][4] = {};

    for (int kb = 0; kb < K; kb += 32) {
        u32x4 a0 = *(const u32x4*)(Ag + kb);
        u32x4 a1 = *(const u32x4*)(Ag + kb + 8);
        u32x4 b0 = *(const u32x4*)(Bg + kb);
        u32x4 b1 = *(const u32x4*)(Bg + kb + 8);
        __syncthreads();
        *(u32x4*)(Asw) = a0; *(u32x4*)(Asw + 8) = a1;
        *(u32x4*)(Bsw) = b0; *(u32x4*)(Bsw + 8) = b1;
        __syncthreads();
        bf16x8 af[4], bfr[4];
        #pragma unroll
        for (int i = 0; i < 4; i++)
            af[i] = *(const bf16x8*)(&As[(qm + i * 16 + fm) * 32 + fkv * 8]);
        #pragma unroll
        for (int i = 0; i < 4; i++)
            bfr[i] = *(const bf16x8*)(&Bs[(qn + i * 16 + fm) * 32 + fkv * 8]);
        #pragma unroll
        for (int i = 0; i < 4; i++)
            #pragma unroll
            for (int j = 0; j < 4; j++)
                acc[i][j] = __builtin_amdgcn_mfma_f32_16x16x32_bf16(af[i], bfr[j], acc[i][j], 0, 0, 0);
    }

    const int r0 = bm * 128 + qm + (lane >> 4) * 4;
    const int c0 = bn * 128 + qn + fm;
    #pragma unroll
    for (int j = 0; j < 4; j++) {
        int col = c0 + j * 16;
        float bv = bias ? bias[col] : 0.f;
        #pragma unroll
        for (int i = 0; i < 4; i++) {
            int row = r0 + i * 16;
            #pragma unroll
            for (int r = 0; r < 4; r++) {
                float v = acc[i][j][r] + bv;
                if (Cf) {
                    size_t o = (size_t)(row + r) * ldc + col;
                    if (accum) v += Cf[o];
                    Cf[o] = v;
                }
                if (Cb) Cb[(size_t)(row + r) * ldcb + col] = f2bf(v);
            }
        }
    }
}

// GRU GEMM with fused gate epilogue. A=[Nn,512] bf16 (a|h), Bt=[1024,512]
// gate-interleaved. Each lane's 4 j-fragments are the 4 gates of one channel.
__global__ __launch_bounds__(256) void gemm_gru(
    const unsigned short* __restrict__ A,
    const unsigned short* __restrict__ Bt,
    const float* __restrict__ b2p,
    float* __restrict__ h,
    unsigned short* __restrict__ hb,
    unsigned short* __restrict__ A2n)
{
    __shared__ __align__(16) unsigned short As[128 * 32];
    __shared__ __align__(16) unsigned short Bs[128 * 32];
    const int tid = threadIdx.x;
    int id = blockIdx.x;                        // 2048
    { int per = gridDim.x >> 3; id = (id & 7) * per + (id >> 3); }
    const int bm = id >> 3;
    const int bn = id & 7;
    const int srow = tid >> 1;
    const int scol = (tid & 1) << 4;
    const unsigned short* Ag = A + (size_t)(bm * 128 + srow) * 512 + scol;
    const unsigned short* Bg = Bt + (size_t)(bn * 128 + srow) * 512 + scol;
    unsigned short* Asw = &As[srow * 32 + scol];
    unsigned short* Bsw = &Bs[srow * 32 + scol];

    const int wave = tid >> 6, lane = tid & 63;
    const int qm = (wave & 1) << 6, qn = (wave >> 1) << 6;
    const int fm = lane & 15, fkv = lane >> 4;

    f32x4 acc[4][4] = {};

    for (int kb = 0; kb < 512; kb += 32) {
        u32x4 a0 = *(const u32x4*)(Ag + kb);
        u32x4 a1 = *(const u32x4*)(Ag + kb + 8);
        u32x4 b0 = *(const u32x4*)(Bg + kb);
        u32x4 b1 = *(const u32x4*)(Bg + kb + 8);
        __syncthreads();
        *(u32x4*)(Asw) = a0; *(u32x4*)(Asw + 8) = a1;
        *(u32x4*)(Bsw) = b0; *(u32x4*)(Bsw + 8) = b1;
        __syncthreads();
        bf16x8 af[4], bfr[4];
        #pragma unroll
        for (int i = 0; i < 4; i++)
            af[i] = *(const bf16x8*)(&As[(qm + i * 16 + fm) * 32 + fkv * 8]);
        #pragma unroll
        for (int i = 0; i < 4; i++)
            bfr[i] = *(const bf16x8*)(&Bs[(qn + i * 16 + fm) * 32 + fkv * 8]);
        #pragma unroll
        for (int i = 0; i < 4; i++)
            #pragma unroll
            for (int j = 0; j < 4; j++)
                acc[i][j] = __builtin_amdgcn_mfma_f32_16x16x32_bf16(af[i], bfr[j], acc[i][j], 0, 0, 0);
    }

    // fused GRU gate epilogue
    const int band = (bn << 1) + (qn >> 6);
    const int ch = (band << 4) + fm;
    const float b0 = b2p[(band << 6) + fm];
    const float b1 = b2p[(band << 6) + 16 + fm];
    const float b2v = b2p[(band << 6) + 32 + fm];
    const float b3v = b2p[(band << 6) + 48 + fm];
    const int r0 = bm * 128 + qm + fkv * 4;
    #pragma unroll
    for (int i = 0; i < 4; i++) {
        #pragma unroll
        for (int r = 0; r < 4; r++) {
            int row = r0 + i * 16 + r;
            float hp = h[(size_t)row * 256 + ch];
            float rg = sigf(acc[i][0][r] + b0);
            float zz = sigf(acc[i][1][r] + b1);
            float pre = acc[i][2][r] + b2v + rg * (acc[i][3][r] + b3v);
            pre = fminf(fmaxf(pre, -15.f), 15.f);
            float t = __expf(2.f * pre);
            float gq = (t - 1.f) / (t + 1.f);
            float hn = (1.f - zz) * gq + zz * hp;
            h[(size_t)row * 256 + ch] = hn;
            unsigned short hv = f2bf(hn);
            hb[(size_t)row * 256 + ch] = hv;
            A2n[(size_t)row * 512 + 256 + ch] = hv;
        }
    }
}

// relu + maxpool over l (window win, stride 2)
__global__ __launch_bounds__(256) void pool_k(
    const float* __restrict__ in, int ldin, int Lb_in, int L_out, int win, int C,
    unsigned short* __restrict__ ob, float* __restrict__ of, int ldo)
{
    int idx = blockIdx.x * 256 + threadIdx.x;
    int c = idx % C;
    int row = idx / C;
    int b = row / L_out, lp = row - b * L_out;
    const float* p = in + (size_t)(b * Lb_in + 2 * lp) * ldin + c;
    float m = p[0];
    for (int d = 1; d < win; d++) m = fmaxf(m, p[(size_t)d * ldin]);
    m = fmaxf(m, 0.f);
    if (ob) ob[(size_t)row * ldo + c] = f2bf(m);
    else    of[(size_t)row * ldo + c] = m;
}

__global__ __launch_bounds__(64) void final_k(
    const float* __restrict__ Y2, const float* __restrict__ Z2,
    const float* __restrict__ wy, const float* __restrict__ by,
    const float* __restrict__ wz, const float* __restrict__ bz,
    float* __restrict__ out)
{
    int b = blockIdx.x, lane = threadIdx.x;
    float val = 0.f;
    if (lane < 63) {
        const float* yr = Y2 + (size_t)(b * 63 + lane) * 256;
        float y = 0.f;
        for (int o = 0; o < 256; o += 4) {
            float4 a = *(const float4*)(yr + o);
            float4 wv = *(const float4*)(wy + o);
            y += a.x * wv.x + a.y * wv.y + a.z * wv.z + a.w * wv.w;
        }
        y += by[0];
        const float* zr = Z2 + (size_t)(b * 63 + lane) * 384;
        float z = 0.f;
        for (int o = 0; o < 384; o += 4) {
            float4 a = *(const float4*)(zr + o);
            float4 wv = *(const float4*)(wz + o);
            z += a.x * wv.x + a.y * wv.y + a.z * wv.z + a.w * wv.w;
        }
        z += bz[0];
        val = y * z;
    }
    for (int off = 32; off > 0; off >>= 1) val += __shfl_down(val, off, 64);
    if (lane == 0) out[b] = sigf(val * (1.f / 63.f));
}

// ---------------- launch ----------------

extern "C" void kernel_launch(void* const* d_in, const int* in_sizes, int n_in,
                              void* d_out, int out_size, void* d_ws, size_t ws_size,
                              hipStream_t stream)
{
    const float* feat = (const float*)d_in[0];
    const int* src = (const int*)d_in[1];
    const int* dst = (const int*)d_in[2];
    const int* et  = (const int*)d_in[3];
    const float* Wm  = (const float*)d_in[4];
    const float* bm  = (const float*)d_in[5];
    const float* Wi  = (const float*)d_in[6];
    const float* Wh  = (const float*)d_in[7];
    const float* bi  = (const float*)d_in[8];
    const float* bh  = (const float*)d_in[9];
    const float* c1w = (const float*)d_in[10];
    const float* c1b = (const float*)d_in[11];
    const float* c2w = (const float*)d_in[12];
    const float* c2b = (const float*)d_in[13];
    const float* cc1w = (const float*)d_in[14];
    const float* cc1b = (const float*)d_in[15];
    const float* cc2w = (const float*)d_in[16];
    const float* cc2b = (const float*)d_in[17];
    const float* wy = (const float*)d_in[18];
    const float* by = (const float*)d_in[19];
    const float* wz = (const float*)d_in[20];
    const float* bz = (const float*)d_in[21];
    float* out = (float*)d_out;

    char* w = (char*)d_ws;
    size_t off = 0;
    auto alloc = [&](size_t bytes) -> char* {
        char* p = w + off; off += (bytes + 255) & ~(size_t)255; return p;
    };
    float* h           = (float*)alloc((size_t)NNODE * 256 * 4);
    unsigned short* hb = (unsigned short*)alloc((size_t)(NNODE + 8) * 256 * 2);
    unsigned short* fb = (unsigned short*)alloc((size_t)(NNODE + 8) * 128 * 2);
    unsigned short* A2a = (unsigned short*)alloc((size_t)NNODE * 512 * 2);
    unsigned short* A2b = (unsigned short*)alloc((size_t)NNODE * 512 * 2);
    char* R = alloc((size_t)NNODE * 1056 * 2);          // s / Cbuf overlay (69.2MB)
    unsigned short* s = (unsigned short*)R;             // [Nn,1056] bf16
    float* Cbuf = (float*)R;                            // [Nn,384] f32 (readout)
    unsigned short* P = (unsigned short*)alloc((size_t)24192 * 384 * 2);
    float* Y2 = (float*)alloc((size_t)8064 * 256 * 4);
    float* Z2 = (float*)alloc((size_t)8064 * 384 * 4);
    unsigned short* WT    = (unsigned short*)alloc(256 * 1056 * 2);
    unsigned short* B2T   = (unsigned short*)alloc(1024 * 512 * 2);
    float* b2             = (float*)alloc(1024 * 4);
    unsigned short* BT1   = (unsigned short*)alloc(3 * 65536 * 2);
    unsigned short* BT2   = (unsigned short*)alloc(65536 * 2);
    unsigned short* BTc1h = (unsigned short*)alloc(3 * 98304 * 2);
    unsigned short* BTc1f = (unsigned short*)alloc(3 * 49152 * 2);
    unsigned short* BTc2  = (unsigned short*)alloc(147456 * 2);
    int* rp     = (int*)alloc((NNODE + 1) * 4);
    int* pos    = (int*)alloc(NNODE * 4);
    int* cnt_nt = (int*)alloc(NNODE * 16);
    int* edat   = (int*)alloc(NEDGE * 4);

    // setup
    hipLaunchKernelGGL(init_k, dim3(NNODE + 8), dim3(256), 0, stream, feat, h, hb, fb, A2a);
    hipLaunchKernelGGL(prep_wmsg_k, dim3(1056), dim3(256), 0, stream, Wm, bm, WT);
    hipLaunchKernelGGL(prep_gru_k, dim3(2048), dim3(256), 0, stream, Wi, Wh, B2T);
    hipLaunchKernelGGL(prep_bias2_k, dim3(4), dim3(256), 0, stream, bi, bh, b2);
    hipLaunchKernelGGL(prep_conv_k, dim3(3328), dim3(256), 0, stream,
                       c1w, c2w, cc1w, cc2w, BT1, BT2, BTc1h, BTc1f, BTc2);
    hipMemsetAsync(pos, 0, NNODE * 4, stream);
    hipMemsetAsync(cnt_nt, 0, NNODE * 16, stream);
    hipLaunchKernelGGL(count_k, dim3(NEDGE / 256), dim3(256), 0, stream, dst, et, cnt_nt);
    hipLaunchKernelGGL(scan_k, dim3(1), dim3(1024), 0, stream, cnt_nt, rp);
    hipLaunchKernelGGL(fill_k, dim3(NEDGE / 256), dim3(256), 0, stream, src, dst, et, rp, pos, edat);

    // 8 GGNN steps (A2 double-buffered: step s reads bufs[s&1], epilogue
    // writes h-half of bufs[(s+1)&1]; gemm1 of step s writes a-half of bufs[s&1])
    unsigned short* bufs[2] = {A2a, A2b};
    for (int step = 0; step < 8; step++) {
        unsigned short* cur = bufs[step & 1];
        unsigned short* nxt = bufs[(step + 1) & 1];
        hipLaunchKernelGGL(agg_k, dim3(NNODE / 4), dim3(256), 0, stream, rp, edat, hb, s);
        hipLaunchKernelGGL(gemm_bt, dim3(512), dim3(256), 0, stream,
            s, 1056, WT, (float*)nullptr, 0, 0, cur, 512, (const float*)nullptr,
            NNODE, 256, 1056, 1);
        hipLaunchKernelGGL(gemm_gru, dim3(2048), dim3(256), 0, stream,
            cur, B2T, b2, h, hb, nxt);
    }

    // readout: Y path (conv1 k=3 as 3 accumulated shifted GEMMs)
    for (int k = 0; k < 3; k++)
        hipLaunchKernelGGL(gemm_bt, dim3(512), dim3(256), 0, stream,
            hb + k * 256, 256, BT1 + k * 65536, Cbuf, 256, (k > 0),
            (unsigned short*)nullptr, 0, (k == 0) ? c1b : (const float*)nullptr,
            NNODE, 256, 256, 1);
    hipLaunchKernelGGL(pool_k, dim3(16128), dim3(256), 0, stream,
        Cbuf, 256, 256, 126, 3, 256, P, (float*)nullptr, 256);
    hipLaunchKernelGGL(gemm_bt, dim3(252), dim3(256), 0, stream,
        P, 256, BT2, Cbuf, 256, 0, (unsigned short*)nullptr, 0, c2b, 16128, 256, 256, 0);
    hipLaunchKernelGGL(pool_k, dim3(8064), dim3(256), 0, stream,
        Cbuf, 256, 126, 63, 2, 256, (unsigned short*)nullptr, Y2, 256);

    // Z path (concat conv: 3 h-part GEMMs K=256 + 3 feature-part GEMMs K=128)
    for (int k = 0; k < 3; k++)
        hipLaunchKernelGGL(gemm_bt, dim3(768), dim3(256), 0, stream,
            hb + k * 256, 256, BTc1h + k * 98304, Cbuf, 384, (k > 0),
            (unsigned short*)nullptr, 0, (k == 0) ? cc1b : (const float*)nullptr,
            NNODE, 384, 256, 1);
    for (int k = 0; k < 3; k++)
        hipLaunchKernelGGL(gemm_bt, dim3(768), dim3(256), 0, stream,
            fb + k * 128, 128, BTc1f + k * 49152, Cbuf, 384, 1,
            (unsigned short*)nullptr, 0, (const float*)nullptr,
            NNODE, 384, 128, 1);
    hipLaunchKernelGGL(pool_k, dim3(24192), dim3(256), 0, stream,
        Cbuf, 384, 256, 126, 3, 384, P, (float*)nullptr, 384);
    hipLaunchKernelGGL(gemm_bt, dim3(378), dim3(256), 0, stream,
        P, 384, BTc2, Cbuf, 384, 0, (unsigned short*)nullptr, 0, cc2b, 16128, 384, 384, 0);
    hipLaunchKernelGGL(pool_k, dim3(12096), dim3(256), 0, stream,
        Cbuf, 384, 126, 63, 2, 384, (unsigned short*)nullptr, Z2, 384);

    hipLaunchKernelGGL(final_k, dim3(128), dim3(64), 0, stream, Y2, Z2, wy, by, wz, bz, out);
}

// Round 3
// 1558.839 us; speedup vs baseline: 1.4683x; 1.2370x over previous
//
#include <hip/hip_runtime.h>

#define DEV static __device__ __forceinline__

typedef float f32x4 __attribute__((ext_vector_type(4)));
typedef __bf16 bf16x8 __attribute__((ext_vector_type(8)));
typedef unsigned int u32x4 __attribute__((ext_vector_type(4)));
typedef unsigned int u32x2 __attribute__((ext_vector_type(2)));

#define NNODE 32768
#define NEDGE 393216

DEV unsigned short f2bf(float f) {
    unsigned int u = __builtin_bit_cast(unsigned int, f);
    u += 0x7FFFu + ((u >> 16) & 1u);
    return (unsigned short)(u >> 16);
}
DEV float bf2f(unsigned int b) {
    unsigned int u = b << 16;
    return __builtin_bit_cast(float, u);
}
DEV unsigned int pk2(float a, float b) {
    return (unsigned int)f2bf(a) | ((unsigned int)f2bf(b) << 16);
}
DEV float sigf(float x) { return 1.f / (1.f + __expf(-x)); }

// async global->LDS, 16B per lane; LDS dest = wave-uniform base + lane*16
DEV void gld16(const void* g, void* l) {
    __builtin_amdgcn_global_load_lds(
        (const __attribute__((address_space(1))) void*)(g),
        (__attribute__((address_space(3))) void*)(l),
        16, 0, 0);
}

// ---------------- setup kernels ----------------

__global__ __launch_bounds__(256) void init_k(
    const float* __restrict__ feat, float* __restrict__ h,
    unsigned short* __restrict__ hb0, unsigned short* __restrict__ hb1,
    unsigned short* __restrict__ fb)
{
    int idx = blockIdx.x * 256 + threadIdx.x;   // (NNODE+8)*256
    int r = idx >> 8, c = idx & 255;
    float f = 0.f;
    if (r < NNODE && c < 128) f = feat[(size_t)r * 128 + c];
    unsigned short v = f2bf(f);
    hb0[(size_t)r * 256 + c] = v;
    hb1[(size_t)r * 256 + c] = v;
    if (c < 128) fb[(size_t)r * 128 + c] = v;
    if (r < NNODE) h[(size_t)r * 256 + c] = f;
}

__global__ __launch_bounds__(256) void prep_wmsg_k(
    const float* __restrict__ Wm, const float* __restrict__ bm,
    unsigned short* __restrict__ WT)
{
    int idx = blockIdx.x * 256 + threadIdx.x;   // 256*1056
    int o = idx / 1056, j = idx - o * 1056;
    float v = 0.f;
    if (j < 1024) { int t = j >> 8, d = j & 255; v = Wm[t * 65536 + d * 256 + o]; }
    else if (j < 1028) v = bm[(j - 1024) * 256 + o];
    WT[idx] = f2bf(v);
}

// GRU weights gate-interleaved: col' = band*64 + g*16 + ch_low,
// ch = band*16 + ch_low, g in {0:r, 1:z, 2:ig, 3:hg}. K: k<256 -> a, else h.
__global__ __launch_bounds__(256) void prep_gru_k(
    const float* __restrict__ Wi, const float* __restrict__ Wh,
    unsigned short* __restrict__ B2T)
{
    int idx = blockIdx.x * 256 + threadIdx.x;   // 1024*512
    int j = idx >> 9, k = idx & 511;
    int band = j >> 6, g = (j >> 4) & 3, ch = (band << 4) + (j & 15);
    float v = 0.f;
    if (g == 0) v = (k < 256) ? Wi[k * 768 + ch] : Wh[(k - 256) * 768 + ch];
    else if (g == 1) v = (k < 256) ? Wi[k * 768 + 256 + ch] : Wh[(k - 256) * 768 + 256 + ch];
    else if (g == 2) { if (k < 256) v = Wi[k * 768 + 512 + ch]; }
    else { if (k >= 256) v = Wh[(k - 256) * 768 + 512 + ch]; }
    B2T[idx] = f2bf(v);
}

__global__ __launch_bounds__(256) void prep_bias2_k(
    const float* __restrict__ bi, const float* __restrict__ bh,
    float* __restrict__ b2)
{
    int j = blockIdx.x * 256 + threadIdx.x;     // 1024
    int band = j >> 6, g = (j >> 4) & 3, ch = (band << 4) + (j & 15);
    float v;
    if (g == 0) v = bi[ch] + bh[ch];
    else if (g == 1) v = bi[256 + ch] + bh[256 + ch];
    else if (g == 2) v = bi[512 + ch];
    else v = bh[512 + ch];
    b2[j] = v;
}

// pack conv weights: BTY [256][768] (kk=k*256+c), BT2 [256][256],
// BTZ [384][1152] (h chunks then f chunks), BTc2 [384][384]
__global__ __launch_bounds__(256) void prep_conv_k(
    const float* __restrict__ c1w, const float* __restrict__ c2w,
    const float* __restrict__ cc1w, const float* __restrict__ cc2w,
    unsigned short* __restrict__ BTY, unsigned short* __restrict__ BT2,
    unsigned short* __restrict__ BTZ, unsigned short* __restrict__ BTc2)
{
    int idx = blockIdx.x * 256 + threadIdx.x;   // 851968 total
    if (idx < 196608) {                                     // BTY
        int o = idx / 768, kk = idx - o * 768, k = kk >> 8, c = kk & 255;
        BTY[idx] = f2bf(c1w[o * 768 + c * 3 + k]);
    } else if (idx < 262144) {                              // BT2 [o][c]
        int r = idx - 196608, o = r >> 8, c = r & 255;
        BT2[r] = f2bf(c2w[o * 256 + c]);
    } else if (idx < 704512) {                              // BTZ
        int jx = idx - 262144, o = jx / 1152, kk = jx - o * 1152;
        float v;
        if (kk < 768) { int k = kk >> 8, c = kk & 255; v = cc1w[o * 1152 + c * 3 + k]; }
        else { int r = kk - 768, kf = r >> 7, cf = r & 127; v = cc1w[o * 1152 + (256 + cf) * 3 + kf]; }
        BTZ[jx] = f2bf(v);
    } else {                                                // BTc2 [o][c]
        int r = idx - 704512, o = r / 384, c = r - o * 384;
        BTc2[r] = f2bf(cc2w[o * 384 + c]);
    }
}

// ---------------- CSR build ----------------

__global__ __launch_bounds__(256) void count_k(
    const int* __restrict__ dst, const int* __restrict__ et,
    int* __restrict__ cnt_nt)
{
    int e = blockIdx.x * 256 + threadIdx.x;
    atomicAdd(&cnt_nt[dst[e] * 4 + et[e]], 1);
}

__global__ __launch_bounds__(1024) void scan_k(
    const int* __restrict__ cnt_nt, int* __restrict__ rp)
{
    __shared__ int buf[1024];
    int tid = threadIdx.x;
    int base = 0;
    for (int chunk = 0; chunk < 32; chunk++) {
        int n = chunk * 1024 + tid;
        int v = cnt_nt[n * 4] + cnt_nt[n * 4 + 1] + cnt_nt[n * 4 + 2] + cnt_nt[n * 4 + 3];
        buf[tid] = v;
        __syncthreads();
        for (int off = 1; off < 1024; off <<= 1) {
            int x = (tid >= off) ? buf[tid - off] : 0;
            __syncthreads();
            buf[tid] += x;
            __syncthreads();
        }
        rp[n] = base + buf[tid] - v;
        base += buf[1023];
        __syncthreads();
    }
    if (tid == 0) rp[NNODE] = base;
}

__global__ __launch_bounds__(256) void fill_k(
    const int* __restrict__ src, const int* __restrict__ dst,
    const int* __restrict__ et, const int* __restrict__ rp,
    int* __restrict__ pos, int* __restrict__ edat)
{
    int e = blockIdx.x * 256 + threadIdx.x;
    int d = dst[e];
    int p = atomicAdd(&pos[d], 1);
    edat[rp[d] + p] = src[e] | (et[e] << 20);
}

// ---------------- per-step kernels ----------------

// one wave per node: gather hb[src] rows, accumulate per etype -> s[Nn,1056]
__global__ __launch_bounds__(256) void agg_k(
    const int* __restrict__ rp, const int* __restrict__ edat,
    const unsigned short* __restrict__ hb, unsigned short* __restrict__ s)
{
    int wave = threadIdx.x >> 6, lane = threadIdx.x & 63;
    int n = (blockIdx.x << 2) + wave;
    int e0 = rp[n], e1 = rp[n + 1];
    float a00=0,a01=0,a02=0,a03=0, a10=0,a11=0,a12=0,a13=0;
    float a20=0,a21=0,a22=0,a23=0, a30=0,a31=0,a32=0,a33=0;
    int c0=0,c1=0,c2=0,c3=0;
    int colb = lane << 2;
    const unsigned short* hbc = hb + colb;
    for (int e = e0; e < e1; e++) {
        int d = edat[e];
        int sn = d & 0xFFFFF, t = d >> 20;     // t is wave-uniform
        u32x2 v = *(const u32x2*)(hbc + (size_t)sn * 256);
        float f0 = bf2f(v.x & 0xFFFFu), f1 = bf2f(v.x >> 16);
        float f2 = bf2f(v.y & 0xFFFFu), f3 = bf2f(v.y >> 16);
        if (t == 0)      { a00+=f0; a01+=f1; a02+=f2; a03+=f3; c0++; }
        else if (t == 1) { a10+=f0; a11+=f1; a12+=f2; a13+=f3; c1++; }
        else if (t == 2) { a20+=f0; a21+=f1; a22+=f2; a23+=f3; c2++; }
        else             { a30+=f0; a31+=f1; a32+=f2; a33+=f3; c3++; }
    }
    unsigned short* srow = s + (size_t)n * 1056 + colb;
    u32x2 p;
    p.x = pk2(a00,a01); p.y = pk2(a02,a03); *(u32x2*)(srow      ) = p;
    p.x = pk2(a10,a11); p.y = pk2(a12,a13); *(u32x2*)(srow + 256) = p;
    p.x = pk2(a20,a21); p.y = pk2(a22,a23); *(u32x2*)(srow + 512) = p;
    p.x = pk2(a30,a31); p.y = pk2(a32,a33); *(u32x2*)(srow + 768) = p;
    unsigned short* sc = s + (size_t)n * 1056 + 1024;
    if (lane == 0) { sc[0]=f2bf((float)c0); sc[1]=f2bf((float)c1);
                     sc[2]=f2bf((float)c2); sc[3]=f2bf((float)c3); }
    if (lane >= 4 && lane < 32) sc[lane] = 0;   // zero K-pad cols 1028..1055
}

// generic bf16 GEMM, B pre-transposed [N,K]; 128x128 tile, BK=32, 4 waves,
// global_load_lds staging (m97 structure)
__global__ __launch_bounds__(256) void gemm_bt(
    const unsigned short* __restrict__ A, int lda,
    const unsigned short* __restrict__ Bt,
    float* __restrict__ Cf, int ldc,
    unsigned short* __restrict__ Cb, int ldcb,
    const float* __restrict__ bias,
    int N, int K, int swz)
{
    __shared__ __align__(16) unsigned short As[128 * 32];
    __shared__ __align__(16) unsigned short Bs[128 * 32];
    const int tid = threadIdx.x;
    int id = blockIdx.x;
    if (swz) { int per = gridDim.x >> 3; id = (id & 7) * per + (id >> 3); }
    const int nb = N >> 7;
    const int bm = id / nb, bn = id - bm * nb;
    const int wave = tid >> 6, lane = tid & 63;
    const int l4 = lane >> 2, c8 = (lane & 3) << 3;
    const unsigned short* Ag = A + (size_t)(bm * 128 + wave * 32 + l4) * lda + c8;
    const unsigned short* Bg = Bt + (size_t)(bn * 128 + wave * 32 + l4) * K + c8;
    unsigned short* lA = As + wave * 1024;
    unsigned short* lB = Bs + wave * 1024;
    const int qm = (wave & 1) << 6, qn = (wave >> 1) << 6;
    const int fm = lane & 15, fkv = lane >> 4;

    f32x4 acc[4][4] = {};

    for (int kb = 0; kb < K; kb += 32) {
        __syncthreads();
        gld16(Ag + kb, lA);
        gld16(Ag + kb + (size_t)16 * lda, lA + 512);
        gld16(Bg + kb, lB);
        gld16(Bg + kb + (size_t)16 * K, lB + 512);
        __syncthreads();
        bf16x8 af[4], bfr[4];
        #pragma unroll
        for (int i = 0; i < 4; i++)
            af[i] = *(const bf16x8*)(&As[(qm + i * 16 + fm) * 32 + fkv * 8]);
        #pragma unroll
        for (int i = 0; i < 4; i++)
            bfr[i] = *(const bf16x8*)(&Bs[(qn + i * 16 + fm) * 32 + fkv * 8]);
        #pragma unroll
        for (int i = 0; i < 4; i++)
            #pragma unroll
            for (int j = 0; j < 4; j++)
                acc[i][j] = __builtin_amdgcn_mfma_f32_16x16x32_bf16(af[i], bfr[j], acc[i][j], 0, 0, 0);
    }

    const int r0 = bm * 128 + qm + fkv * 4;
    const int c0 = bn * 128 + qn + fm;
    #pragma unroll
    for (int j = 0; j < 4; j++) {
        int col = c0 + j * 16;
        float bv = bias ? bias[col] : 0.f;
        #pragma unroll
        for (int i = 0; i < 4; i++) {
            int row = r0 + i * 16;
            #pragma unroll
            for (int r = 0; r < 4; r++) {
                float v = acc[i][j][r] + bv;
                if (Cf) Cf[(size_t)(row + r) * ldc + col] = v;
                if (Cb) Cb[(size_t)(row + r) * ldcb + col] = f2bf(v);
            }
        }
    }
}

// conv1 as single K-extended GEMM: C[l,:] = sum_k A[l+k,:] @ Wk  (+ f-part)
// K layout: kk<768 -> h chunks (lda 256, shift kk>>8), kk>=768 -> f chunks
// (lda 128, shift (kk-768)>>7). M=NNODE fixed.
__global__ __launch_bounds__(256) void gemm_conv(
    const unsigned short* __restrict__ Ah,
    const unsigned short* __restrict__ Af,
    const unsigned short* __restrict__ Bt,
    float* __restrict__ Cf, int ldc,
    const float* __restrict__ bias,
    int N, int K)
{
    __shared__ __align__(16) unsigned short As[128 * 32];
    __shared__ __align__(16) unsigned short Bs[128 * 32];
    const int tid = threadIdx.x;
    int id = blockIdx.x;
    { int per = gridDim.x >> 3; id = (id & 7) * per + (id >> 3); }
    const int nb = N >> 7;
    const int bm = id / nb, bn = id - bm * nb;
    const int wave = tid >> 6, lane = tid & 63;
    const int l4 = lane >> 2, c8 = (lane & 3) << 3;
    const int arow = bm * 128 + wave * 32 + l4;
    const unsigned short* Bg = Bt + (size_t)(bn * 128 + wave * 32 + l4) * K + c8;
    unsigned short* lA = As + wave * 1024;
    unsigned short* lB = Bs + wave * 1024;
    const int qm = (wave & 1) << 6, qn = (wave >> 1) << 6;
    const int fm = lane & 15, fkv = lane >> 4;

    f32x4 acc[4][4] = {};

    for (int kb = 0; kb < K; kb += 32) {
        const unsigned short* base; int ldA, col, shift;
        if (kb < 768) { base = Ah; ldA = 256; shift = kb >> 8; col = kb & 255; }
        else { int r = kb - 768; base = Af; ldA = 128; shift = r >> 7; col = r & 127; }
        const unsigned short* Ag = base + (size_t)(arow + shift) * ldA + col + c8;
        __syncthreads();
        gld16(Ag, lA);
        gld16(Ag + (size_t)16 * ldA, lA + 512);
        gld16(Bg + kb, lB);
        gld16(Bg + kb + (size_t)16 * K, lB + 512);
        __syncthreads();
        bf16x8 af[4], bfr[4];
        #pragma unroll
        for (int i = 0; i < 4; i++)
            af[i] = *(const bf16x8*)(&As[(qm + i * 16 + fm) * 32 + fkv * 8]);
        #pragma unroll
        for (int i = 0; i < 4; i++)
            bfr[i] = *(const bf16x8*)(&Bs[(qn + i * 16 + fm) * 32 + fkv * 8]);
        #pragma unroll
        for (int i = 0; i < 4; i++)
            #pragma unroll
            for (int j = 0; j < 4; j++)
                acc[i][j] = __builtin_amdgcn_mfma_f32_16x16x32_bf16(af[i], bfr[j], acc[i][j], 0, 0, 0);
    }

    const int r0 = bm * 128 + qm + fkv * 4;
    const int c0 = bn * 128 + qn + fm;
    #pragma unroll
    for (int j = 0; j < 4; j++) {
        int col = c0 + j * 16;
        float bv = bias[col];
        #pragma unroll
        for (int i = 0; i < 4; i++) {
            int row = r0 + i * 16;
            #pragma unroll
            for (int r = 0; r < 4; r++)
                Cf[(size_t)(row + r) * ldc + col] = acc[i][j][r] + bv;
        }
    }
}

// GRU GEMM + fused gate epilogue. A = [a|h] staged from Aonly / hbc (both
// [Nn,256]); Bt [1024,512] gate-interleaved. Lane's 4 j-frags = 4 gates of
// one channel. Writes h (fp32) and hbn (bf16, next step's state).
__global__ __launch_bounds__(256) void gemm_gru(
    const unsigned short* __restrict__ Aonly,
    const unsigned short* __restrict__ hbc,
    const unsigned short* __restrict__ Bt,
    const float* __restrict__ b2p,
    float* __restrict__ h,
    unsigned short* __restrict__ hbn)
{
    __shared__ __align__(16) unsigned short As[128 * 32];
    __shared__ __align__(16) unsigned short Bs[128 * 32];
    const int tid = threadIdx.x;
    int id = blockIdx.x;                        // 2048
    { int per = gridDim.x >> 3; id = (id & 7) * per + (id >> 3); }
    const int bm = id >> 3;
    const int bn = id & 7;
    const int wave = tid >> 6, lane = tid & 63;
    const int l4 = lane >> 2, c8 = (lane & 3) << 3;
    const int arow = bm * 128 + wave * 32 + l4;
    const unsigned short* Bg = Bt + (size_t)(bn * 128 + wave * 32 + l4) * 512 + c8;
    unsigned short* lA = As + wave * 1024;
    unsigned short* lB = Bs + wave * 1024;
    const int qm = (wave & 1) << 6, qn = (wave >> 1) << 6;
    const int fm = lane & 15, fkv = lane >> 4;

    f32x4 acc[4][4] = {};

    for (int kb = 0; kb < 512; kb += 32) {
        const unsigned short* base = (kb < 256) ? Aonly : hbc;
        int col = kb & 255;
        const unsigned short* Ag = base + (size_t)arow * 256 + col + c8;
        __syncthreads();
        gld16(Ag, lA);
        gld16(Ag + 16 * 256, lA + 512);
        gld16(Bg + kb, lB);
        gld16(Bg + kb + 16 * 512, lB + 512);
        __syncthreads();
        bf16x8 af[4], bfr[4];
        #pragma unroll
        for (int i = 0; i < 4; i++)
            af[i] = *(const bf16x8*)(&As[(qm + i * 16 + fm) * 32 + fkv * 8]);
        #pragma unroll
        for (int i = 0; i < 4; i++)
            bfr[i] = *(const bf16x8*)(&Bs[(qn + i * 16 + fm) * 32 + fkv * 8]);
        #pragma unroll
        for (int i = 0; i < 4; i++)
            #pragma unroll
            for (int j = 0; j < 4; j++)
                acc[i][j] = __builtin_amdgcn_mfma_f32_16x16x32_bf16(af[i], bfr[j], acc[i][j], 0, 0, 0);
    }

    // fused GRU gate epilogue
    const int band = (bn << 1) + (qn >> 6);
    const int ch = (band << 4) + fm;
    const float b0 = b2p[(band << 6) + fm];
    const float b1 = b2p[(band << 6) + 16 + fm];
    const float b2v = b2p[(band << 6) + 32 + fm];
    const float b3v = b2p[(band << 6) + 48 + fm];
    const int r0 = bm * 128 + qm + fkv * 4;
    #pragma unroll
    for (int i = 0; i < 4; i++) {
        #pragma unroll
        for (int r = 0; r < 4; r++) {
            int row = r0 + i * 16 + r;
            float hp = h[(size_t)row * 256 + ch];
            float rg = sigf(acc[i][0][r] + b0);
            float zz = sigf(acc[i][1][r] + b1);
            float pre = acc[i][2][r] + b2v + rg * (acc[i][3][r] + b3v);
            pre = fminf(fmaxf(pre, -15.f), 15.f);
            float t = __expf(2.f * pre);
            float gq = (t - 1.f) / (t + 1.f);
            float hn = (1.f - zz) * gq + zz * hp;
            h[(size_t)row * 256 + ch] = hn;
            hbn[(size_t)row * 256 + ch] = f2bf(hn);
        }
    }
}

// relu + maxpool over l (window win, stride 2)
__global__ __launch_bounds__(256) void pool_k(
    const float* __restrict__ in, int ldin, int Lb_in, int L_out, int win, int C,
    unsigned short* __restrict__ ob, float* __restrict__ of, int ldo)
{
    int idx = blockIdx.x * 256 + threadIdx.x;
    int c = idx % C;
    int row = idx / C;
    int b = row / L_out, lp = row - b * L_out;
    const float* p = in + (size_t)(b * Lb_in + 2 * lp) * ldin + c;
    float m = p[0];
    for (int d = 1; d < win; d++) m = fmaxf(m, p[(size_t)d * ldin]);
    m = fmaxf(m, 0.f);
    if (ob) ob[(size_t)row * ldo + c] = f2bf(m);
    else    of[(size_t)row * ldo + c] = m;
}

__global__ __launch_bounds__(64) void final_k(
    const float* __restrict__ Y2, const float* __restrict__ Z2,
    const float* __restrict__ wy, const float* __restrict__ by,
    const float* __restrict__ wz, const float* __restrict__ bz,
    float* __restrict__ out)
{
    int b = blockIdx.x, lane = threadIdx.x;
    float val = 0.f;
    if (lane < 63) {
        const float* yr = Y2 + (size_t)(b * 63 + lane) * 256;
        float y = 0.f;
        for (int o = 0; o < 256; o += 4) {
            float4 a = *(const float4*)(yr + o);
            float4 wv = *(const float4*)(wy + o);
            y += a.x * wv.x + a.y * wv.y + a.z * wv.z + a.w * wv.w;
        }
        y += by[0];
        const float* zr = Z2 + (size_t)(b * 63 + lane) * 384;
        float z = 0.f;
        for (int o = 0; o < 384; o += 4) {
            float4 a = *(const float4*)(zr + o);
            float4 wv = *(const float4*)(wz + o);
            z += a.x * wv.x + a.y * wv.y + a.z * wv.z + a.w * wv.w;
        }
        z += bz[0];
        val = y * z;
    }
    for (int off = 32; off > 0; off >>= 1) val += __shfl_down(val, off, 64);
    if (lane == 0) out[b] = sigf(val * (1.f / 63.f));
}

// ---------------- launch ----------------

extern "C" void kernel_launch(void* const* d_in, const int* in_sizes, int n_in,
                              void* d_out, int out_size, void* d_ws, size_t ws_size,
                              hipStream_t stream)
{
    const float* feat = (const float*)d_in[0];
    const int* src = (const int*)d_in[1];
    const int* dst = (const int*)d_in[2];
    const int* et  = (const int*)d_in[3];
    const float* Wm  = (const float*)d_in[4];
    const float* bm  = (const float*)d_in[5];
    const float* Wi  = (const float*)d_in[6];
    const float* Wh  = (const float*)d_in[7];
    const float* bi  = (const float*)d_in[8];
    const float* bh  = (const float*)d_in[9];
    const float* c1w = (const float*)d_in[10];
    const float* c1b = (const float*)d_in[11];
    const float* c2w = (const float*)d_in[12];
    const float* c2b = (const float*)d_in[13];
    const float* cc1w = (const float*)d_in[14];
    const float* cc1b = (const float*)d_in[15];
    const float* cc2w = (const float*)d_in[16];
    const float* cc2b = (const float*)d_in[17];
    const float* wy = (const float*)d_in[18];
    const float* by = (const float*)d_in[19];
    const float* wz = (const float*)d_in[20];
    const float* bz = (const float*)d_in[21];
    float* out = (float*)d_out;

    char* w = (char*)d_ws;
    size_t off = 0;
    auto alloc = [&](size_t bytes) -> char* {
        char* p = w + off; off += (bytes + 255) & ~(size_t)255; return p;
    };
    float* h            = (float*)alloc((size_t)NNODE * 256 * 4);
    unsigned short* hb0 = (unsigned short*)alloc((size_t)(NNODE + 8) * 256 * 2);
    unsigned short* hb1 = (unsigned short*)alloc((size_t)(NNODE + 8) * 256 * 2);
    unsigned short* fb  = (unsigned short*)alloc((size_t)(NNODE + 8) * 128 * 2);
    unsigned short* Aonly = (unsigned short*)alloc((size_t)NNODE * 256 * 2);
    char* R = alloc((size_t)NNODE * 1056 * 2);          // s / Cbuf overlay
    unsigned short* s = (unsigned short*)R;             // [Nn,1056] bf16
    float* Cbuf = (float*)R;                            // [Nn,<=384] f32 (readout)
    unsigned short* P = (unsigned short*)alloc((size_t)24192 * 384 * 2);
    float* Y2 = (float*)alloc((size_t)8064 * 256 * 4);
    float* Z2 = (float*)alloc((size_t)8064 * 384 * 4);
    unsigned short* WT   = (unsigned short*)alloc(256 * 1056 * 2);
    unsigned short* B2T  = (unsigned short*)alloc(1024 * 512 * 2);
    float* b2            = (float*)alloc(1024 * 4);
    unsigned short* BTY  = (unsigned short*)alloc(256 * 768 * 2);
    unsigned short* BT2  = (unsigned short*)alloc(256 * 256 * 2);
    unsigned short* BTZ  = (unsigned short*)alloc(384 * 1152 * 2);
    unsigned short* BTc2 = (unsigned short*)alloc(384 * 384 * 2);
    int* rp     = (int*)alloc((NNODE + 1) * 4);
    int* pos    = (int*)alloc(NNODE * 4);
    int* cnt_nt = (int*)alloc(NNODE * 16);
    int* edat   = (int*)alloc(NEDGE * 4);

    // setup
    hipLaunchKernelGGL(init_k, dim3(NNODE + 8), dim3(256), 0, stream, feat, h, hb0, hb1, fb);
    hipLaunchKernelGGL(prep_wmsg_k, dim3(1056), dim3(256), 0, stream, Wm, bm, WT);
    hipLaunchKernelGGL(prep_gru_k, dim3(2048), dim3(256), 0, stream, Wi, Wh, B2T);
    hipLaunchKernelGGL(prep_bias2_k, dim3(4), dim3(256), 0, stream, bi, bh, b2);
    hipLaunchKernelGGL(prep_conv_k, dim3(3328), dim3(256), 0, stream,
                       c1w, c2w, cc1w, cc2w, BTY, BT2, BTZ, BTc2);
    hipMemsetAsync(pos, 0, NNODE * 4, stream);
    hipMemsetAsync(cnt_nt, 0, NNODE * 16, stream);
    hipLaunchKernelGGL(count_k, dim3(NEDGE / 256), dim3(256), 0, stream, dst, et, cnt_nt);
    hipLaunchKernelGGL(scan_k, dim3(1), dim3(1024), 0, stream, cnt_nt, rp);
    hipLaunchKernelGGL(fill_k, dim3(NEDGE / 256), dim3(256), 0, stream, src, dst, et, rp, pos, edat);

    // 8 GGNN steps; h-state bf16 double-buffered (hb0 -> hb1 -> hb0 ...)
    unsigned short* hbuf[2] = {hb0, hb1};
    for (int step = 0; step < 8; step++) {
        unsigned short* cur = hbuf[step & 1];
        unsigned short* nxt = hbuf[(step + 1) & 1];
        hipLaunchKernelGGL(agg_k, dim3(NNODE / 4), dim3(256), 0, stream, rp, edat, cur, s);
        hipLaunchKernelGGL(gemm_bt, dim3(512), dim3(256), 0, stream,
            s, 1056, WT, (float*)nullptr, 0, Aonly, 256, (const float*)nullptr,
            256, 1056, 1);
        hipLaunchKernelGGL(gemm_gru, dim3(2048), dim3(256), 0, stream,
            Aonly, cur, B2T, b2, h, nxt);
    }
    // final state is in hb0 (after 8 flips)

    // readout: Y path
    hipLaunchKernelGGL(gemm_conv, dim3(512), dim3(256), 0, stream,
        hb0, (const unsigned short*)nullptr, BTY, Cbuf, 256, c1b, 256, 768);
    hipLaunchKernelGGL(pool_k, dim3(16128), dim3(256), 0, stream,
        Cbuf, 256, 256, 126, 3, 256, P, (float*)nullptr, 256);
    hipLaunchKernelGGL(gemm_bt, dim3(252), dim3(256), 0, stream,
        P, 256, BT2, Cbuf, 256, (unsigned short*)nullptr, 0, c2b, 256, 256, 0);
    hipLaunchKernelGGL(pool_k, dim3(8064), dim3(256), 0, stream,
        Cbuf, 256, 126, 63, 2, 256, (unsigned short*)nullptr, Y2, 256);

    // Z path
    hipLaunchKernelGGL(gemm_conv, dim3(768), dim3(256), 0, stream,
        hb0, fb, BTZ, Cbuf, 384, cc1b, 384, 1152);
    hipLaunchKernelGGL(pool_k, dim3(24192), dim3(256), 0, stream,
        Cbuf, 384, 256, 126, 3, 384, P, (float*)nullptr, 384);
    hipLaunchKernelGGL(gemm_bt, dim3(378), dim3(256), 0, stream,
        P, 384, BTc2, Cbuf, 384, (unsigned short*)nullptr, 0, cc2b, 384, 384, 0);
    hipLaunchKernelGGL(pool_k, dim3(12096), dim3(256), 0, stream,
        Cbuf, 384, 126, 63, 2, 384, (unsigned short*)nullptr, Z2, 384);

    hipLaunchKernelGGL(final_k, dim3(128), dim3(64), 0, stream, Y2, Z2, wy, by, wz, bz, out);
}

// Round 4
// 1536.974 us; speedup vs baseline: 1.4892x; 1.0142x over previous
//
#include <hip/hip_runtime.h>

#define DEV static __device__ __forceinline__

typedef float f32x4 __attribute__((ext_vector_type(4)));
typedef __bf16 bf16x8 __attribute__((ext_vector_type(8)));
typedef unsigned int u32x4 __attribute__((ext_vector_type(4)));
typedef unsigned int u32x2 __attribute__((ext_vector_type(2)));

#define NNODE 32768
#define NEDGE 393216

DEV unsigned short f2bf(float f) {
    unsigned int u = __builtin_bit_cast(unsigned int, f);
    u += 0x7FFFu + ((u >> 16) & 1u);
    return (unsigned short)(u >> 16);
}
DEV float bf2f(unsigned int b) {
    unsigned int u = b << 16;
    return __builtin_bit_cast(float, u);
}
DEV unsigned int pk2(float a, float b) {
    return (unsigned int)f2bf(a) | ((unsigned int)f2bf(b) << 16);
}
DEV float sigf(float x) { return 1.f / (1.f + __expf(-x)); }

// async global->LDS, 16B per lane; LDS dest = wave-uniform base + lane*16
DEV void gld16(const void* g, void* l) {
    __builtin_amdgcn_global_load_lds(
        (const __attribute__((address_space(1))) void*)(g),
        (__attribute__((address_space(3))) void*)(l),
        16, 0, 0);
}

// ---------------- setup kernels ----------------

__global__ __launch_bounds__(256) void init_k(
    const float* __restrict__ feat, float* __restrict__ h,
    unsigned short* __restrict__ hb0, unsigned short* __restrict__ hb1,
    unsigned short* __restrict__ fb)
{
    int idx = blockIdx.x * 256 + threadIdx.x;   // (NNODE+8)*256
    int r = idx >> 8, c = idx & 255;
    float f = 0.f;
    if (r < NNODE && c < 128) f = feat[(size_t)r * 128 + c];
    unsigned short v = f2bf(f);
    hb0[(size_t)r * 256 + c] = v;
    hb1[(size_t)r * 256 + c] = v;
    if (c < 128) fb[(size_t)r * 128 + c] = v;
    if (r < NNODE) h[(size_t)r * 256 + c] = f;
}

// WT [1024,256]: row j = t*256+o, col d -> Wm[t][d][o]
__global__ __launch_bounds__(256) void prep_wmsg_k(
    const float* __restrict__ Wm, unsigned short* __restrict__ WT)
{
    int idx = blockIdx.x * 256 + threadIdx.x;   // 1024*256
    int j = idx >> 8, d = idx & 255;
    int t = j >> 8, o = j & 255;
    WT[idx] = f2bf(Wm[t * 65536 + d * 256 + o]);
}

// GRU weights gate-interleaved: col' = band*64 + g*16 + ch_low,
// ch = band*16 + ch_low, g in {0:r, 1:z, 2:ig, 3:hg}. K: k<256 -> a, else h.
__global__ __launch_bounds__(256) void prep_gru_k(
    const float* __restrict__ Wi, const float* __restrict__ Wh,
    unsigned short* __restrict__ B2T)
{
    int idx = blockIdx.x * 256 + threadIdx.x;   // 1024*512
    int j = idx >> 9, k = idx & 511;
    int band = j >> 6, g = (j >> 4) & 3, ch = (band << 4) + (j & 15);
    float v = 0.f;
    if (g == 0) v = (k < 256) ? Wi[k * 768 + ch] : Wh[(k - 256) * 768 + ch];
    else if (g == 1) v = (k < 256) ? Wi[k * 768 + 256 + ch] : Wh[(k - 256) * 768 + 256 + ch];
    else if (g == 2) { if (k < 256) v = Wi[k * 768 + 512 + ch]; }
    else { if (k >= 256) v = Wh[(k - 256) * 768 + 512 + ch]; }
    B2T[idx] = f2bf(v);
}

__global__ __launch_bounds__(256) void prep_bias2_k(
    const float* __restrict__ bi, const float* __restrict__ bh,
    float* __restrict__ b2)
{
    int j = blockIdx.x * 256 + threadIdx.x;     // 1024
    int band = j >> 6, g = (j >> 4) & 3, ch = (band << 4) + (j & 15);
    float v;
    if (g == 0) v = bi[ch] + bh[ch];
    else if (g == 1) v = bi[256 + ch] + bh[256 + ch];
    else if (g == 2) v = bi[512 + ch];
    else v = bh[512 + ch];
    b2[j] = v;
}

// pack conv weights: BTY [256][768] (kk=k*256+c), BT2 [256][256],
// BTZ [384][1152] (h chunks then f chunks), BTc2 [384][384]
__global__ __launch_bounds__(256) void prep_conv_k(
    const float* __restrict__ c1w, const float* __restrict__ c2w,
    const float* __restrict__ cc1w, const float* __restrict__ cc2w,
    unsigned short* __restrict__ BTY, unsigned short* __restrict__ BT2,
    unsigned short* __restrict__ BTZ, unsigned short* __restrict__ BTc2)
{
    int idx = blockIdx.x * 256 + threadIdx.x;   // 851968 total
    if (idx < 196608) {                                     // BTY
        int o = idx / 768, kk = idx - o * 768, k = kk >> 8, c = kk & 255;
        BTY[idx] = f2bf(c1w[o * 768 + c * 3 + k]);
    } else if (idx < 262144) {                              // BT2 [o][c]
        int r = idx - 196608, o = r >> 8, c = r & 255;
        BT2[r] = f2bf(c2w[o * 256 + c]);
    } else if (idx < 704512) {                              // BTZ
        int jx = idx - 262144, o = jx / 1152, kk = jx - o * 1152;
        float v;
        if (kk < 768) { int k = kk >> 8, c = kk & 255; v = cc1w[o * 1152 + c * 3 + k]; }
        else { int r = kk - 768, kf = r >> 7, cf = r & 127; v = cc1w[o * 1152 + (256 + cf) * 3 + kf]; }
        BTZ[jx] = f2bf(v);
    } else {                                                // BTc2 [o][c]
        int r = idx - 704512, o = r / 384, c = r - o * 384;
        BTc2[r] = f2bf(cc2w[o * 384 + c]);
    }
}

// ---------------- CSR build ----------------

__global__ __launch_bounds__(256) void count_k(
    const int* __restrict__ dst, int* __restrict__ cnt)
{
    int e = blockIdx.x * 256 + threadIdx.x;
    atomicAdd(&cnt[dst[e]], 1);
}

__global__ __launch_bounds__(1024) void scan_k(
    const int* __restrict__ cnt, int* __restrict__ rp)
{
    __shared__ int buf[1024];
    int tid = threadIdx.x;
    int base = 0;
    for (int chunk = 0; chunk < 32; chunk++) {
        int n = chunk * 1024 + tid;
        int v = cnt[n];
        buf[tid] = v;
        __syncthreads();
        for (int off = 1; off < 1024; off <<= 1) {
            int x = (tid >= off) ? buf[tid - off] : 0;
            __syncthreads();
            buf[tid] += x;
            __syncthreads();
        }
        rp[n] = base + buf[tid] - v;
        base += buf[1023];
        __syncthreads();
    }
    if (tid == 0) rp[NNODE] = base;
}

__global__ __launch_bounds__(256) void fill_k(
    const int* __restrict__ src, const int* __restrict__ dst,
    const int* __restrict__ et, const int* __restrict__ rp,
    int* __restrict__ pos, int* __restrict__ edat)
{
    int e = blockIdx.x * 256 + threadIdx.x;
    int d = dst[e];
    int p = atomicAdd(&pos[d], 1);
    edat[rp[d] + p] = src[e] | (et[e] << 20);
}

// ---------------- per-step kernels ----------------

// one wave per node: gather Hmsg[src, et*256 .. +256] rows, sum fp32 -> Aonly
__global__ __launch_bounds__(256) void agg2_k(
    const int* __restrict__ rp, const int* __restrict__ edat,
    const unsigned short* __restrict__ Hmsg, unsigned short* __restrict__ Aonly)
{
    int wave = threadIdx.x >> 6, lane = threadIdx.x & 63;
    int n = (blockIdx.x << 2) + wave;
    int e0 = rp[n], e1 = rp[n + 1];
    float a0 = 0.f, a1 = 0.f, a2 = 0.f, a3 = 0.f;
    const unsigned short* hc = Hmsg + (lane << 2);
    for (int e = e0; e < e1; e++) {
        int d = edat[e];
        int sn = d & 0xFFFFF, t = d >> 20;
        u32x2 v = *(const u32x2*)(hc + ((size_t)sn << 10) + (t << 8));
        a0 += bf2f(v.x & 0xFFFFu); a1 += bf2f(v.x >> 16);
        a2 += bf2f(v.y & 0xFFFFu); a3 += bf2f(v.y >> 16);
    }
    u32x2 p; p.x = pk2(a0, a1); p.y = pk2(a2, a3);
    *(u32x2*)(Aonly + (size_t)n * 256 + (lane << 2)) = p;
}

// generic bf16 GEMM, B pre-transposed [N,K]; 128x128 tile, BK=32, 4 waves,
// global_load_lds staging (m97 structure)
__global__ __launch_bounds__(256) void gemm_bt(
    const unsigned short* __restrict__ A, int lda,
    const unsigned short* __restrict__ Bt,
    float* __restrict__ Cf, int ldc,
    unsigned short* __restrict__ Cb, int ldcb,
    const float* __restrict__ bias,
    int N, int K, int swz)
{
    __shared__ __align__(16) unsigned short As[128 * 32];
    __shared__ __align__(16) unsigned short Bs[128 * 32];
    const int tid = threadIdx.x;
    int id = blockIdx.x;
    if (swz) { int per = gridDim.x >> 3; id = (id & 7) * per + (id >> 3); }
    const int nb = N >> 7;
    const int bm = id / nb, bn = id - bm * nb;
    const int wave = tid >> 6, lane = tid & 63;
    const int l4 = lane >> 2, c8 = (lane & 3) << 3;
    const unsigned short* Ag = A + (size_t)(bm * 128 + wave * 32 + l4) * lda + c8;
    const unsigned short* Bg = Bt + (size_t)(bn * 128 + wave * 32 + l4) * K + c8;
    unsigned short* lA = As + wave * 1024;
    unsigned short* lB = Bs + wave * 1024;
    const int qm = (wave & 1) << 6, qn = (wave >> 1) << 6;
    const int fm = lane & 15, fkv = lane >> 4;

    f32x4 acc[4][4] = {};

    for (int kb = 0; kb < K; kb += 32) {
        __syncthreads();
        gld16(Ag + kb, lA);
        gld16(Ag + kb + (size_t)16 * lda, lA + 512);
        gld16(Bg + kb, lB);
        gld16(Bg + kb + (size_t)16 * K, lB + 512);
        __syncthreads();
        bf16x8 af[4], bfr[4];
        #pragma unroll
        for (int i = 0; i < 4; i++)
            af[i] = *(const bf16x8*)(&As[(qm + i * 16 + fm) * 32 + fkv * 8]);
        #pragma unroll
        for (int i = 0; i < 4; i++)
            bfr[i] = *(const bf16x8*)(&Bs[(qn + i * 16 + fm) * 32 + fkv * 8]);
        #pragma unroll
        for (int i = 0; i < 4; i++)
            #pragma unroll
            for (int j = 0; j < 4; j++)
                acc[i][j] = __builtin_amdgcn_mfma_f32_16x16x32_bf16(af[i], bfr[j], acc[i][j], 0, 0, 0);
    }

    const int r0 = bm * 128 + qm + fkv * 4;
    const int c0 = bn * 128 + qn + fm;
    #pragma unroll
    for (int j = 0; j < 4; j++) {
        int col = c0 + j * 16;
        float bv = bias ? bias[col] : 0.f;
        #pragma unroll
        for (int i = 0; i < 4; i++) {
            int row = r0 + i * 16;
            #pragma unroll
            for (int r = 0; r < 4; r++) {
                float v = acc[i][j][r] + bv;
                if (Cf) Cf[(size_t)(row + r) * ldc + col] = v;
                if (Cb) Cb[(size_t)(row + r) * ldcb + col] = f2bf(v);
            }
        }
    }
}

// conv1 as single K-extended GEMM: C[l,:] = sum_k A[l+k,:] @ Wk  (+ f-part)
// K layout: kk<768 -> h chunks (lda 256, shift kk>>8), kk>=768 -> f chunks
// (lda 128, shift (kk-768)>>7). M=NNODE fixed.
__global__ __launch_bounds__(256) void gemm_conv(
    const unsigned short* __restrict__ Ah,
    const unsigned short* __restrict__ Af,
    const unsigned short* __restrict__ Bt,
    float* __restrict__ Cf, int ldc,
    const float* __restrict__ bias,
    int N, int K)
{
    __shared__ __align__(16) unsigned short As[128 * 32];
    __shared__ __align__(16) unsigned short Bs[128 * 32];
    const int tid = threadIdx.x;
    int id = blockIdx.x;
    { int per = gridDim.x >> 3; id = (id & 7) * per + (id >> 3); }
    const int nb = N >> 7;
    const int bm = id / nb, bn = id - bm * nb;
    const int wave = tid >> 6, lane = tid & 63;
    const int l4 = lane >> 2, c8 = (lane & 3) << 3;
    const int arow = bm * 128 + wave * 32 + l4;
    const unsigned short* Bg = Bt + (size_t)(bn * 128 + wave * 32 + l4) * K + c8;
    unsigned short* lA = As + wave * 1024;
    unsigned short* lB = Bs + wave * 1024;
    const int qm = (wave & 1) << 6, qn = (wave >> 1) << 6;
    const int fm = lane & 15, fkv = lane >> 4;

    f32x4 acc[4][4] = {};

    for (int kb = 0; kb < K; kb += 32) {
        const unsigned short* base; int ldA, col, shift;
        if (kb < 768) { base = Ah; ldA = 256; shift = kb >> 8; col = kb & 255; }
        else { int r = kb - 768; base = Af; ldA = 128; shift = r >> 7; col = r & 127; }
        const unsigned short* Ag = base + (size_t)(arow + shift) * ldA + col + c8;
        __syncthreads();
        gld16(Ag, lA);
        gld16(Ag + (size_t)16 * ldA, lA + 512);
        gld16(Bg + kb, lB);
        gld16(Bg + kb + (size_t)16 * K, lB + 512);
        __syncthreads();
        bf16x8 af[4], bfr[4];
        #pragma unroll
        for (int i = 0; i < 4; i++)
            af[i] = *(const bf16x8*)(&As[(qm + i * 16 + fm) * 32 + fkv * 8]);
        #pragma unroll
        for (int i = 0; i < 4; i++)
            bfr[i] = *(const bf16x8*)(&Bs[(qn + i * 16 + fm) * 32 + fkv * 8]);
        #pragma unroll
        for (int i = 0; i < 4; i++)
            #pragma unroll
            for (int j = 0; j < 4; j++)
                acc[i][j] = __builtin_amdgcn_mfma_f32_16x16x32_bf16(af[i], bfr[j], acc[i][j], 0, 0, 0);
    }

    const int r0 = bm * 128 + qm + fkv * 4;
    const int c0 = bn * 128 + qn + fm;
    #pragma unroll
    for (int j = 0; j < 4; j++) {
        int col = c0 + j * 16;
        float bv = bias[col];
        #pragma unroll
        for (int i = 0; i < 4; i++) {
            int row = r0 + i * 16;
            #pragma unroll
            for (int r = 0; r < 4; r++)
                Cf[(size_t)(row + r) * ldc + col] = acc[i][j][r] + bv;
        }
    }
}

// GRU GEMM + fused gate epilogue. A = [a|h] staged from Aonly / hbc (both
// [Nn,256]); Bt [1024,512] gate-interleaved. Lane's 4 j-frags = 4 gates of
// one channel. Writes h (fp32) and hbn (bf16, next step's state).
__global__ __launch_bounds__(256) void gemm_gru(
    const unsigned short* __restrict__ Aonly,
    const unsigned short* __restrict__ hbc,
    const unsigned short* __restrict__ Bt,
    const float* __restrict__ b2p,
    float* __restrict__ h,
    unsigned short* __restrict__ hbn)
{
    __shared__ __align__(16) unsigned short As[128 * 32];
    __shared__ __align__(16) unsigned short Bs[128 * 32];
    const int tid = threadIdx.x;
    int id = blockIdx.x;                        // 2048
    { int per = gridDim.x >> 3; id = (id & 7) * per + (id >> 3); }
    const int bm = id >> 3;
    const int bn = id & 7;
    const int wave = tid >> 6, lane = tid & 63;
    const int l4 = lane >> 2, c8 = (lane & 3) << 3;
    const int arow = bm * 128 + wave * 32 + l4;
    const unsigned short* Bg = Bt + (size_t)(bn * 128 + wave * 32 + l4) * 512 + c8;
    unsigned short* lA = As + wave * 1024;
    unsigned short* lB = Bs + wave * 1024;
    const int qm = (wave & 1) << 6, qn = (wave >> 1) << 6;
    const int fm = lane & 15, fkv = lane >> 4;

    f32x4 acc[4][4] = {};

    for (int kb = 0; kb < 512; kb += 32) {
        const unsigned short* base = (kb < 256) ? Aonly : hbc;
        int col = kb & 255;
        const unsigned short* Ag = base + (size_t)arow * 256 + col + c8;
        __syncthreads();
        gld16(Ag, lA);
        gld16(Ag + 16 * 256, lA + 512);
        gld16(Bg + kb, lB);
        gld16(Bg + kb + 16 * 512, lB + 512);
        __syncthreads();
        bf16x8 af[4], bfr[4];
        #pragma unroll
        for (int i = 0; i < 4; i++)
            af[i] = *(const bf16x8*)(&As[(qm + i * 16 + fm) * 32 + fkv * 8]);
        #pragma unroll
        for (int i = 0; i < 4; i++)
            bfr[i] = *(const bf16x8*)(&Bs[(qn + i * 16 + fm) * 32 + fkv * 8]);
        #pragma unroll
        for (int i = 0; i < 4; i++)
            #pragma unroll
            for (int j = 0; j < 4; j++)
                acc[i][j] = __builtin_amdgcn_mfma_f32_16x16x32_bf16(af[i], bfr[j], acc[i][j], 0, 0, 0);
    }

    // fused GRU gate epilogue
    const int band = (bn << 1) + (qn >> 6);
    const int ch = (band << 4) + fm;
    const float b0 = b2p[(band << 6) + fm];
    const float b1 = b2p[(band << 6) + 16 + fm];
    const float b2v = b2p[(band << 6) + 32 + fm];
    const float b3v = b2p[(band << 6) + 48 + fm];
    const int r0 = bm * 128 + qm + fkv * 4;
    #pragma unroll
    for (int i = 0; i < 4; i++) {
        #pragma unroll
        for (int r = 0; r < 4; r++) {
            int row = r0 + i * 16 + r;
            float hp = h[(size_t)row * 256 + ch];
            float rg = sigf(acc[i][0][r] + b0);
            float zz = sigf(acc[i][1][r] + b1);
            float pre = acc[i][2][r] + b2v + rg * (acc[i][3][r] + b3v);
            pre = fminf(fmaxf(pre, -15.f), 15.f);
            float t = __expf(2.f * pre);
            float gq = (t - 1.f) / (t + 1.f);
            float hn = (1.f - zz) * gq + zz * hp;
            h[(size_t)row * 256 + ch] = hn;
            hbn[(size_t)row * 256 + ch] = f2bf(hn);
        }
    }
}

// relu + maxpool over l (window win, stride 2)
__global__ __launch_bounds__(256) void pool_k(
    const float* __restrict__ in, int ldin, int Lb_in, int L_out, int win, int C,
    unsigned short* __restrict__ ob, float* __restrict__ of, int ldo)
{
    int idx = blockIdx.x * 256 + threadIdx.x;
    int c = idx % C;
    int row = idx / C;
    int b = row / L_out, lp = row - b * L_out;
    const float* p = in + (size_t)(b * Lb_in + 2 * lp) * ldin + c;
    float m = p[0];
    for (int d = 1; d < win; d++) m = fmaxf(m, p[(size_t)d * ldin]);
    m = fmaxf(m, 0.f);
    if (ob) ob[(size_t)row * ldo + c] = f2bf(m);
    else    of[(size_t)row * ldo + c] = m;
}

__global__ __launch_bounds__(64) void final_k(
    const float* __restrict__ Y2, const float* __restrict__ Z2,
    const float* __restrict__ wy, const float* __restrict__ by,
    const float* __restrict__ wz, const float* __restrict__ bz,
    float* __restrict__ out)
{
    int b = blockIdx.x, lane = threadIdx.x;
    float val = 0.f;
    if (lane < 63) {
        const float* yr = Y2 + (size_t)(b * 63 + lane) * 256;
        float y = 0.f;
        for (int o = 0; o < 256; o += 4) {
            float4 a = *(const float4*)(yr + o);
            float4 wv = *(const float4*)(wy + o);
            y += a.x * wv.x + a.y * wv.y + a.z * wv.z + a.w * wv.w;
        }
        y += by[0];
        const float* zr = Z2 + (size_t)(b * 63 + lane) * 384;
        float z = 0.f;
        for (int o = 0; o < 384; o += 4) {
            float4 a = *(const float4*)(zr + o);
            float4 wv = *(const float4*)(wz + o);
            z += a.x * wv.x + a.y * wv.y + a.z * wv.z + a.w * wv.w;
        }
        z += bz[0];
        val = y * z;
    }
    for (int off = 32; off > 0; off >>= 1) val += __shfl_down(val, off, 64);
    if (lane == 0) out[b] = sigf(val * (1.f / 63.f));
}

// ---------------- launch ----------------

extern "C" void kernel_launch(void* const* d_in, const int* in_sizes, int n_in,
                              void* d_out, int out_size, void* d_ws, size_t ws_size,
                              hipStream_t stream)
{
    const float* feat = (const float*)d_in[0];
    const int* src = (const int*)d_in[1];
    const int* dst = (const int*)d_in[2];
    const int* et  = (const int*)d_in[3];
    const float* Wm  = (const float*)d_in[4];
    const float* bm  = (const float*)d_in[5];
    const float* Wi  = (const float*)d_in[6];
    const float* Wh  = (const float*)d_in[7];
    const float* bi  = (const float*)d_in[8];
    const float* bh  = (const float*)d_in[9];
    const float* c1w = (const float*)d_in[10];
    const float* c1b = (const float*)d_in[11];
    const float* c2w = (const float*)d_in[12];
    const float* c2b = (const float*)d_in[13];
    const float* cc1w = (const float*)d_in[14];
    const float* cc1b = (const float*)d_in[15];
    const float* cc2w = (const float*)d_in[16];
    const float* cc2b = (const float*)d_in[17];
    const float* wy = (const float*)d_in[18];
    const float* by = (const float*)d_in[19];
    const float* wz = (const float*)d_in[20];
    const float* bz = (const float*)d_in[21];
    float* out = (float*)d_out;

    char* w = (char*)d_ws;
    size_t off = 0;
    auto alloc = [&](size_t bytes) -> char* {
        char* p = w + off; off += (bytes + 255) & ~(size_t)255; return p;
    };
    float* h            = (float*)alloc((size_t)NNODE * 256 * 4);
    unsigned short* hb0 = (unsigned short*)alloc((size_t)(NNODE + 8) * 256 * 2);
    unsigned short* hb1 = (unsigned short*)alloc((size_t)(NNODE + 8) * 256 * 2);
    unsigned short* fb  = (unsigned short*)alloc((size_t)(NNODE + 8) * 128 * 2);
    unsigned short* Aonly = (unsigned short*)alloc((size_t)NNODE * 256 * 2);
    char* R = alloc((size_t)NNODE * 1024 * 2);          // Hmsg / Cbuf overlay (67MB)
    unsigned short* Hmsg = (unsigned short*)R;          // [Nn,1024] bf16
    float* Cbuf = (float*)R;                            // [Nn,<=384] f32 (readout)
    unsigned short* P = (unsigned short*)alloc((size_t)24192 * 384 * 2);
    float* Y2 = (float*)alloc((size_t)8064 * 256 * 4);
    float* Z2 = (float*)alloc((size_t)8064 * 384 * 4);
    unsigned short* WT   = (unsigned short*)alloc(1024 * 256 * 2);
    unsigned short* B2T  = (unsigned short*)alloc(1024 * 512 * 2);
    float* b2            = (float*)alloc(1024 * 4);
    unsigned short* BTY  = (unsigned short*)alloc(256 * 768 * 2);
    unsigned short* BT2  = (unsigned short*)alloc(256 * 256 * 2);
    unsigned short* BTZ  = (unsigned short*)alloc(384 * 1152 * 2);
    unsigned short* BTc2 = (unsigned short*)alloc(384 * 384 * 2);
    int* rp     = (int*)alloc((NNODE + 1) * 4);
    int* pos    = (int*)alloc(NNODE * 4);
    int* cnt    = (int*)alloc(NNODE * 4);
    int* edat   = (int*)alloc(NEDGE * 4);

    // setup
    hipLaunchKernelGGL(init_k, dim3(NNODE + 8), dim3(256), 0, stream, feat, h, hb0, hb1, fb);
    hipLaunchKernelGGL(prep_wmsg_k, dim3(1024), dim3(256), 0, stream, Wm, WT);
    hipLaunchKernelGGL(prep_gru_k, dim3(2048), dim3(256), 0, stream, Wi, Wh, B2T);
    hipLaunchKernelGGL(prep_bias2_k, dim3(4), dim3(256), 0, stream, bi, bh, b2);
    hipLaunchKernelGGL(prep_conv_k, dim3(3328), dim3(256), 0, stream,
                       c1w, c2w, cc1w, cc2w, BTY, BT2, BTZ, BTc2);
    hipMemsetAsync(pos, 0, NNODE * 4, stream);
    hipMemsetAsync(cnt, 0, NNODE * 4, stream);
    hipLaunchKernelGGL(count_k, dim3(NEDGE / 256), dim3(256), 0, stream, dst, cnt);
    hipLaunchKernelGGL(scan_k, dim3(1), dim3(1024), 0, stream, cnt, rp);
    hipLaunchKernelGGL(fill_k, dim3(NEDGE / 256), dim3(256), 0, stream, src, dst, et, rp, pos, edat);

    // 8 GGNN steps; h-state bf16 double-buffered (hb0 -> hb1 -> hb0 ...)
    // per step: Hmsg = hb@WT + bm  ->  Aonly[dst] = sum Hmsg[src, et]  ->  GRU
    unsigned short* hbuf[2] = {hb0, hb1};
    for (int step = 0; step < 8; step++) {
        unsigned short* cur = hbuf[step & 1];
        unsigned short* nxt = hbuf[(step + 1) & 1];
        hipLaunchKernelGGL(gemm_bt, dim3(2048), dim3(256), 0, stream,
            cur, 256, WT, (float*)nullptr, 0, Hmsg, 1024, bm,
            1024, 256, 1);
        hipLaunchKernelGGL(agg2_k, dim3(NNODE / 4), dim3(256), 0, stream, rp, edat, Hmsg, Aonly);
        hipLaunchKernelGGL(gemm_gru, dim3(2048), dim3(256), 0, stream,
            Aonly, cur, B2T, b2, h, nxt);
    }
    // final state is in hb0 (after 8 flips)

    // readout: Y path
    hipLaunchKernelGGL(gemm_conv, dim3(512), dim3(256), 0, stream,
        hb0, (const unsigned short*)nullptr, BTY, Cbuf, 256, c1b, 256, 768);
    hipLaunchKernelGGL(pool_k, dim3(16128), dim3(256), 0, stream,
        Cbuf, 256, 256, 126, 3, 256, P, (float*)nullptr, 256);
    hipLaunchKernelGGL(gemm_bt, dim3(252), dim3(256), 0, stream,
        P, 256, BT2, Cbuf, 256, (unsigned short*)nullptr, 0, c2b, 256, 256, 0);
    hipLaunchKernelGGL(pool_k, dim3(8064), dim3(256), 0, stream,
        Cbuf, 256, 126, 63, 2, 256, (unsigned short*)nullptr, Y2, 256);

    // Z path
    hipLaunchKernelGGL(gemm_conv, dim3(768), dim3(256), 0, stream,
        hb0, fb, BTZ, Cbuf, 384, cc1b, 384, 1152);
    hipLaunchKernelGGL(pool_k, dim3(24192), dim3(256), 0, stream,
        Cbuf, 384, 256, 126, 3, 384, P, (float*)nullptr, 384);
    hipLaunchKernelGGL(gemm_bt, dim3(378), dim3(256), 0, stream,
        P, 384, BTc2, Cbuf, 384, (unsigned short*)nullptr, 0, cc2b, 384, 384, 0);
    hipLaunchKernelGGL(pool_k, dim3(12096), dim3(256), 0, stream,
        Cbuf, 384, 126, 63, 2, 384, (unsigned short*)nullptr, Z2, 384);

    hipLaunchKernelGGL(final_k, dim3(128), dim3(64), 0, stream, Y2, Z2, wy, by, wz, bz, out);
}

// Round 5
// 1486.562 us; speedup vs baseline: 1.5397x; 1.0339x over previous
//
#include <hip/hip_runtime.h>

#define DEV static __device__ __forceinline__

typedef float f32x4 __attribute__((ext_vector_type(4)));
typedef __bf16 bf16x8 __attribute__((ext_vector_type(8)));
typedef unsigned int u32x4 __attribute__((ext_vector_type(4)));
typedef unsigned int u32x2 __attribute__((ext_vector_type(2)));

#define NNODE 32768
#define NEDGE 393216

DEV unsigned short f2bf(float f) {
    unsigned int u = __builtin_bit_cast(unsigned int, f);
    u += 0x7FFFu + ((u >> 16) & 1u);
    return (unsigned short)(u >> 16);
}
DEV float bf2f(unsigned int b) {
    unsigned int u = b << 16;
    return __builtin_bit_cast(float, u);
}
DEV unsigned int pk2(float a, float b) {
    return (unsigned int)f2bf(a) | ((unsigned int)f2bf(b) << 16);
}
DEV float sigf(float x) { return 1.f / (1.f + __expf(-x)); }

// async global->LDS, 16B per lane; LDS dest = wave-uniform base + lane*16
DEV void gld16(const void* g, void* l) {
    __builtin_amdgcn_global_load_lds(
        (const __attribute__((address_space(1))) void*)(g),
        (__attribute__((address_space(3))) void*)(l),
        16, 0, 0);
}

// ---------------- setup kernels ----------------

__global__ __launch_bounds__(256) void init_k(
    const float* __restrict__ feat,
    unsigned short* __restrict__ hb0, unsigned short* __restrict__ hb1,
    unsigned short* __restrict__ fb)
{
    int idx = blockIdx.x * 256 + threadIdx.x;   // (NNODE+8)*256
    int r = idx >> 8, c = idx & 255;
    float f = 0.f;
    if (r < NNODE && c < 128) f = feat[(size_t)r * 128 + c];
    unsigned short v = f2bf(f);
    hb0[(size_t)r * 256 + c] = v;
    hb1[(size_t)r * 256 + c] = v;
    if (c < 128) fb[(size_t)r * 128 + c] = v;
}

// WT [1024,256]: row j = t*256+o, col d -> Wm[t][d][o]
__global__ __launch_bounds__(256) void prep_wmsg_k(
    const float* __restrict__ Wm, unsigned short* __restrict__ WT)
{
    int idx = blockIdx.x * 256 + threadIdx.x;   // 1024*256
    int j = idx >> 8, d = idx & 255;
    int t = j >> 8, o = j & 255;
    WT[idx] = f2bf(Wm[t * 65536 + d * 256 + o]);
}

// GRU weights gate-interleaved: col' = band*64 + g*16 + ch_low,
// ch = band*16 + ch_low, g in {0:r, 1:z, 2:ig, 3:hg}. K: k<256 -> a, else h.
__global__ __launch_bounds__(256) void prep_gru_k(
    const float* __restrict__ Wi, const float* __restrict__ Wh,
    unsigned short* __restrict__ B2T)
{
    int idx = blockIdx.x * 256 + threadIdx.x;   // 1024*512
    int j = idx >> 9, k = idx & 511;
    int band = j >> 6, g = (j >> 4) & 3, ch = (band << 4) + (j & 15);
    float v = 0.f;
    if (g == 0) v = (k < 256) ? Wi[k * 768 + ch] : Wh[(k - 256) * 768 + ch];
    else if (g == 1) v = (k < 256) ? Wi[k * 768 + 256 + ch] : Wh[(k - 256) * 768 + 256 + ch];
    else if (g == 2) { if (k < 256) v = Wi[k * 768 + 512 + ch]; }
    else { if (k >= 256) v = Wh[(k - 256) * 768 + 512 + ch]; }
    B2T[idx] = f2bf(v);
}

__global__ __launch_bounds__(256) void prep_bias2_k(
    const float* __restrict__ bi, const float* __restrict__ bh,
    float* __restrict__ b2)
{
    int j = blockIdx.x * 256 + threadIdx.x;     // 1024
    int band = j >> 6, g = (j >> 4) & 3, ch = (band << 4) + (j & 15);
    float v;
    if (g == 0) v = bi[ch] + bh[ch];
    else if (g == 1) v = bi[256 + ch] + bh[256 + ch];
    else if (g == 2) v = bi[512 + ch];
    else v = bh[512 + ch];
    b2[j] = v;
}

// pack conv weights: BTY [256][768] (kk=k*256+c), BT2 [256][256],
// BTZ [384][1152] (h chunks then f chunks), BTc2 [384][384]
__global__ __launch_bounds__(256) void prep_conv_k(
    const float* __restrict__ c1w, const float* __restrict__ c2w,
    const float* __restrict__ cc1w, const float* __restrict__ cc2w,
    unsigned short* __restrict__ BTY, unsigned short* __restrict__ BT2,
    unsigned short* __restrict__ BTZ, unsigned short* __restrict__ BTc2)
{
    int idx = blockIdx.x * 256 + threadIdx.x;   // 851968 total
    if (idx < 196608) {                                     // BTY
        int o = idx / 768, kk = idx - o * 768, k = kk >> 8, c = kk & 255;
        BTY[idx] = f2bf(c1w[o * 768 + c * 3 + k]);
    } else if (idx < 262144) {                              // BT2 [o][c]
        int r = idx - 196608, o = r >> 8, c = r & 255;
        BT2[r] = f2bf(c2w[o * 256 + c]);
    } else if (idx < 704512) {                              // BTZ
        int jx = idx - 262144, o = jx / 1152, kk = jx - o * 1152;
        float v;
        if (kk < 768) { int k = kk >> 8, c = kk & 255; v = cc1w[o * 1152 + c * 3 + k]; }
        else { int r = kk - 768, kf = r >> 7, cf = r & 127; v = cc1w[o * 1152 + (256 + cf) * 3 + kf]; }
        BTZ[jx] = f2bf(v);
    } else {                                                // BTc2 [o][c]
        int r = idx - 704512, o = r / 384, c = r - o * 384;
        BTc2[r] = f2bf(cc2w[o * 384 + c]);
    }
}

// ---------------- CSR build ----------------

__global__ __launch_bounds__(256) void count_k(
    const int* __restrict__ dst, int* __restrict__ cnt)
{
    int e = blockIdx.x * 256 + threadIdx.x;
    atomicAdd(&cnt[dst[e]], 1);
}

__global__ __launch_bounds__(1024) void scan_k(
    const int* __restrict__ cnt, int* __restrict__ rp)
{
    __shared__ int buf[1024];
    int tid = threadIdx.x;
    int base = 0;
    for (int chunk = 0; chunk < 32; chunk++) {
        int n = chunk * 1024 + tid;
        int v = cnt[n];
        buf[tid] = v;
        __syncthreads();
        for (int off = 1; off < 1024; off <<= 1) {
            int x = (tid >= off) ? buf[tid - off] : 0;
            __syncthreads();
            buf[tid] += x;
            __syncthreads();
        }
        rp[n] = base + buf[tid] - v;
        base += buf[1023];
        __syncthreads();
    }
    if (tid == 0) rp[NNODE] = base;
}

__global__ __launch_bounds__(256) void fill_k(
    const int* __restrict__ src, const int* __restrict__ dst,
    const int* __restrict__ et, const int* __restrict__ rp,
    int* __restrict__ pos, int* __restrict__ edat)
{
    int e = blockIdx.x * 256 + threadIdx.x;
    int d = dst[e];
    int p = atomicAdd(&pos[d], 1);
    edat[rp[d] + p] = src[e] | (et[e] << 20);
}

// ---------------- per-step kernels ----------------

// one wave per node: gather Hmsg[src, et*256 .. +256] rows, sum fp32 -> Aonly
__global__ __launch_bounds__(256) void agg2_k(
    const int* __restrict__ rp, const int* __restrict__ edat,
    const unsigned short* __restrict__ Hmsg, unsigned short* __restrict__ Aonly)
{
    int wave = threadIdx.x >> 6, lane = threadIdx.x & 63;
    int n = (blockIdx.x << 2) + wave;
    int e0 = rp[n], e1 = rp[n + 1];
    float a0 = 0.f, a1 = 0.f, a2 = 0.f, a3 = 0.f;
    const unsigned short* hc = Hmsg + (lane << 2);
    for (int e = e0; e < e1; e++) {
        int d = edat[e];
        int sn = d & 0xFFFFF, t = d >> 20;
        u32x2 v = *(const u32x2*)(hc + ((size_t)sn << 10) + (t << 8));
        a0 += bf2f(v.x & 0xFFFFu); a1 += bf2f(v.x >> 16);
        a2 += bf2f(v.y & 0xFFFFu); a3 += bf2f(v.y >> 16);
    }
    u32x2 p; p.x = pk2(a0, a1); p.y = pk2(a2, a3);
    *(u32x2*)(Aonly + (size_t)n * 256 + (lane << 2)) = p;
}

// bf16 GEMM, B pre-transposed [N,K]; 128x128 tile, BK=32, 4 waves,
// global_load_lds staging; bf16 output with optional relu
__global__ __launch_bounds__(256) void gemm_bt(
    const unsigned short* __restrict__ A, int lda,
    const unsigned short* __restrict__ Bt,
    unsigned short* __restrict__ Cb, int ldcb,
    const float* __restrict__ bias,
    int N, int K, int swz, int relu)
{
    __shared__ __align__(16) unsigned short As[128 * 32];
    __shared__ __align__(16) unsigned short Bs[128 * 32];
    const int tid = threadIdx.x;
    int id = blockIdx.x;
    if (swz) { int per = gridDim.x >> 3; id = (id & 7) * per + (id >> 3); }
    const int nb = N >> 7;
    const int bm = id / nb, bn = id - bm * nb;
    const int wave = tid >> 6, lane = tid & 63;
    const int l4 = lane >> 2, c8 = (lane & 3) << 3;
    const unsigned short* Ag = A + (size_t)(bm * 128 + wave * 32 + l4) * lda + c8;
    const unsigned short* Bg = Bt + (size_t)(bn * 128 + wave * 32 + l4) * K + c8;
    unsigned short* lA = As + wave * 1024;
    unsigned short* lB = Bs + wave * 1024;
    const int qm = (wave & 1) << 6, qn = (wave >> 1) << 6;
    const int fm = lane & 15, fkv = lane >> 4;

    f32x4 acc[4][4] = {};

    for (int kb = 0; kb < K; kb += 32) {
        __syncthreads();
        gld16(Ag + kb, lA);
        gld16(Ag + kb + (size_t)16 * lda, lA + 512);
        gld16(Bg + kb, lB);
        gld16(Bg + kb + (size_t)16 * K, lB + 512);
        __syncthreads();
        bf16x8 af[4], bfr[4];
        #pragma unroll
        for (int i = 0; i < 4; i++)
            af[i] = *(const bf16x8*)(&As[(qm + i * 16 + fm) * 32 + fkv * 8]);
        #pragma unroll
        for (int i = 0; i < 4; i++)
            bfr[i] = *(const bf16x8*)(&Bs[(qn + i * 16 + fm) * 32 + fkv * 8]);
        #pragma unroll
        for (int i = 0; i < 4; i++)
            #pragma unroll
            for (int j = 0; j < 4; j++)
                acc[i][j] = __builtin_amdgcn_mfma_f32_16x16x32_bf16(af[i], bfr[j], acc[i][j], 0, 0, 0);
    }

    const int r0 = bm * 128 + qm + fkv * 4;
    const int c0 = bn * 128 + qn + fm;
    #pragma unroll
    for (int j = 0; j < 4; j++) {
        int col = c0 + j * 16;
        float bv = bias ? bias[col] : 0.f;
        #pragma unroll
        for (int i = 0; i < 4; i++) {
            int row = r0 + i * 16;
            #pragma unroll
            for (int r = 0; r < 4; r++) {
                float v = acc[i][j][r] + bv;
                if (relu) v = fmaxf(v, 0.f);
                Cb[(size_t)(row + r) * ldcb + col] = f2bf(v);
            }
        }
    }
}

// conv1 as single K-extended GEMM: C[l,:] = relu(sum_k A[l+k,:] @ Wk + b)
// K layout: kk<768 -> h chunks (lda 256, shift kk>>8), kk>=768 -> f chunks
// (lda 128, shift (kk-768)>>7). M=NNODE fixed. bf16 output.
__global__ __launch_bounds__(256) void gemm_conv(
    const unsigned short* __restrict__ Ah,
    const unsigned short* __restrict__ Af,
    const unsigned short* __restrict__ Bt,
    unsigned short* __restrict__ Cb, int ldcb,
    const float* __restrict__ bias,
    int N, int K)
{
    __shared__ __align__(16) unsigned short As[128 * 32];
    __shared__ __align__(16) unsigned short Bs[128 * 32];
    const int tid = threadIdx.x;
    int id = blockIdx.x;
    { int per = gridDim.x >> 3; id = (id & 7) * per + (id >> 3); }
    const int nb = N >> 7;
    const int bm = id / nb, bn = id - bm * nb;
    const int wave = tid >> 6, lane = tid & 63;
    const int l4 = lane >> 2, c8 = (lane & 3) << 3;
    const int arow = bm * 128 + wave * 32 + l4;
    const unsigned short* Bg = Bt + (size_t)(bn * 128 + wave * 32 + l4) * K + c8;
    unsigned short* lA = As + wave * 1024;
    unsigned short* lB = Bs + wave * 1024;
    const int qm = (wave & 1) << 6, qn = (wave >> 1) << 6;
    const int fm = lane & 15, fkv = lane >> 4;

    f32x4 acc[4][4] = {};

    for (int kb = 0; kb < K; kb += 32) {
        const unsigned short* base; int ldA, col, shift;
        if (kb < 768) { base = Ah; ldA = 256; shift = kb >> 8; col = kb & 255; }
        else { int r = kb - 768; base = Af; ldA = 128; shift = r >> 7; col = r & 127; }
        const unsigned short* Ag = base + (size_t)(arow + shift) * ldA + col + c8;
        __syncthreads();
        gld16(Ag, lA);
        gld16(Ag + (size_t)16 * ldA, lA + 512);
        gld16(Bg + kb, lB);
        gld16(Bg + kb + (size_t)16 * K, lB + 512);
        __syncthreads();
        bf16x8 af[4], bfr[4];
        #pragma unroll
        for (int i = 0; i < 4; i++)
            af[i] = *(const bf16x8*)(&As[(qm + i * 16 + fm) * 32 + fkv * 8]);
        #pragma unroll
        for (int i = 0; i < 4; i++)
            bfr[i] = *(const bf16x8*)(&Bs[(qn + i * 16 + fm) * 32 + fkv * 8]);
        #pragma unroll
        for (int i = 0; i < 4; i++)
            #pragma unroll
            for (int j = 0; j < 4; j++)
                acc[i][j] = __builtin_amdgcn_mfma_f32_16x16x32_bf16(af[i], bfr[j], acc[i][j], 0, 0, 0);
    }

    const int r0 = bm * 128 + qm + fkv * 4;
    const int c0 = bn * 128 + qn + fm;
    #pragma unroll
    for (int j = 0; j < 4; j++) {
        int col = c0 + j * 16;
        float bv = bias[col];
        #pragma unroll
        for (int i = 0; i < 4; i++) {
            int row = r0 + i * 16;
            #pragma unroll
            for (int r = 0; r < 4; r++)
                Cb[(size_t)(row + r) * ldcb + col] = f2bf(fmaxf(acc[i][j][r] + bv, 0.f));
        }
    }
}

// GRU GEMM + fused gate epilogue. A = [a|h] staged from Aonly / hbc (both
// [Nn,256] bf16); Bt [1024,512] gate-interleaved. Lane's 4 j-frags = 4 gates
// of one channel. State is bf16-only: reads hbc, writes hbn.
__global__ __launch_bounds__(256) void gemm_gru(
    const unsigned short* __restrict__ Aonly,
    const unsigned short* __restrict__ hbc,
    const unsigned short* __restrict__ Bt,
    const float* __restrict__ b2p,
    unsigned short* __restrict__ hbn)
{
    __shared__ __align__(16) unsigned short As[128 * 32];
    __shared__ __align__(16) unsigned short Bs[128 * 32];
    const int tid = threadIdx.x;
    int id = blockIdx.x;                        // 2048
    { int per = gridDim.x >> 3; id = (id & 7) * per + (id >> 3); }
    const int bm = id >> 3;
    const int bn = id & 7;
    const int wave = tid >> 6, lane = tid & 63;
    const int l4 = lane >> 2, c8 = (lane & 3) << 3;
    const int arow = bm * 128 + wave * 32 + l4;
    const unsigned short* Bg = Bt + (size_t)(bn * 128 + wave * 32 + l4) * 512 + c8;
    unsigned short* lA = As + wave * 1024;
    unsigned short* lB = Bs + wave * 1024;
    const int qm = (wave & 1) << 6, qn = (wave >> 1) << 6;
    const int fm = lane & 15, fkv = lane >> 4;

    f32x4 acc[4][4] = {};

    for (int kb = 0; kb < 512; kb += 32) {
        const unsigned short* base = (kb < 256) ? Aonly : hbc;
        int col = kb & 255;
        const unsigned short* Ag = base + (size_t)arow * 256 + col + c8;
        __syncthreads();
        gld16(Ag, lA);
        gld16(Ag + 16 * 256, lA + 512);
        gld16(Bg + kb, lB);
        gld16(Bg + kb + 16 * 512, lB + 512);
        __syncthreads();
        bf16x8 af[4], bfr[4];
        #pragma unroll
        for (int i = 0; i < 4; i++)
            af[i] = *(const bf16x8*)(&As[(qm + i * 16 + fm) * 32 + fkv * 8]);
        #pragma unroll
        for (int i = 0; i < 4; i++)
            bfr[i] = *(const bf16x8*)(&Bs[(qn + i * 16 + fm) * 32 + fkv * 8]);
        #pragma unroll
        for (int i = 0; i < 4; i++)
            #pragma unroll
            for (int j = 0; j < 4; j++)
                acc[i][j] = __builtin_amdgcn_mfma_f32_16x16x32_bf16(af[i], bfr[j], acc[i][j], 0, 0, 0);
    }

    // fused GRU gate epilogue (bf16 state)
    const int band = (bn << 1) + (qn >> 6);
    const int ch = (band << 4) + fm;
    const float b0 = b2p[(band << 6) + fm];
    const float b1 = b2p[(band << 6) + 16 + fm];
    const float b2v = b2p[(band << 6) + 32 + fm];
    const float b3v = b2p[(band << 6) + 48 + fm];
    const int r0 = bm * 128 + qm + fkv * 4;
    #pragma unroll
    for (int i = 0; i < 4; i++) {
        #pragma unroll
        for (int r = 0; r < 4; r++) {
            int row = r0 + i * 16 + r;
            float hp = bf2f(hbc[(size_t)row * 256 + ch]);
            float rg = sigf(acc[i][0][r] + b0);
            float zz = sigf(acc[i][1][r] + b1);
            float pre = acc[i][2][r] + b2v + rg * (acc[i][3][r] + b3v);
            pre = fminf(fmaxf(pre, -15.f), 15.f);
            float t = __expf(2.f * pre);
            float gq = (t - 1.f) / (t + 1.f);
            float hn = (1.f - zz) * gq + zz * hp;
            hbn[(size_t)row * 256 + ch] = f2bf(hn);
        }
    }
}

// maxpool over l (window win, stride 2), bf16 input (relu pre-applied)
__global__ __launch_bounds__(256) void pool_k(
    const unsigned short* __restrict__ in, int ldin, int Lb_in, int L_out,
    int win, int C,
    unsigned short* __restrict__ ob, float* __restrict__ of, int ldo)
{
    int idx = blockIdx.x * 256 + threadIdx.x;
    int c = idx % C;
    int row = idx / C;
    int b = row / L_out, lp = row - b * L_out;
    const unsigned short* p = in + (size_t)(b * Lb_in + 2 * lp) * ldin + c;
    float m = bf2f(p[0]);
    for (int d = 1; d < win; d++) m = fmaxf(m, bf2f(p[(size_t)d * ldin]));
    if (ob) ob[(size_t)row * ldo + c] = f2bf(m);
    else    of[(size_t)row * ldo + c] = m;
}

__global__ __launch_bounds__(64) void final_k(
    const float* __restrict__ Y2, const float* __restrict__ Z2,
    const float* __restrict__ wy, const float* __restrict__ by,
    const float* __restrict__ wz, const float* __restrict__ bz,
    float* __restrict__ out)
{
    int b = blockIdx.x, lane = threadIdx.x;
    float val = 0.f;
    if (lane < 63) {
        const float* yr = Y2 + (size_t)(b * 63 + lane) * 256;
        float y = 0.f;
        for (int o = 0; o < 256; o += 4) {
            float4 a = *(const float4*)(yr + o);
            float4 wv = *(const float4*)(wy + o);
            y += a.x * wv.x + a.y * wv.y + a.z * wv.z + a.w * wv.w;
        }
        y += by[0];
        const float* zr = Z2 + (size_t)(b * 63 + lane) * 384;
        float z = 0.f;
        for (int o = 0; o < 384; o += 4) {
            float4 a = *(const float4*)(zr + o);
            float4 wv = *(const float4*)(wz + o);
            z += a.x * wv.x + a.y * wv.y + a.z * wv.z + a.w * wv.w;
        }
        z += bz[0];
        val = y * z;
    }
    for (int off = 32; off > 0; off >>= 1) val += __shfl_down(val, off, 64);
    if (lane == 0) out[b] = sigf(val * (1.f / 63.f));
}

// ---------------- launch ----------------

extern "C" void kernel_launch(void* const* d_in, const int* in_sizes, int n_in,
                              void* d_out, int out_size, void* d_ws, size_t ws_size,
                              hipStream_t stream)
{
    const float* feat = (const float*)d_in[0];
    const int* src = (const int*)d_in[1];
    const int* dst = (const int*)d_in[2];
    const int* et  = (const int*)d_in[3];
    const float* Wm  = (const float*)d_in[4];
    const float* bm  = (const float*)d_in[5];
    const float* Wi  = (const float*)d_in[6];
    const float* Wh  = (const float*)d_in[7];
    const float* bi  = (const float*)d_in[8];
    const float* bh  = (const float*)d_in[9];
    const float* c1w = (const float*)d_in[10];
    const float* c1b = (const float*)d_in[11];
    const float* c2w = (const float*)d_in[12];
    const float* c2b = (const float*)d_in[13];
    const float* cc1w = (const float*)d_in[14];
    const float* cc1b = (const float*)d_in[15];
    const float* cc2w = (const float*)d_in[16];
    const float* cc2b = (const float*)d_in[17];
    const float* wy = (const float*)d_in[18];
    const float* by = (const float*)d_in[19];
    const float* wz = (const float*)d_in[20];
    const float* bz = (const float*)d_in[21];
    float* out = (float*)d_out;

    char* w = (char*)d_ws;
    size_t off = 0;
    auto alloc = [&](size_t bytes) -> char* {
        char* p = w + off; off += (bytes + 255) & ~(size_t)255; return p;
    };
    unsigned short* hb0 = (unsigned short*)alloc((size_t)(NNODE + 8) * 256 * 2);
    unsigned short* hb1 = (unsigned short*)alloc((size_t)(NNODE + 8) * 256 * 2);
    unsigned short* fb  = (unsigned short*)alloc((size_t)(NNODE + 8) * 128 * 2);
    unsigned short* Aonly = (unsigned short*)alloc((size_t)NNODE * 256 * 2);
    char* R = alloc((size_t)NNODE * 1024 * 2);          // Hmsg / conv1-out overlay
    unsigned short* Hmsg = (unsigned short*)R;          // [Nn,1024] bf16
    unsigned short* CbY  = (unsigned short*)R;          // [Nn,256] bf16 (conv1 Y)
    unsigned short* CbZ  = (unsigned short*)(R + (size_t)NNODE * 256 * 2); // [Nn,384]
    unsigned short* P    = (unsigned short*)alloc((size_t)16128 * 384 * 2);
    unsigned short* Cb2  = (unsigned short*)alloc((size_t)16128 * 384 * 2); // conv2 out
    float* Y2 = (float*)alloc((size_t)8064 * 256 * 4);
    float* Z2 = (float*)alloc((size_t)8064 * 384 * 4);
    unsigned short* WT   = (unsigned short*)alloc(1024 * 256 * 2);
    unsigned short* B2T  = (unsigned short*)alloc(1024 * 512 * 2);
    float* b2            = (float*)alloc(1024 * 4);
    unsigned short* BTY  = (unsigned short*)alloc(256 * 768 * 2);
    unsigned short* BT2  = (unsigned short*)alloc(256 * 256 * 2);
    unsigned short* BTZ  = (unsigned short*)alloc(384 * 1152 * 2);
    unsigned short* BTc2 = (unsigned short*)alloc(384 * 384 * 2);
    int* rp     = (int*)alloc((NNODE + 1) * 4);
    int* pos    = (int*)alloc(NNODE * 4);
    int* cnt    = (int*)alloc(NNODE * 4);
    int* edat   = (int*)alloc(NEDGE * 4);

    // setup
    hipLaunchKernelGGL(init_k, dim3(NNODE + 8), dim3(256), 0, stream, feat, hb0, hb1, fb);
    hipLaunchKernelGGL(prep_wmsg_k, dim3(1024), dim3(256), 0, stream, Wm, WT);
    hipLaunchKernelGGL(prep_gru_k, dim3(2048), dim3(256), 0, stream, Wi, Wh, B2T);
    hipLaunchKernelGGL(prep_bias2_k, dim3(4), dim3(256), 0, stream, bi, bh, b2);
    hipLaunchKernelGGL(prep_conv_k, dim3(3328), dim3(256), 0, stream,
                       c1w, c2w, cc1w, cc2w, BTY, BT2, BTZ, BTc2);
    hipMemsetAsync(pos, 0, NNODE * 4, stream);
    hipMemsetAsync(cnt, 0, NNODE * 4, stream);
    hipLaunchKernelGGL(count_k, dim3(NEDGE / 256), dim3(256), 0, stream, dst, cnt);
    hipLaunchKernelGGL(scan_k, dim3(1), dim3(1024), 0, stream, cnt, rp);
    hipLaunchKernelGGL(fill_k, dim3(NEDGE / 256), dim3(256), 0, stream, src, dst, et, rp, pos, edat);

    // 8 GGNN steps; bf16 state double-buffered (hb0 -> hb1 -> hb0 ...)
    // per step: Hmsg = hb@WT + bm  ->  Aonly[dst] = sum Hmsg[src, et]  ->  GRU
    unsigned short* hbuf[2] = {hb0, hb1};
    for (int step = 0; step < 8; step++) {
        unsigned short* cur = hbuf[step & 1];
        unsigned short* nxt = hbuf[(step + 1) & 1];
        hipLaunchKernelGGL(gemm_bt, dim3(2048), dim3(256), 0, stream,
            cur, 256, WT, Hmsg, 1024, bm, 1024, 256, 1, 0);
        hipLaunchKernelGGL(agg2_k, dim3(NNODE / 4), dim3(256), 0, stream, rp, edat, Hmsg, Aonly);
        hipLaunchKernelGGL(gemm_gru, dim3(2048), dim3(256), 0, stream,
            Aonly, cur, B2T, b2, nxt);
    }
    // final state is in hb0 (after 8 flips)

    // readout: Y path (relu fused in GEMMs, bf16 intermediates)
    hipLaunchKernelGGL(gemm_conv, dim3(512), dim3(256), 0, stream,
        hb0, (const unsigned short*)nullptr, BTY, CbY, 256, c1b, 256, 768);
    hipLaunchKernelGGL(pool_k, dim3(16128), dim3(256), 0, stream,
        CbY, 256, 256, 126, 3, 256, P, (float*)nullptr, 256);
    hipLaunchKernelGGL(gemm_bt, dim3(252), dim3(256), 0, stream,
        P, 256, BT2, Cb2, 256, c2b, 256, 256, 0, 1);
    hipLaunchKernelGGL(pool_k, dim3(8064), dim3(256), 0, stream,
        Cb2, 256, 126, 63, 2, 256, (unsigned short*)nullptr, Y2, 256);

    // Z path
    hipLaunchKernelGGL(gemm_conv, dim3(768), dim3(256), 0, stream,
        hb0, fb, BTZ, CbZ, 384, cc1b, 384, 1152);
    hipLaunchKernelGGL(pool_k, dim3(24192), dim3(256), 0, stream,
        CbZ, 384, 256, 126, 3, 384, P, (float*)nullptr, 384);
    hipLaunchKernelGGL(gemm_bt, dim3(378), dim3(256), 0, stream,
        P, 384, BTc2, Cb2, 384, cc2b, 384, 384, 0, 1);
    hipLaunchKernelGGL(pool_k, dim3(12096), dim3(256), 0, stream,
        Cb2, 384, 126, 63, 2, 384, (unsigned short*)nullptr, Z2, 384);

    hipLaunchKernelGGL(final_k, dim3(128), dim3(64), 0, stream, Y2, Z2, wy, by, wz, bz, out);
}

// Round 6
// 1478.341 us; speedup vs baseline: 1.5483x; 1.0056x over previous
//
#include <hip/hip_runtime.h>

#define DEV static __device__ __forceinline__

typedef float f32x4 __attribute__((ext_vector_type(4)));
typedef __bf16 bf16x8 __attribute__((ext_vector_type(8)));
typedef unsigned int u32x4 __attribute__((ext_vector_type(4)));
typedef unsigned int u32x2 __attribute__((ext_vector_type(2)));

#define NNODE 32768
#define NEDGE 393216

DEV unsigned short f2bf(float f) {
    unsigned int u = __builtin_bit_cast(unsigned int, f);
    u += 0x7FFFu + ((u >> 16) & 1u);
    return (unsigned short)(u >> 16);
}
DEV float bf2f(unsigned int b) {
    unsigned int u = b << 16;
    return __builtin_bit_cast(float, u);
}
DEV unsigned int pk2(float a, float b) {
    return (unsigned int)f2bf(a) | ((unsigned int)f2bf(b) << 16);
}
DEV float sigf(float x) { return 1.f / (1.f + __expf(-x)); }

// async global->LDS, 16B per lane; LDS dest = wave-uniform base + lane*16
DEV void gld16(const void* g, void* l) {
    __builtin_amdgcn_global_load_lds(
        (const __attribute__((address_space(1))) void*)(g),
        (__attribute__((address_space(3))) void*)(l),
        16, 0, 0);
}

// ---------------- setup kernels ----------------

__global__ __launch_bounds__(256) void init_k(
    const float* __restrict__ feat,
    unsigned short* __restrict__ hb0, unsigned short* __restrict__ hb1,
    unsigned short* __restrict__ fb)
{
    int idx = blockIdx.x * 256 + threadIdx.x;   // (NNODE+8)*256
    int r = idx >> 8, c = idx & 255;
    float f = 0.f;
    if (r < NNODE && c < 128) f = feat[(size_t)r * 128 + c];
    unsigned short v = f2bf(f);
    hb0[(size_t)r * 256 + c] = v;
    hb1[(size_t)r * 256 + c] = v;
    if (c < 128) fb[(size_t)r * 128 + c] = v;
}

// WT [1024,256]: row j = t*256+o, col d -> Wm[t][d][o]
__global__ __launch_bounds__(256) void prep_wmsg_k(
    const float* __restrict__ Wm, unsigned short* __restrict__ WT)
{
    int idx = blockIdx.x * 256 + threadIdx.x;   // 1024*256
    int j = idx >> 8, d = idx & 255;
    int t = j >> 8, o = j & 255;
    WT[idx] = f2bf(Wm[t * 65536 + d * 256 + o]);
}

// GRU weights gate-interleaved: col' = band*64 + g*16 + ch_low,
// ch = band*16 + ch_low, g in {0:r, 1:z, 2:ig, 3:hg}. K: k<256 -> a, else h.
__global__ __launch_bounds__(256) void prep_gru_k(
    const float* __restrict__ Wi, const float* __restrict__ Wh,
    unsigned short* __restrict__ B2T)
{
    int idx = blockIdx.x * 256 + threadIdx.x;   // 1024*512
    int j = idx >> 9, k = idx & 511;
    int band = j >> 6, g = (j >> 4) & 3, ch = (band << 4) + (j & 15);
    float v = 0.f;
    if (g == 0) v = (k < 256) ? Wi[k * 768 + ch] : Wh[(k - 256) * 768 + ch];
    else if (g == 1) v = (k < 256) ? Wi[k * 768 + 256 + ch] : Wh[(k - 256) * 768 + 256 + ch];
    else if (g == 2) { if (k < 256) v = Wi[k * 768 + 512 + ch]; }
    else { if (k >= 256) v = Wh[(k - 256) * 768 + 512 + ch]; }
    B2T[idx] = f2bf(v);
}

__global__ __launch_bounds__(256) void prep_bias2_k(
    const float* __restrict__ bi, const float* __restrict__ bh,
    float* __restrict__ b2)
{
    int j = blockIdx.x * 256 + threadIdx.x;     // 1024
    int band = j >> 6, g = (j >> 4) & 3, ch = (band << 4) + (j & 15);
    float v;
    if (g == 0) v = bi[ch] + bh[ch];
    else if (g == 1) v = bi[256 + ch] + bh[256 + ch];
    else if (g == 2) v = bi[512 + ch];
    else v = bh[512 + ch];
    b2[j] = v;
}

// pack conv weights: BTY [256][768] (kk=k*256+c), BT2 [256][256],
// BTZ [384][1152] (h chunks then f chunks), BTc2 [384][384]
__global__ __launch_bounds__(256) void prep_conv_k(
    const float* __restrict__ c1w, const float* __restrict__ c2w,
    const float* __restrict__ cc1w, const float* __restrict__ cc2w,
    unsigned short* __restrict__ BTY, unsigned short* __restrict__ BT2,
    unsigned short* __restrict__ BTZ, unsigned short* __restrict__ BTc2)
{
    int idx = blockIdx.x * 256 + threadIdx.x;   // 851968 total
    if (idx < 196608) {                                     // BTY
        int o = idx / 768, kk = idx - o * 768, k = kk >> 8, c = kk & 255;
        BTY[idx] = f2bf(c1w[o * 768 + c * 3 + k]);
    } else if (idx < 262144) {                              // BT2 [o][c]
        int r = idx - 196608, o = r >> 8, c = r & 255;
        BT2[r] = f2bf(c2w[o * 256 + c]);
    } else if (idx < 704512) {                              // BTZ
        int jx = idx - 262144, o = jx / 1152, kk = jx - o * 1152;
        float v;
        if (kk < 768) { int k = kk >> 8, c = kk & 255; v = cc1w[o * 1152 + c * 3 + k]; }
        else { int r = kk - 768, kf = r >> 7, cf = r & 127; v = cc1w[o * 1152 + (256 + cf) * 3 + kf]; }
        BTZ[jx] = f2bf(v);
    } else {                                                // BTc2 [o][c]
        int r = idx - 704512, o = r / 384, c = r - o * 384;
        BTc2[r] = f2bf(cc2w[o * 384 + c]);
    }
}

// ---------------- CSR build ----------------

__global__ __launch_bounds__(256) void count_k(
    const int* __restrict__ dst, int* __restrict__ cnt)
{
    int e = blockIdx.x * 256 + threadIdx.x;
    atomicAdd(&cnt[dst[e]], 1);
}

__global__ __launch_bounds__(1024) void scan_k(
    const int* __restrict__ cnt, int* __restrict__ rp)
{
    __shared__ int buf[1024];
    int tid = threadIdx.x;
    int base = 0;
    for (int chunk = 0; chunk < 32; chunk++) {
        int n = chunk * 1024 + tid;
        int v = cnt[n];
        buf[tid] = v;
        __syncthreads();
        for (int off = 1; off < 1024; off <<= 1) {
            int x = (tid >= off) ? buf[tid - off] : 0;
            __syncthreads();
            buf[tid] += x;
            __syncthreads();
        }
        rp[n] = base + buf[tid] - v;
        base += buf[1023];
        __syncthreads();
    }
    if (tid == 0) rp[NNODE] = base;
}

__global__ __launch_bounds__(256) void fill_k(
    const int* __restrict__ src, const int* __restrict__ dst,
    const int* __restrict__ et, const int* __restrict__ rp,
    int* __restrict__ pos, int* __restrict__ edat)
{
    int e = blockIdx.x * 256 + threadIdx.x;
    int d = dst[e];
    int p = atomicAdd(&pos[d], 1);
    edat[rp[d] + p] = src[e] | (et[e] << 20);
}

// ---------------- per-step kernels ----------------

// one wave per node: gather Hmsg[src, et*256 .. +256] rows, sum fp32 -> Aonly
// unrolled x4 so 4 gathers are in flight
__global__ __launch_bounds__(256) void agg2_k(
    const int* __restrict__ rp, const int* __restrict__ edat,
    const unsigned short* __restrict__ Hmsg, unsigned short* __restrict__ Aonly)
{
    int wave = threadIdx.x >> 6, lane = threadIdx.x & 63;
    int n = (blockIdx.x << 2) + wave;
    int e0 = rp[n], e1 = rp[n + 1];
    float a0 = 0.f, a1 = 0.f, a2 = 0.f, a3 = 0.f;
    const unsigned short* hc = Hmsg + (lane << 2);
    int e = e0;
    for (; e + 4 <= e1; e += 4) {
        int d0 = edat[e], d1 = edat[e + 1], d2 = edat[e + 2], d3 = edat[e + 3];
        u32x2 v0 = *(const u32x2*)(hc + ((size_t)(d0 & 0xFFFFF) << 10) + ((d0 >> 20) << 8));
        u32x2 v1 = *(const u32x2*)(hc + ((size_t)(d1 & 0xFFFFF) << 10) + ((d1 >> 20) << 8));
        u32x2 v2 = *(const u32x2*)(hc + ((size_t)(d2 & 0xFFFFF) << 10) + ((d2 >> 20) << 8));
        u32x2 v3 = *(const u32x2*)(hc + ((size_t)(d3 & 0xFFFFF) << 10) + ((d3 >> 20) << 8));
        a0 += bf2f(v0.x & 0xFFFFu) + bf2f(v1.x & 0xFFFFu) + bf2f(v2.x & 0xFFFFu) + bf2f(v3.x & 0xFFFFu);
        a1 += bf2f(v0.x >> 16) + bf2f(v1.x >> 16) + bf2f(v2.x >> 16) + bf2f(v3.x >> 16);
        a2 += bf2f(v0.y & 0xFFFFu) + bf2f(v1.y & 0xFFFFu) + bf2f(v2.y & 0xFFFFu) + bf2f(v3.y & 0xFFFFu);
        a3 += bf2f(v0.y >> 16) + bf2f(v1.y >> 16) + bf2f(v2.y >> 16) + bf2f(v3.y >> 16);
    }
    for (; e < e1; e++) {
        int d = edat[e];
        u32x2 v = *(const u32x2*)(hc + ((size_t)(d & 0xFFFFF) << 10) + ((d >> 20) << 8));
        a0 += bf2f(v.x & 0xFFFFu); a1 += bf2f(v.x >> 16);
        a2 += bf2f(v.y & 0xFFFFu); a3 += bf2f(v.y >> 16);
    }
    u32x2 p; p.x = pk2(a0, a1); p.y = pk2(a2, a3);
    *(u32x2*)(Aonly + (size_t)n * 256 + (lane << 2)) = p;
}

// bf16 GEMM, B pre-transposed [N,K]; 128x128 tile, BK=32, 4 waves,
// global_load_lds staging. MFMA operands SWAPPED (computes C^T in regs):
// lane holds 4 consecutive N-elements per fragment -> 8B packed stores.
// m = qm + i*16 + fm ; n = qn + j*16 + fkv*4 + r
__global__ __launch_bounds__(256) void gemm_bt(
    const unsigned short* __restrict__ A, int lda,
    const unsigned short* __restrict__ Bt,
    unsigned short* __restrict__ Cb, int ldcb,
    const float* __restrict__ bias,
    int N, int K, int swz, int relu)
{
    __shared__ __align__(16) unsigned short As[128 * 32];
    __shared__ __align__(16) unsigned short Bs[128 * 32];
    const int tid = threadIdx.x;
    int id = blockIdx.x;
    if (swz) { int per = gridDim.x >> 3; id = (id & 7) * per + (id >> 3); }
    const int nb = N >> 7;
    const int bm = id / nb, bn = id - bm * nb;
    const int wave = tid >> 6, lane = tid & 63;
    const int l4 = lane >> 2, c8 = (lane & 3) << 3;
    const unsigned short* Ag = A + (size_t)(bm * 128 + wave * 32 + l4) * lda + c8;
    const unsigned short* Bg = Bt + (size_t)(bn * 128 + wave * 32 + l4) * K + c8;
    unsigned short* lA = As + wave * 1024;
    unsigned short* lB = Bs + wave * 1024;
    const int qm = (wave & 1) << 6, qn = (wave >> 1) << 6;
    const int fm = lane & 15, fkv = lane >> 4;

    f32x4 acc[4][4] = {};

    for (int kb = 0; kb < K; kb += 32) {
        __syncthreads();
        gld16(Ag + kb, lA);
        gld16(Ag + kb + (size_t)16 * lda, lA + 512);
        gld16(Bg + kb, lB);
        gld16(Bg + kb + (size_t)16 * K, lB + 512);
        __syncthreads();
        bf16x8 af[4], bfr[4];
        #pragma unroll
        for (int i = 0; i < 4; i++)
            af[i] = *(const bf16x8*)(&As[(qm + i * 16 + fm) * 32 + fkv * 8]);
        #pragma unroll
        for (int i = 0; i < 4; i++)
            bfr[i] = *(const bf16x8*)(&Bs[(qn + i * 16 + fm) * 32 + fkv * 8]);
        #pragma unroll
        for (int i = 0; i < 4; i++)
            #pragma unroll
            for (int j = 0; j < 4; j++)
                acc[i][j] = __builtin_amdgcn_mfma_f32_16x16x32_bf16(bfr[j], af[i], acc[i][j], 0, 0, 0);
    }

    const int m0 = bm * 128 + qm + fm;
    const int n0 = bn * 128 + qn + (fkv << 2);
    #pragma unroll
    for (int i = 0; i < 4; i++) {
        int row = m0 + i * 16;
        #pragma unroll
        for (int j = 0; j < 4; j++) {
            int col = n0 + j * 16;
            float v0 = acc[i][j][0], v1 = acc[i][j][1],
                  v2 = acc[i][j][2], v3 = acc[i][j][3];
            if (bias) {
                float4 bv = *(const float4*)(bias + col);
                v0 += bv.x; v1 += bv.y; v2 += bv.z; v3 += bv.w;
            }
            if (relu) {
                v0 = fmaxf(v0, 0.f); v1 = fmaxf(v1, 0.f);
                v2 = fmaxf(v2, 0.f); v3 = fmaxf(v3, 0.f);
            }
            u32x2 p; p.x = pk2(v0, v1); p.y = pk2(v2, v3);
            *(u32x2*)(Cb + (size_t)row * ldcb + col) = p;
        }
    }
}

// conv1 as single K-extended GEMM: C[l,:] = relu(sum_k A[l+k,:] @ Wk + b)
// K layout: kk<768 -> h chunks (lda 256, shift kk>>8), kk>=768 -> f chunks
// (lda 128, shift (kk-768)>>7). M=NNODE fixed. bf16 output, swapped MFMA.
__global__ __launch_bounds__(256) void gemm_conv(
    const unsigned short* __restrict__ Ah,
    const unsigned short* __restrict__ Af,
    const unsigned short* __restrict__ Bt,
    unsigned short* __restrict__ Cb, int ldcb,
    const float* __restrict__ bias,
    int N, int K)
{
    __shared__ __align__(16) unsigned short As[128 * 32];
    __shared__ __align__(16) unsigned short Bs[128 * 32];
    const int tid = threadIdx.x;
    int id = blockIdx.x;
    { int per = gridDim.x >> 3; id = (id & 7) * per + (id >> 3); }
    const int nb = N >> 7;
    const int bm = id / nb, bn = id - bm * nb;
    const int wave = tid >> 6, lane = tid & 63;
    const int l4 = lane >> 2, c8 = (lane & 3) << 3;
    const int arow = bm * 128 + wave * 32 + l4;
    const unsigned short* Bg = Bt + (size_t)(bn * 128 + wave * 32 + l4) * K + c8;
    unsigned short* lA = As + wave * 1024;
    unsigned short* lB = Bs + wave * 1024;
    const int qm = (wave & 1) << 6, qn = (wave >> 1) << 6;
    const int fm = lane & 15, fkv = lane >> 4;

    f32x4 acc[4][4] = {};

    for (int kb = 0; kb < K; kb += 32) {
        const unsigned short* base; int ldA, col, shift;
        if (kb < 768) { base = Ah; ldA = 256; shift = kb >> 8; col = kb & 255; }
        else { int r = kb - 768; base = Af; ldA = 128; shift = r >> 7; col = r & 127; }
        const unsigned short* Ag = base + (size_t)(arow + shift) * ldA + col + c8;
        __syncthreads();
        gld16(Ag, lA);
        gld16(Ag + (size_t)16 * ldA, lA + 512);
        gld16(Bg + kb, lB);
        gld16(Bg + kb + (size_t)16 * K, lB + 512);
        __syncthreads();
        bf16x8 af[4], bfr[4];
        #pragma unroll
        for (int i = 0; i < 4; i++)
            af[i] = *(const bf16x8*)(&As[(qm + i * 16 + fm) * 32 + fkv * 8]);
        #pragma unroll
        for (int i = 0; i < 4; i++)
            bfr[i] = *(const bf16x8*)(&Bs[(qn + i * 16 + fm) * 32 + fkv * 8]);
        #pragma unroll
        for (int i = 0; i < 4; i++)
            #pragma unroll
            for (int j = 0; j < 4; j++)
                acc[i][j] = __builtin_amdgcn_mfma_f32_16x16x32_bf16(bfr[j], af[i], acc[i][j], 0, 0, 0);
    }

    const int m0 = bm * 128 + qm + fm;
    const int n0 = bn * 128 + qn + (fkv << 2);
    #pragma unroll
    for (int i = 0; i < 4; i++) {
        int row = m0 + i * 16;
        #pragma unroll
        for (int j = 0; j < 4; j++) {
            int col = n0 + j * 16;
            float4 bv = *(const float4*)(bias + col);
            float v0 = fmaxf(acc[i][j][0] + bv.x, 0.f);
            float v1 = fmaxf(acc[i][j][1] + bv.y, 0.f);
            float v2 = fmaxf(acc[i][j][2] + bv.z, 0.f);
            float v3 = fmaxf(acc[i][j][3] + bv.w, 0.f);
            u32x2 p; p.x = pk2(v0, v1); p.y = pk2(v2, v3);
            *(u32x2*)(Cb + (size_t)row * ldcb + col) = p;
        }
    }
}

// GRU GEMM + fused gate epilogue (swapped MFMA). A = [a|h] from Aonly / hbc
// (both [Nn,256] bf16); Bt [1024,512] gate-interleaved. gate g = j-frag,
// channel = band*16 + fkv*4 + r (4 consecutive per lane -> 8B state I/O).
__global__ __launch_bounds__(256) void gemm_gru(
    const unsigned short* __restrict__ Aonly,
    const unsigned short* __restrict__ hbc,
    const unsigned short* __restrict__ Bt,
    const float* __restrict__ b2p,
    unsigned short* __restrict__ hbn)
{
    __shared__ __align__(16) unsigned short As[128 * 32];
    __shared__ __align__(16) unsigned short Bs[128 * 32];
    const int tid = threadIdx.x;
    int id = blockIdx.x;                        // 2048
    { int per = gridDim.x >> 3; id = (id & 7) * per + (id >> 3); }
    const int bm = id >> 3;
    const int bn = id & 7;
    const int wave = tid >> 6, lane = tid & 63;
    const int l4 = lane >> 2, c8 = (lane & 3) << 3;
    const int arow = bm * 128 + wave * 32 + l4;
    const unsigned short* Bg = Bt + (size_t)(bn * 128 + wave * 32 + l4) * 512 + c8;
    unsigned short* lA = As + wave * 1024;
    unsigned short* lB = Bs + wave * 1024;
    const int qm = (wave & 1) << 6, qn = (wave >> 1) << 6;
    const int fm = lane & 15, fkv = lane >> 4;

    f32x4 acc[4][4] = {};

    for (int kb = 0; kb < 512; kb += 32) {
        const unsigned short* base = (kb < 256) ? Aonly : hbc;
        int col = kb & 255;
        const unsigned short* Ag = base + (size_t)arow * 256 + col + c8;
        __syncthreads();
        gld16(Ag, lA);
        gld16(Ag + 16 * 256, lA + 512);
        gld16(Bg + kb, lB);
        gld16(Bg + kb + 16 * 512, lB + 512);
        __syncthreads();
        bf16x8 af[4], bfr[4];
        #pragma unroll
        for (int i = 0; i < 4; i++)
            af[i] = *(const bf16x8*)(&As[(qm + i * 16 + fm) * 32 + fkv * 8]);
        #pragma unroll
        for (int i = 0; i < 4; i++)
            bfr[i] = *(const bf16x8*)(&Bs[(qn + i * 16 + fm) * 32 + fkv * 8]);
        #pragma unroll
        for (int i = 0; i < 4; i++)
            #pragma unroll
            for (int j = 0; j < 4; j++)
                acc[i][j] = __builtin_amdgcn_mfma_f32_16x16x32_bf16(bfr[j], af[i], acc[i][j], 0, 0, 0);
    }

    // fused GRU gate epilogue (bf16 state, 8B vector I/O)
    const int band = (bn << 1) + (qn >> 6);
    const int chb = (band << 4) + (fkv << 2);
    const float4 brv = *(const float4*)(b2p + (band << 6) + 0  + (fkv << 2));
    const float4 bzv = *(const float4*)(b2p + (band << 6) + 16 + (fkv << 2));
    const float4 bgv = *(const float4*)(b2p + (band << 6) + 32 + (fkv << 2));
    const float4 bhv = *(const float4*)(b2p + (band << 6) + 48 + (fkv << 2));
    const float br_[4] = {brv.x, brv.y, brv.z, brv.w};
    const float bz_[4] = {bzv.x, bzv.y, bzv.z, bzv.w};
    const float bg_[4] = {bgv.x, bgv.y, bgv.z, bgv.w};
    const float bh_[4] = {bhv.x, bhv.y, bhv.z, bhv.w};
    const int m0 = bm * 128 + qm + fm;
    #pragma unroll
    for (int i = 0; i < 4; i++) {
        int row = m0 + i * 16;
        u32x2 hv = *(const u32x2*)(hbc + (size_t)row * 256 + chb);
        float hp[4] = {bf2f(hv.x & 0xFFFFu), bf2f(hv.x >> 16),
                       bf2f(hv.y & 0xFFFFu), bf2f(hv.y >> 16)};
        float hn[4];
        #pragma unroll
        for (int r = 0; r < 4; r++) {
            float rg = sigf(acc[i][0][r] + br_[r]);
            float zz = sigf(acc[i][1][r] + bz_[r]);
            float pre = acc[i][2][r] + bg_[r] + rg * (acc[i][3][r] + bh_[r]);
            pre = fminf(fmaxf(pre, -15.f), 15.f);
            float t = __expf(2.f * pre);
            float gq = (t - 1.f) / (t + 1.f);
            hn[r] = (1.f - zz) * gq + zz * hp[r];
        }
        u32x2 p; p.x = pk2(hn[0], hn[1]); p.y = pk2(hn[2], hn[3]);
        *(u32x2*)(hbn + (size_t)row * 256 + chb) = p;
    }
}

// maxpool over l (window win, stride 2), bf16 input (relu pre-applied)
__global__ __launch_bounds__(256) void pool_k(
    const unsigned short* __restrict__ in, int ldin, int Lb_in, int L_out,
    int win, int C,
    unsigned short* __restrict__ ob, float* __restrict__ of, int ldo)
{
    int idx = blockIdx.x * 256 + threadIdx.x;
    int c = idx % C;
    int row = idx / C;
    int b = row / L_out, lp = row - b * L_out;
    const unsigned short* p = in + (size_t)(b * Lb_in + 2 * lp) * ldin + c;
    float m = bf2f(p[0]);
    for (int d = 1; d < win; d++) m = fmaxf(m, bf2f(p[(size_t)d * ldin]));
    if (ob) ob[(size_t)row * ldo + c] = f2bf(m);
    else    of[(size_t)row * ldo + c] = m;
}

__global__ __launch_bounds__(64) void final_k(
    const float* __restrict__ Y2, const float* __restrict__ Z2,
    const float* __restrict__ wy, const float* __restrict__ by,
    const float* __restrict__ wz, const float* __restrict__ bz,
    float* __restrict__ out)
{
    int b = blockIdx.x, lane = threadIdx.x;
    float val = 0.f;
    if (lane < 63) {
        const float* yr = Y2 + (size_t)(b * 63 + lane) * 256;
        float y = 0.f;
        for (int o = 0; o < 256; o += 4) {
            float4 a = *(const float4*)(yr + o);
            float4 wv = *(const float4*)(wy + o);
            y += a.x * wv.x + a.y * wv.y + a.z * wv.z + a.w * wv.w;
        }
        y += by[0];
        const float* zr = Z2 + (size_t)(b * 63 + lane) * 384;
        float z = 0.f;
        for (int o = 0; o < 384; o += 4) {
            float4 a = *(const float4*)(zr + o);
            float4 wv = *(const float4*)(wz + o);
            z += a.x * wv.x + a.y * wv.y + a.z * wv.z + a.w * wv.w;
        }
        z += bz[0];
        val = y * z;
    }
    for (int off = 32; off > 0; off >>= 1) val += __shfl_down(val, off, 64);
    if (lane == 0) out[b] = sigf(val * (1.f / 63.f));
}

// ---------------- launch ----------------

extern "C" void kernel_launch(void* const* d_in, const int* in_sizes, int n_in,
                              void* d_out, int out_size, void* d_ws, size_t ws_size,
                              hipStream_t stream)
{
    const float* feat = (const float*)d_in[0];
    const int* src = (const int*)d_in[1];
    const int* dst = (const int*)d_in[2];
    const int* et  = (const int*)d_in[3];
    const float* Wm  = (const float*)d_in[4];
    const float* bm  = (const float*)d_in[5];
    const float* Wi  = (const float*)d_in[6];
    const float* Wh  = (const float*)d_in[7];
    const float* bi  = (const float*)d_in[8];
    const float* bh  = (const float*)d_in[9];
    const float* c1w = (const float*)d_in[10];
    const float* c1b = (const float*)d_in[11];
    const float* c2w = (const float*)d_in[12];
    const float* c2b = (const float*)d_in[13];
    const float* cc1w = (const float*)d_in[14];
    const float* cc1b = (const float*)d_in[15];
    const float* cc2w = (const float*)d_in[16];
    const float* cc2b = (const float*)d_in[17];
    const float* wy = (const float*)d_in[18];
    const float* by = (const float*)d_in[19];
    const float* wz = (const float*)d_in[20];
    const float* bz = (const float*)d_in[21];
    float* out = (float*)d_out;

    char* w = (char*)d_ws;
    size_t off = 0;
    auto alloc = [&](size_t bytes) -> char* {
        char* p = w + off; off += (bytes + 255) & ~(size_t)255; return p;
    };
    unsigned short* hb0 = (unsigned short*)alloc((size_t)(NNODE + 8) * 256 * 2);
    unsigned short* hb1 = (unsigned short*)alloc((size_t)(NNODE + 8) * 256 * 2);
    unsigned short* fb  = (unsigned short*)alloc((size_t)(NNODE + 8) * 128 * 2);
    unsigned short* Aonly = (unsigned short*)alloc((size_t)NNODE * 256 * 2);
    char* R = alloc((size_t)NNODE * 1024 * 2);          // Hmsg / conv1-out overlay
    unsigned short* Hmsg = (unsigned short*)R;          // [Nn,1024] bf16
    unsigned short* CbY  = (unsigned short*)R;          // [Nn,256] bf16 (conv1 Y)
    unsigned short* CbZ  = (unsigned short*)(R + (size_t)NNODE * 256 * 2); // [Nn,384]
    unsigned short* P    = (unsigned short*)alloc((size_t)16128 * 384 * 2);
    unsigned short* Cb2  = (unsigned short*)alloc((size_t)16128 * 384 * 2); // conv2 out
    float* Y2 = (float*)alloc((size_t)8064 * 256 * 4);
    float* Z2 = (float*)alloc((size_t)8064 * 384 * 4);
    unsigned short* WT   = (unsigned short*)alloc(1024 * 256 * 2);
    unsigned short* B2T  = (unsigned short*)alloc(1024 * 512 * 2);
    float* b2            = (float*)alloc(1024 * 4);
    unsigned short* BTY  = (unsigned short*)alloc(256 * 768 * 2);
    unsigned short* BT2  = (unsigned short*)alloc(256 * 256 * 2);
    unsigned short* BTZ  = (unsigned short*)alloc(384 * 1152 * 2);
    unsigned short* BTc2 = (unsigned short*)alloc(384 * 384 * 2);
    int* rp     = (int*)alloc((NNODE + 1) * 4);
    int* pos    = (int*)alloc(NNODE * 4);
    int* cnt    = (int*)alloc(NNODE * 4);
    int* edat   = (int*)alloc(NEDGE * 4);

    // setup
    hipLaunchKernelGGL(init_k, dim3(NNODE + 8), dim3(256), 0, stream, feat, hb0, hb1, fb);
    hipLaunchKernelGGL(prep_wmsg_k, dim3(1024), dim3(256), 0, stream, Wm, WT);
    hipLaunchKernelGGL(prep_gru_k, dim3(2048), dim3(256), 0, stream, Wi, Wh, B2T);
    hipLaunchKernelGGL(prep_bias2_k, dim3(4), dim3(256), 0, stream, bi, bh, b2);
    hipLaunchKernelGGL(prep_conv_k, dim3(3328), dim3(256), 0, stream,
                       c1w, c2w, cc1w, cc2w, BTY, BT2, BTZ, BTc2);
    hipMemsetAsync(pos, 0, NNODE * 4, stream);
    hipMemsetAsync(cnt, 0, NNODE * 4, stream);
    hipLaunchKernelGGL(count_k, dim3(NEDGE / 256), dim3(256), 0, stream, dst, cnt);
    hipLaunchKernelGGL(scan_k, dim3(1), dim3(1024), 0, stream, cnt, rp);
    hipLaunchKernelGGL(fill_k, dim3(NEDGE / 256), dim3(256), 0, stream, src, dst, et, rp, pos, edat);

    // 8 GGNN steps; bf16 state double-buffered (hb0 -> hb1 -> hb0 ...)
    // per step: Hmsg = hb@WT + bm  ->  Aonly[dst] = sum Hmsg[src, et]  ->  GRU
    unsigned short* hbuf[2] = {hb0, hb1};
    for (int step = 0; step < 8; step++) {
        unsigned short* cur = hbuf[step & 1];
        unsigned short* nxt = hbuf[(step + 1) & 1];
        hipLaunchKernelGGL(gemm_bt, dim3(2048), dim3(256), 0, stream,
            cur, 256, WT, Hmsg, 1024, bm, 1024, 256, 1, 0);
        hipLaunchKernelGGL(agg2_k, dim3(NNODE / 4), dim3(256), 0, stream, rp, edat, Hmsg, Aonly);
        hipLaunchKernelGGL(gemm_gru, dim3(2048), dim3(256), 0, stream,
            Aonly, cur, B2T, b2, nxt);
    }
    // final state is in hb0 (after 8 flips)

    // readout: Y path (relu fused in GEMMs, bf16 intermediates)
    hipLaunchKernelGGL(gemm_conv, dim3(512), dim3(256), 0, stream,
        hb0, (const unsigned short*)nullptr, BTY, CbY, 256, c1b, 256, 768);
    hipLaunchKernelGGL(pool_k, dim3(16128), dim3(256), 0, stream,
        CbY, 256, 256, 126, 3, 256, P, (float*)nullptr, 256);
    hipLaunchKernelGGL(gemm_bt, dim3(252), dim3(256), 0, stream,
        P, 256, BT2, Cb2, 256, c2b, 256, 256, 0, 1);
    hipLaunchKernelGGL(pool_k, dim3(8064), dim3(256), 0, stream,
        Cb2, 256, 126, 63, 2, 256, (unsigned short*)nullptr, Y2, 256);

    // Z path
    hipLaunchKernelGGL(gemm_conv, dim3(768), dim3(256), 0, stream,
        hb0, fb, BTZ, CbZ, 384, cc1b, 384, 1152);
    hipLaunchKernelGGL(pool_k, dim3(24192), dim3(256), 0, stream,
        CbZ, 384, 256, 126, 3, 384, P, (float*)nullptr, 384);
    hipLaunchKernelGGL(gemm_bt, dim3(378), dim3(256), 0, stream,
        P, 384, BTc2, Cb2, 384, cc2b, 384, 384, 0, 1);
    hipLaunchKernelGGL(pool_k, dim3(12096), dim3(256), 0, stream,
        Cb2, 384, 126, 63, 2, 384, (unsigned short*)nullptr, Z2, 384);

    hipLaunchKernelGGL(final_k, dim3(128), dim3(64), 0, stream, Y2, Z2, wy, by, wz, bz, out);
}

// Round 7
// 1401.083 us; speedup vs baseline: 1.6337x; 1.0551x over previous
//
#include <hip/hip_runtime.h>

#define DEV static __device__ __forceinline__

typedef float f32x4 __attribute__((ext_vector_type(4)));
typedef __bf16 bf16x8 __attribute__((ext_vector_type(8)));
typedef unsigned int u32x4 __attribute__((ext_vector_type(4)));
typedef unsigned int u32x2 __attribute__((ext_vector_type(2)));

#define NNODE 32768
#define NEDGE 393216

DEV unsigned short f2bf(float f) {
    unsigned int u = __builtin_bit_cast(unsigned int, f);
    u += 0x7FFFu + ((u >> 16) & 1u);
    return (unsigned short)(u >> 16);
}
DEV float bf2f(unsigned int b) {
    unsigned int u = b << 16;
    return __builtin_bit_cast(float, u);
}
DEV unsigned int pk2(float a, float b) {
    return (unsigned int)f2bf(a) | ((unsigned int)f2bf(b) << 16);
}
DEV float sigf(float x) { return 1.f / (1.f + __expf(-x)); }

// async global->LDS, 16B per lane; LDS dest = wave-uniform base + lane*16
DEV void gld16(const void* g, void* l) {
    __builtin_amdgcn_global_load_lds(
        (const __attribute__((address_space(1))) void*)(g),
        (__attribute__((address_space(3))) void*)(l),
        16, 0, 0);
}

// ---------------- setup kernels ----------------

__global__ __launch_bounds__(256) void init_k(
    const float* __restrict__ feat,
    unsigned short* __restrict__ hb0, unsigned short* __restrict__ hb1,
    unsigned short* __restrict__ fb)
{
    int idx = blockIdx.x * 256 + threadIdx.x;   // (NNODE+8)*256
    int r = idx >> 8, c = idx & 255;
    float f = 0.f;
    if (r < NNODE && c < 128) f = feat[(size_t)r * 128 + c];
    unsigned short v = f2bf(f);
    hb0[(size_t)r * 256 + c] = v;
    hb1[(size_t)r * 256 + c] = v;
    if (c < 128) fb[(size_t)r * 128 + c] = v;
}

// WT [1024,256]: row j = t*256+o, col d -> Wm[t][d][o]
__global__ __launch_bounds__(256) void prep_wmsg_k(
    const float* __restrict__ Wm, unsigned short* __restrict__ WT)
{
    int idx = blockIdx.x * 256 + threadIdx.x;   // 1024*256
    int j = idx >> 8, d = idx & 255;
    int t = j >> 8, o = j & 255;
    WT[idx] = f2bf(Wm[t * 65536 + d * 256 + o]);
}

// GRU weights gate-interleaved: col' = band*64 + g*16 + ch_low,
// ch = band*16 + ch_low, g in {0:r, 1:z, 2:ig, 3:hg}. K: k<256 -> a, else h.
__global__ __launch_bounds__(256) void prep_gru_k(
    const float* __restrict__ Wi, const float* __restrict__ Wh,
    unsigned short* __restrict__ B2T)
{
    int idx = blockIdx.x * 256 + threadIdx.x;   // 1024*512
    int j = idx >> 9, k = idx & 511;
    int band = j >> 6, g = (j >> 4) & 3, ch = (band << 4) + (j & 15);
    float v = 0.f;
    if (g == 0) v = (k < 256) ? Wi[k * 768 + ch] : Wh[(k - 256) * 768 + ch];
    else if (g == 1) v = (k < 256) ? Wi[k * 768 + 256 + ch] : Wh[(k - 256) * 768 + 256 + ch];
    else if (g == 2) { if (k < 256) v = Wi[k * 768 + 512 + ch]; }
    else { if (k >= 256) v = Wh[(k - 256) * 768 + 512 + ch]; }
    B2T[idx] = f2bf(v);
}

__global__ __launch_bounds__(256) void prep_bias2_k(
    const float* __restrict__ bi, const float* __restrict__ bh,
    float* __restrict__ b2)
{
    int j = blockIdx.x * 256 + threadIdx.x;     // 1024
    int band = j >> 6, g = (j >> 4) & 3, ch = (band << 4) + (j & 15);
    float v;
    if (g == 0) v = bi[ch] + bh[ch];
    else if (g == 1) v = bi[256 + ch] + bh[256 + ch];
    else if (g == 2) v = bi[512 + ch];
    else v = bh[512 + ch];
    b2[j] = v;
}

// pack conv weights: BTY [256][768] (kk=k*256+c), BT2 [256][256],
// BTZ [384][1152] (h chunks then f chunks), BTc2 [384][384]
__global__ __launch_bounds__(256) void prep_conv_k(
    const float* __restrict__ c1w, const float* __restrict__ c2w,
    const float* __restrict__ cc1w, const float* __restrict__ cc2w,
    unsigned short* __restrict__ BTY, unsigned short* __restrict__ BT2,
    unsigned short* __restrict__ BTZ, unsigned short* __restrict__ BTc2)
{
    int idx = blockIdx.x * 256 + threadIdx.x;   // 851968 total
    if (idx < 196608) {                                     // BTY
        int o = idx / 768, kk = idx - o * 768, k = kk >> 8, c = kk & 255;
        BTY[idx] = f2bf(c1w[o * 768 + c * 3 + k]);
    } else if (idx < 262144) {                              // BT2 [o][c]
        int r = idx - 196608, o = r >> 8, c = r & 255;
        BT2[r] = f2bf(c2w[o * 256 + c]);
    } else if (idx < 704512) {                              // BTZ
        int jx = idx - 262144, o = jx / 1152, kk = jx - o * 1152;
        float v;
        if (kk < 768) { int k = kk >> 8, c = kk & 255; v = cc1w[o * 1152 + c * 3 + k]; }
        else { int r = kk - 768, kf = r >> 7, cf = r & 127; v = cc1w[o * 1152 + (256 + cf) * 3 + kf]; }
        BTZ[jx] = f2bf(v);
    } else {                                                // BTc2 [o][c]
        int r = idx - 704512, o = r / 384, c = r - o * 384;
        BTc2[r] = f2bf(cc2w[o * 384 + c]);
    }
}

// ---------------- CSR build ----------------

__global__ __launch_bounds__(256) void count_k(
    const int* __restrict__ dst, int* __restrict__ cnt)
{
    int e = blockIdx.x * 256 + threadIdx.x;
    atomicAdd(&cnt[dst[e]], 1);
}

__global__ __launch_bounds__(1024) void scan_k(
    const int* __restrict__ cnt, int* __restrict__ rp)
{
    __shared__ int buf[1024];
    int tid = threadIdx.x;
    int base = 0;
    for (int chunk = 0; chunk < 32; chunk++) {
        int n = chunk * 1024 + tid;
        int v = cnt[n];
        buf[tid] = v;
        __syncthreads();
        for (int off = 1; off < 1024; off <<= 1) {
            int x = (tid >= off) ? buf[tid - off] : 0;
            __syncthreads();
            buf[tid] += x;
            __syncthreads();
        }
        rp[n] = base + buf[tid] - v;
        base += buf[1023];
        __syncthreads();
    }
    if (tid == 0) rp[NNODE] = base;
}

__global__ __launch_bounds__(256) void fill_k(
    const int* __restrict__ src, const int* __restrict__ dst,
    const int* __restrict__ et, const int* __restrict__ rp,
    int* __restrict__ pos, int* __restrict__ edat)
{
    int e = blockIdx.x * 256 + threadIdx.x;
    int d = dst[e];
    int p = atomicAdd(&pos[d], 1);
    edat[rp[d] + p] = src[e] | (et[e] << 20);
}

// ---------------- per-step kernels ----------------

// one wave per node: gather Hmsg[src, et*256 .. +256] rows, sum fp32 -> Aonly
// unrolled x4 so 4 gathers are in flight
__global__ __launch_bounds__(256) void agg2_k(
    const int* __restrict__ rp, const int* __restrict__ edat,
    const unsigned short* __restrict__ Hmsg, unsigned short* __restrict__ Aonly)
{
    int wave = threadIdx.x >> 6, lane = threadIdx.x & 63;
    int n = (blockIdx.x << 2) + wave;
    int e0 = rp[n], e1 = rp[n + 1];
    float a0 = 0.f, a1 = 0.f, a2 = 0.f, a3 = 0.f;
    const unsigned short* hc = Hmsg + (lane << 2);
    int e = e0;
    for (; e + 4 <= e1; e += 4) {
        int d0 = edat[e], d1 = edat[e + 1], d2 = edat[e + 2], d3 = edat[e + 3];
        u32x2 v0 = *(const u32x2*)(hc + ((size_t)(d0 & 0xFFFFF) << 10) + ((d0 >> 20) << 8));
        u32x2 v1 = *(const u32x2*)(hc + ((size_t)(d1 & 0xFFFFF) << 10) + ((d1 >> 20) << 8));
        u32x2 v2 = *(const u32x2*)(hc + ((size_t)(d2 & 0xFFFFF) << 10) + ((d2 >> 20) << 8));
        u32x2 v3 = *(const u32x2*)(hc + ((size_t)(d3 & 0xFFFFF) << 10) + ((d3 >> 20) << 8));
        a0 += bf2f(v0.x & 0xFFFFu) + bf2f(v1.x & 0xFFFFu) + bf2f(v2.x & 0xFFFFu) + bf2f(v3.x & 0xFFFFu);
        a1 += bf2f(v0.x >> 16) + bf2f(v1.x >> 16) + bf2f(v2.x >> 16) + bf2f(v3.x >> 16);
        a2 += bf2f(v0.y & 0xFFFFu) + bf2f(v1.y & 0xFFFFu) + bf2f(v2.y & 0xFFFFu) + bf2f(v3.y & 0xFFFFu);
        a3 += bf2f(v0.y >> 16) + bf2f(v1.y >> 16) + bf2f(v2.y >> 16) + bf2f(v3.y >> 16);
    }
    for (; e < e1; e++) {
        int d = edat[e];
        u32x2 v = *(const u32x2*)(hc + ((size_t)(d & 0xFFFFF) << 10) + ((d >> 20) << 8));
        a0 += bf2f(v.x & 0xFFFFu); a1 += bf2f(v.x >> 16);
        a2 += bf2f(v.y & 0xFFFFu); a3 += bf2f(v.y >> 16);
    }
    u32x2 p; p.x = pk2(a0, a1); p.y = pk2(a2, a3);
    *(u32x2*)(Aonly + (size_t)n * 256 + (lane << 2)) = p;
}

// ---- BK=64 staging helpers: tile stored as two stacked 32-K halves so
// global_load_lds lane-contiguity holds and ds_read pattern matches BK=32.
// Thread issues 4 gld16; chunk c = wave + p*4; half = c>>3.
#define STAGE_COORDS                                            \
    int srow[4], scb[4], soff[4];                               \
    _Pragma("unroll")                                           \
    for (int p = 0; p < 4; p++) {                               \
        int c = wave + p * 4;                                   \
        int half = c >> 3, cc = c & 7;                          \
        srow[p] = cc * 16 + (lane >> 2);                        \
        scb[p] = ((lane & 3) + half * 4) * 8;                   \
        soff[p] = half * 4096 + cc * 512;                       \
    }

// MFMA over one 64-K LDS tile pair (two 32-K halves), swapped operands
#define MFMA64(AS, BS)                                                        \
    _Pragma("unroll")                                                         \
    for (int h = 0; h < 2; h++) {                                             \
        bf16x8 af[4], bfr[4];                                                 \
        _Pragma("unroll")                                                     \
        for (int i = 0; i < 4; i++)                                           \
            af[i] = *(const bf16x8*)(&AS[h * 4096 + (qm + i * 16 + fm) * 32 + fkv * 8]); \
        _Pragma("unroll")                                                     \
        for (int i = 0; i < 4; i++)                                           \
            bfr[i] = *(const bf16x8*)(&BS[h * 4096 + (qn + i * 16 + fm) * 32 + fkv * 8]); \
        _Pragma("unroll")                                                     \
        for (int i = 0; i < 4; i++)                                           \
            _Pragma("unroll")                                                 \
            for (int j = 0; j < 4; j++)                                       \
                acc[i][j] = __builtin_amdgcn_mfma_f32_16x16x32_bf16(bfr[j], af[i], acc[i][j], 0, 0, 0); \
    }

// bf16 GEMM, B pre-transposed [N,K]; 128x128 tile, BK=64, 4 waves,
// global_load_lds staging, swapped MFMA (lane holds 4 consecutive N elems).
__global__ __launch_bounds__(256) void gemm_bt(
    const unsigned short* __restrict__ A, int lda,
    const unsigned short* __restrict__ Bt,
    unsigned short* __restrict__ Cb, int ldcb,
    const float* __restrict__ bias,
    int N, int K, int swz, int relu)
{
    __shared__ __align__(16) unsigned short As[128 * 64];
    __shared__ __align__(16) unsigned short Bs[128 * 64];
    const int tid = threadIdx.x;
    int id = blockIdx.x;
    if (swz) { int per = gridDim.x >> 3; id = (id & 7) * per + (id >> 3); }
    const int nb = N >> 7;
    const int bm = id / nb, bn = id - bm * nb;
    const int wave = tid >> 6, lane = tid & 63;
    const unsigned short* Ag = A + (size_t)(bm * 128) * lda;
    const unsigned short* Bg = Bt + (size_t)(bn * 128) * K;
    const int qm = (wave & 1) << 6, qn = (wave >> 1) << 6;
    const int fm = lane & 15, fkv = lane >> 4;
    STAGE_COORDS

    f32x4 acc[4][4] = {};

    for (int kb = 0; kb < K; kb += 64) {
        __syncthreads();
        #pragma unroll
        for (int p = 0; p < 4; p++)
            gld16(Ag + (size_t)srow[p] * lda + kb + scb[p], As + soff[p]);
        #pragma unroll
        for (int p = 0; p < 4; p++)
            gld16(Bg + (size_t)srow[p] * K + kb + scb[p], Bs + soff[p]);
        __syncthreads();
        MFMA64(As, Bs)
    }

    const int m0 = bm * 128 + qm + fm;
    const int n0 = bn * 128 + qn + (fkv << 2);
    #pragma unroll
    for (int i = 0; i < 4; i++) {
        int row = m0 + i * 16;
        #pragma unroll
        for (int j = 0; j < 4; j++) {
            int col = n0 + j * 16;
            float v0 = acc[i][j][0], v1 = acc[i][j][1],
                  v2 = acc[i][j][2], v3 = acc[i][j][3];
            if (bias) {
                float4 bv = *(const float4*)(bias + col);
                v0 += bv.x; v1 += bv.y; v2 += bv.z; v3 += bv.w;
            }
            if (relu) {
                v0 = fmaxf(v0, 0.f); v1 = fmaxf(v1, 0.f);
                v2 = fmaxf(v2, 0.f); v3 = fmaxf(v3, 0.f);
            }
            u32x2 p; p.x = pk2(v0, v1); p.y = pk2(v2, v3);
            *(u32x2*)(Cb + (size_t)row * ldcb + col) = p;
        }
    }
}

// conv1 as single K-extended GEMM: C[l,:] = relu(sum_k A[l+k,:] @ Wk + b)
// K layout: kb<768 -> h chunks (lda 256, shift kb>>8), kb>=768 -> f chunks
// (lda 128, shift (kb-768)>>7). BK=64 (divides both 256 and 128 chunks).
__global__ __launch_bounds__(256) void gemm_conv(
    const unsigned short* __restrict__ Ah,
    const unsigned short* __restrict__ Af,
    const unsigned short* __restrict__ Bt,
    unsigned short* __restrict__ Cb, int ldcb,
    const float* __restrict__ bias,
    int N, int K)
{
    __shared__ __align__(16) unsigned short As[128 * 64];
    __shared__ __align__(16) unsigned short Bs[128 * 64];
    const int tid = threadIdx.x;
    int id = blockIdx.x;
    { int per = gridDim.x >> 3; id = (id & 7) * per + (id >> 3); }
    const int nb = N >> 7;
    const int bm = id / nb, bn = id - bm * nb;
    const int wave = tid >> 6, lane = tid & 63;
    const unsigned short* Bg = Bt + (size_t)(bn * 128) * K;
    const int qm = (wave & 1) << 6, qn = (wave >> 1) << 6;
    const int fm = lane & 15, fkv = lane >> 4;
    STAGE_COORDS

    f32x4 acc[4][4] = {};

    for (int kb = 0; kb < K; kb += 64) {
        const unsigned short* base; int ldA, col, shift;
        if (kb < 768) { base = Ah; ldA = 256; shift = kb >> 8; col = kb & 255; }
        else { int r = kb - 768; base = Af; ldA = 128; shift = r >> 7; col = r & 127; }
        const unsigned short* Ag = base + (size_t)(bm * 128 + shift) * ldA + col;
        __syncthreads();
        #pragma unroll
        for (int p = 0; p < 4; p++)
            gld16(Ag + (size_t)srow[p] * ldA + scb[p], As + soff[p]);
        #pragma unroll
        for (int p = 0; p < 4; p++)
            gld16(Bg + (size_t)srow[p] * K + kb + scb[p], Bs + soff[p]);
        __syncthreads();
        MFMA64(As, Bs)
    }

    const int m0 = bm * 128 + qm + fm;
    const int n0 = bn * 128 + qn + (fkv << 2);
    #pragma unroll
    for (int i = 0; i < 4; i++) {
        int row = m0 + i * 16;
        #pragma unroll
        for (int j = 0; j < 4; j++) {
            int col = n0 + j * 16;
            float4 bv = *(const float4*)(bias + col);
            float v0 = fmaxf(acc[i][j][0] + bv.x, 0.f);
            float v1 = fmaxf(acc[i][j][1] + bv.y, 0.f);
            float v2 = fmaxf(acc[i][j][2] + bv.z, 0.f);
            float v3 = fmaxf(acc[i][j][3] + bv.w, 0.f);
            u32x2 p; p.x = pk2(v0, v1); p.y = pk2(v2, v3);
            *(u32x2*)(Cb + (size_t)row * ldcb + col) = p;
        }
    }
}

// GRU GEMM + fused gate epilogue (swapped MFMA, BK=64, fully unrolled K=512).
// A = [a|h] from Aonly / hbc (both [Nn,256] bf16); Bt [1024,512]
// gate-interleaved. gate g = j-frag, channel = band*16 + fkv*4 + r.
__global__ __launch_bounds__(256) void gemm_gru(
    const unsigned short* __restrict__ Aonly,
    const unsigned short* __restrict__ hbc,
    const unsigned short* __restrict__ Bt,
    const float* __restrict__ b2p,
    unsigned short* __restrict__ hbn)
{
    __shared__ __align__(16) unsigned short As[128 * 64];
    __shared__ __align__(16) unsigned short Bs[128 * 64];
    const int tid = threadIdx.x;
    int id = blockIdx.x;                        // 2048
    { int per = gridDim.x >> 3; id = (id & 7) * per + (id >> 3); }
    const int bm = id >> 3;
    const int bn = id & 7;
    const int wave = tid >> 6, lane = tid & 63;
    const unsigned short* Bg = Bt + (size_t)(bn * 128) * 512;
    const int qm = (wave & 1) << 6, qn = (wave >> 1) << 6;
    const int fm = lane & 15, fkv = lane >> 4;
    STAGE_COORDS

    f32x4 acc[4][4] = {};

    #pragma unroll
    for (int kb = 0; kb < 512; kb += 64) {
        const unsigned short* base = (kb < 256) ? Aonly : hbc;
        const unsigned short* Ag = base + (size_t)(bm * 128) * 256 + (kb & 255);
        __syncthreads();
        #pragma unroll
        for (int p = 0; p < 4; p++)
            gld16(Ag + (size_t)srow[p] * 256 + scb[p], As + soff[p]);
        #pragma unroll
        for (int p = 0; p < 4; p++)
            gld16(Bg + (size_t)srow[p] * 512 + kb + scb[p], Bs + soff[p]);
        __syncthreads();
        MFMA64(As, Bs)
    }

    // fused GRU gate epilogue (bf16 state, 8B vector I/O)
    const int band = (bn << 1) + (qn >> 6);
    const int chb = (band << 4) + (fkv << 2);
    const float4 brv = *(const float4*)(b2p + (band << 6) + 0  + (fkv << 2));
    const float4 bzv = *(const float4*)(b2p + (band << 6) + 16 + (fkv << 2));
    const float4 bgv = *(const float4*)(b2p + (band << 6) + 32 + (fkv << 2));
    const float4 bhv = *(const float4*)(b2p + (band << 6) + 48 + (fkv << 2));
    const float br_[4] = {brv.x, brv.y, brv.z, brv.w};
    const float bz_[4] = {bzv.x, bzv.y, bzv.z, bzv.w};
    const float bg_[4] = {bgv.x, bgv.y, bgv.z, bgv.w};
    const float bh_[4] = {bhv.x, bhv.y, bhv.z, bhv.w};
    const int m0 = bm * 128 + qm + fm;
    #pragma unroll
    for (int i = 0; i < 4; i++) {
        int row = m0 + i * 16;
        u32x2 hv = *(const u32x2*)(hbc + (size_t)row * 256 + chb);
        float hp[4] = {bf2f(hv.x & 0xFFFFu), bf2f(hv.x >> 16),
                       bf2f(hv.y & 0xFFFFu), bf2f(hv.y >> 16)};
        float hn[4];
        #pragma unroll
        for (int r = 0; r < 4; r++) {
            float rg = sigf(acc[i][0][r] + br_[r]);
            float zz = sigf(acc[i][1][r] + bz_[r]);
            float pre = acc[i][2][r] + bg_[r] + rg * (acc[i][3][r] + bh_[r]);
            pre = fminf(fmaxf(pre, -15.f), 15.f);
            float t = __expf(2.f * pre);
            float gq = (t - 1.f) / (t + 1.f);
            hn[r] = (1.f - zz) * gq + zz * hp[r];
        }
        u32x2 p; p.x = pk2(hn[0], hn[1]); p.y = pk2(hn[2], hn[3]);
        *(u32x2*)(hbn + (size_t)row * 256 + chb) = p;
    }
}

// maxpool over l (window win, stride 2), bf16 input (relu pre-applied)
__global__ __launch_bounds__(256) void pool_k(
    const unsigned short* __restrict__ in, int ldin, int Lb_in, int L_out,
    int win, int C,
    unsigned short* __restrict__ ob, float* __restrict__ of, int ldo)
{
    int idx = blockIdx.x * 256 + threadIdx.x;
    int c = idx % C;
    int row = idx / C;
    int b = row / L_out, lp = row - b * L_out;
    const unsigned short* p = in + (size_t)(b * Lb_in + 2 * lp) * ldin + c;
    float m = bf2f(p[0]);
    for (int d = 1; d < win; d++) m = fmaxf(m, bf2f(p[(size_t)d * ldin]));
    if (ob) ob[(size_t)row * ldo + c] = f2bf(m);
    else    of[(size_t)row * ldo + c] = m;
}

__global__ __launch_bounds__(64) void final_k(
    const float* __restrict__ Y2, const float* __restrict__ Z2,
    const float* __restrict__ wy, const float* __restrict__ by,
    const float* __restrict__ wz, const float* __restrict__ bz,
    float* __restrict__ out)
{
    int b = blockIdx.x, lane = threadIdx.x;
    float val = 0.f;
    if (lane < 63) {
        const float* yr = Y2 + (size_t)(b * 63 + lane) * 256;
        float y = 0.f;
        for (int o = 0; o < 256; o += 4) {
            float4 a = *(const float4*)(yr + o);
            float4 wv = *(const float4*)(wy + o);
            y += a.x * wv.x + a.y * wv.y + a.z * wv.z + a.w * wv.w;
        }
        y += by[0];
        const float* zr = Z2 + (size_t)(b * 63 + lane) * 384;
        float z = 0.f;
        for (int o = 0; o < 384; o += 4) {
            float4 a = *(const float4*)(zr + o);
            float4 wv = *(const float4*)(wz + o);
            z += a.x * wv.x + a.y * wv.y + a.z * wv.z + a.w * wv.w;
        }
        z += bz[0];
        val = y * z;
    }
    for (int off = 32; off > 0; off >>= 1) val += __shfl_down(val, off, 64);
    if (lane == 0) out[b] = sigf(val * (1.f / 63.f));
}

// ---------------- launch ----------------

extern "C" void kernel_launch(void* const* d_in, const int* in_sizes, int n_in,
                              void* d_out, int out_size, void* d_ws, size_t ws_size,
                              hipStream_t stream)
{
    const float* feat = (const float*)d_in[0];
    const int* src = (const int*)d_in[1];
    const int* dst = (const int*)d_in[2];
    const int* et  = (const int*)d_in[3];
    const float* Wm  = (const float*)d_in[4];
    const float* bm  = (const float*)d_in[5];
    const float* Wi  = (const float*)d_in[6];
    const float* Wh  = (const float*)d_in[7];
    const float* bi  = (const float*)d_in[8];
    const float* bh  = (const float*)d_in[9];
    const float* c1w = (const float*)d_in[10];
    const float* c1b = (const float*)d_in[11];
    const float* c2w = (const float*)d_in[12];
    const float* c2b = (const float*)d_in[13];
    const float* cc1w = (const float*)d_in[14];
    const float* cc1b = (const float*)d_in[15];
    const float* cc2w = (const float*)d_in[16];
    const float* cc2b = (const float*)d_in[17];
    const float* wy = (const float*)d_in[18];
    const float* by = (const float*)d_in[19];
    const float* wz = (const float*)d_in[20];
    const float* bz = (const float*)d_in[21];
    float* out = (float*)d_out;

    char* w = (char*)d_ws;
    size_t off = 0;
    auto alloc = [&](size_t bytes) -> char* {
        char* p = w + off; off += (bytes + 255) & ~(size_t)255; return p;
    };
    unsigned short* hb0 = (unsigned short*)alloc((size_t)(NNODE + 8) * 256 * 2);
    unsigned short* hb1 = (unsigned short*)alloc((size_t)(NNODE + 8) * 256 * 2);
    unsigned short* fb  = (unsigned short*)alloc((size_t)(NNODE + 8) * 128 * 2);
    unsigned short* Aonly = (unsigned short*)alloc((size_t)NNODE * 256 * 2);
    char* R = alloc((size_t)NNODE * 1024 * 2);          // Hmsg / conv1-out overlay
    unsigned short* Hmsg = (unsigned short*)R;          // [Nn,1024] bf16
    unsigned short* CbY  = (unsigned short*)R;          // [Nn,256] bf16 (conv1 Y)
    unsigned short* CbZ  = (unsigned short*)(R + (size_t)NNODE * 256 * 2); // [Nn,384]
    unsigned short* P    = (unsigned short*)alloc((size_t)16128 * 384 * 2);
    unsigned short* Cb2  = (unsigned short*)alloc((size_t)16128 * 384 * 2); // conv2 out
    float* Y2 = (float*)alloc((size_t)8064 * 256 * 4);
    float* Z2 = (float*)alloc((size_t)8064 * 384 * 4);
    unsigned short* WT   = (unsigned short*)alloc(1024 * 256 * 2);
    unsigned short* B2T  = (unsigned short*)alloc(1024 * 512 * 2);
    float* b2            = (float*)alloc(1024 * 4);
    unsigned short* BTY  = (unsigned short*)alloc(256 * 768 * 2);
    unsigned short* BT2  = (unsigned short*)alloc(256 * 256 * 2);
    unsigned short* BTZ  = (unsigned short*)alloc(384 * 1152 * 2);
    unsigned short* BTc2 = (unsigned short*)alloc(384 * 384 * 2);
    int* rp     = (int*)alloc((NNODE + 1) * 4);
    int* pos    = (int*)alloc(NNODE * 4);
    int* cnt    = (int*)alloc(NNODE * 4);
    int* edat   = (int*)alloc(NEDGE * 4);

    // setup
    hipLaunchKernelGGL(init_k, dim3(NNODE + 8), dim3(256), 0, stream, feat, hb0, hb1, fb);
    hipLaunchKernelGGL(prep_wmsg_k, dim3(1024), dim3(256), 0, stream, Wm, WT);
    hipLaunchKernelGGL(prep_gru_k, dim3(2048), dim3(256), 0, stream, Wi, Wh, B2T);
    hipLaunchKernelGGL(prep_bias2_k, dim3(4), dim3(256), 0, stream, bi, bh, b2);
    hipLaunchKernelGGL(prep_conv_k, dim3(3328), dim3(256), 0, stream,
                       c1w, c2w, cc1w, cc2w, BTY, BT2, BTZ, BTc2);
    hipMemsetAsync(pos, 0, NNODE * 4, stream);
    hipMemsetAsync(cnt, 0, NNODE * 4, stream);
    hipLaunchKernelGGL(count_k, dim3(NEDGE / 256), dim3(256), 0, stream, dst, cnt);
    hipLaunchKernelGGL(scan_k, dim3(1), dim3(1024), 0, stream, cnt, rp);
    hipLaunchKernelGGL(fill_k, dim3(NEDGE / 256), dim3(256), 0, stream, src, dst, et, rp, pos, edat);

    // 8 GGNN steps; bf16 state double-buffered (hb0 -> hb1 -> hb0 ...)
    // per step: Hmsg = hb@WT + bm  ->  Aonly[dst] = sum Hmsg[src, et]  ->  GRU
    unsigned short* hbuf[2] = {hb0, hb1};
    for (int step = 0; step < 8; step++) {
        unsigned short* cur = hbuf[step & 1];
        unsigned short* nxt = hbuf[(step + 1) & 1];
        hipLaunchKernelGGL(gemm_bt, dim3(2048), dim3(256), 0, stream,
            cur, 256, WT, Hmsg, 1024, bm, 1024, 256, 1, 0);
        hipLaunchKernelGGL(agg2_k, dim3(NNODE / 4), dim3(256), 0, stream, rp, edat, Hmsg, Aonly);
        hipLaunchKernelGGL(gemm_gru, dim3(2048), dim3(256), 0, stream,
            Aonly, cur, B2T, b2, nxt);
    }
    // final state is in hb0 (after 8 flips)

    // readout: Y path (relu fused in GEMMs, bf16 intermediates)
    hipLaunchKernelGGL(gemm_conv, dim3(512), dim3(256), 0, stream,
        hb0, (const unsigned short*)nullptr, BTY, CbY, 256, c1b, 256, 768);
    hipLaunchKernelGGL(pool_k, dim3(16128), dim3(256), 0, stream,
        CbY, 256, 256, 126, 3, 256, P, (float*)nullptr, 256);
    hipLaunchKernelGGL(gemm_bt, dim3(252), dim3(256), 0, stream,
        P, 256, BT2, Cb2, 256, c2b, 256, 256, 0, 1);
    hipLaunchKernelGGL(pool_k, dim3(8064), dim3(256), 0, stream,
        Cb2, 256, 126, 63, 2, 256, (unsigned short*)nullptr, Y2, 256);

    // Z path
    hipLaunchKernelGGL(gemm_conv, dim3(768), dim3(256), 0, stream,
        hb0, fb, BTZ, CbZ, 384, cc1b, 384, 1152);
    hipLaunchKernelGGL(pool_k, dim3(24192), dim3(256), 0, stream,
        CbZ, 384, 256, 126, 3, 384, P, (float*)nullptr, 384);
    hipLaunchKernelGGL(gemm_bt, dim3(378), dim3(256), 0, stream,
        P, 384, BTc2, Cb2, 384, cc2b, 384, 384, 0, 1);
    hipLaunchKernelGGL(pool_k, dim3(12096), dim3(256), 0, stream,
        Cb2, 384, 126, 63, 2, 384, (unsigned short*)nullptr, Z2, 384);

    hipLaunchKernelGGL(final_k, dim3(128), dim3(64), 0, stream, Y2, Z2, wy, by, wz, bz, out);
}

// Round 8
// 1333.929 us; speedup vs baseline: 1.7159x; 1.0503x over previous
//
#include <hip/hip_runtime.h>

#define DEV static __device__ __forceinline__

typedef float f32x4 __attribute__((ext_vector_type(4)));
typedef __bf16 bf16x8 __attribute__((ext_vector_type(8)));
typedef unsigned int u32x4 __attribute__((ext_vector_type(4)));
typedef unsigned int u32x2 __attribute__((ext_vector_type(2)));

#define NNODE 32768
#define NEDGE 393216

DEV unsigned short f2bf(float f) {
    unsigned int u = __builtin_bit_cast(unsigned int, f);
    u += 0x7FFFu + ((u >> 16) & 1u);
    return (unsigned short)(u >> 16);
}
DEV float bf2f(unsigned int b) {
    unsigned int u = b << 16;
    return __builtin_bit_cast(float, u);
}
DEV unsigned int pk2(float a, float b) {
    return (unsigned int)f2bf(a) | ((unsigned int)f2bf(b) << 16);
}
DEV float sigf(float x) { return 1.f / (1.f + __expf(-x)); }

// async global->LDS, 16B per lane; LDS dest = wave-uniform base + lane*16
DEV void gld16(const void* g, void* l) {
    __builtin_amdgcn_global_load_lds(
        (const __attribute__((address_space(1))) void*)(g),
        (__attribute__((address_space(3))) void*)(l),
        16, 0, 0);
}

// ---------------- setup kernels ----------------

__global__ __launch_bounds__(256) void init_k(
    const float* __restrict__ feat,
    unsigned short* __restrict__ hb0, unsigned short* __restrict__ hb1,
    unsigned short* __restrict__ fb)
{
    int idx = blockIdx.x * 256 + threadIdx.x;   // (NNODE+8)*256
    int r = idx >> 8, c = idx & 255;
    float f = 0.f;
    if (r < NNODE && c < 128) f = feat[(size_t)r * 128 + c];
    unsigned short v = f2bf(f);
    hb0[(size_t)r * 256 + c] = v;
    hb1[(size_t)r * 256 + c] = v;
    if (c < 128) fb[(size_t)r * 128 + c] = v;
}

// WT [1024,256]: row j = t*256+o, col d -> Wm[t][d][o]
__global__ __launch_bounds__(256) void prep_wmsg_k(
    const float* __restrict__ Wm, unsigned short* __restrict__ WT)
{
    int idx = blockIdx.x * 256 + threadIdx.x;   // 1024*256
    int j = idx >> 8, d = idx & 255;
    int t = j >> 8, o = j & 255;
    WT[idx] = f2bf(Wm[t * 65536 + d * 256 + o]);
}

// GRU weights gate-interleaved: col' = band*64 + g*16 + ch_low,
// ch = band*16 + ch_low, g in {0:r, 1:z, 2:ig, 3:hg}. K: k<256 -> a, else h.
__global__ __launch_bounds__(256) void prep_gru_k(
    const float* __restrict__ Wi, const float* __restrict__ Wh,
    unsigned short* __restrict__ B2T)
{
    int idx = blockIdx.x * 256 + threadIdx.x;   // 1024*512
    int j = idx >> 9, k = idx & 511;
    int band = j >> 6, g = (j >> 4) & 3, ch = (band << 4) + (j & 15);
    float v = 0.f;
    if (g == 0) v = (k < 256) ? Wi[k * 768 + ch] : Wh[(k - 256) * 768 + ch];
    else if (g == 1) v = (k < 256) ? Wi[k * 768 + 256 + ch] : Wh[(k - 256) * 768 + 256 + ch];
    else if (g == 2) { if (k < 256) v = Wi[k * 768 + 512 + ch]; }
    else { if (k >= 256) v = Wh[(k - 256) * 768 + 512 + ch]; }
    B2T[idx] = f2bf(v);
}

__global__ __launch_bounds__(256) void prep_bias2_k(
    const float* __restrict__ bi, const float* __restrict__ bh,
    float* __restrict__ b2)
{
    int j = blockIdx.x * 256 + threadIdx.x;     // 1024
    int band = j >> 6, g = (j >> 4) & 3, ch = (band << 4) + (j & 15);
    float v;
    if (g == 0) v = bi[ch] + bh[ch];
    else if (g == 1) v = bi[256 + ch] + bh[256 + ch];
    else if (g == 2) v = bi[512 + ch];
    else v = bh[512 + ch];
    b2[j] = v;
}

// pack conv weights: BTY [256][768] (kk=k*256+c), BT2 [256][256],
// BTZ [384][1152] (h chunks then f chunks), BTc2 [384][384]
__global__ __launch_bounds__(256) void prep_conv_k(
    const float* __restrict__ c1w, const float* __restrict__ c2w,
    const float* __restrict__ cc1w, const float* __restrict__ cc2w,
    unsigned short* __restrict__ BTY, unsigned short* __restrict__ BT2,
    unsigned short* __restrict__ BTZ, unsigned short* __restrict__ BTc2)
{
    int idx = blockIdx.x * 256 + threadIdx.x;   // 851968 total
    if (idx < 196608) {                                     // BTY
        int o = idx / 768, kk = idx - o * 768, k = kk >> 8, c = kk & 255;
        BTY[idx] = f2bf(c1w[o * 768 + c * 3 + k]);
    } else if (idx < 262144) {                              // BT2 [o][c]
        int r = idx - 196608, o = r >> 8, c = r & 255;
        BT2[r] = f2bf(c2w[o * 256 + c]);
    } else if (idx < 704512) {                              // BTZ
        int jx = idx - 262144, o = jx / 1152, kk = jx - o * 1152;
        float v;
        if (kk < 768) { int k = kk >> 8, c = kk & 255; v = cc1w[o * 1152 + c * 3 + k]; }
        else { int r = kk - 768, kf = r >> 7, cf = r & 127; v = cc1w[o * 1152 + (256 + cf) * 3 + kf]; }
        BTZ[jx] = f2bf(v);
    } else {                                                // BTc2 [o][c]
        int r = idx - 704512, o = r / 384, c = r - o * 384;
        BTc2[r] = f2bf(cc2w[o * 384 + c]);
    }
}

// ---------------- CSR build ----------------

__global__ __launch_bounds__(256) void count_k(
    const int* __restrict__ dst, int* __restrict__ cnt)
{
    int e = blockIdx.x * 256 + threadIdx.x;
    atomicAdd(&cnt[dst[e]], 1);
}

// hierarchical scan: 32 blocks x 1024 local scan -> 1-wave block-sum scan
// -> 32 blocks offset add
__global__ __launch_bounds__(1024) void scan1_k(
    const int* __restrict__ cnt, int* __restrict__ rp, int* __restrict__ bsum)
{
    __shared__ int buf[1024];
    int b = blockIdx.x, tid = threadIdx.x;
    int n = (b << 10) + tid;
    int v = cnt[n];
    buf[tid] = v;
    __syncthreads();
    for (int off = 1; off < 1024; off <<= 1) {
        int x = (tid >= off) ? buf[tid - off] : 0;
        __syncthreads();
        buf[tid] += x;
        __syncthreads();
    }
    rp[n] = buf[tid] - v;                   // local exclusive
    if (tid == 1023) bsum[b] = buf[1023];   // block total
}

__global__ __launch_bounds__(64) void scan2_k(
    const int* __restrict__ bsum, int* __restrict__ boff, int* __restrict__ rp)
{
    int lane = threadIdx.x;
    int v = (lane < 32) ? bsum[lane] : 0;
    int s = v;
    #pragma unroll
    for (int off = 1; off < 32; off <<= 1) {
        int x = __shfl_up(s, off, 64);
        if (lane >= off) s += x;
    }
    if (lane < 32) boff[lane] = s - v;      // exclusive block offset
    if (lane == 31) rp[NNODE] = s;          // grand total
}

__global__ __launch_bounds__(1024) void scan3_k(
    int* __restrict__ rp, const int* __restrict__ boff)
{
    int b = blockIdx.x, tid = threadIdx.x;
    rp[(b << 10) + tid] += boff[b];
}

__global__ __launch_bounds__(256) void fill_k(
    const int* __restrict__ src, const int* __restrict__ dst,
    const int* __restrict__ et, const int* __restrict__ rp,
    int* __restrict__ pos, int* __restrict__ edat)
{
    int e = blockIdx.x * 256 + threadIdx.x;
    int d = dst[e];
    int p = atomicAdd(&pos[d], 1);
    edat[rp[d] + p] = src[e] | (et[e] << 20);
}

// ---------------- per-step kernels ----------------

// one wave per node: gather Hmsg[src, et*256 .. +256] rows, sum fp32 -> Aonly
// unrolled x4 so 4 gathers are in flight
__global__ __launch_bounds__(256) void agg2_k(
    const int* __restrict__ rp, const int* __restrict__ edat,
    const unsigned short* __restrict__ Hmsg, unsigned short* __restrict__ Aonly)
{
    int wave = threadIdx.x >> 6, lane = threadIdx.x & 63;
    int n = (blockIdx.x << 2) + wave;
    int e0 = rp[n], e1 = rp[n + 1];
    float a0 = 0.f, a1 = 0.f, a2 = 0.f, a3 = 0.f;
    const unsigned short* hc = Hmsg + (lane << 2);
    int e = e0;
    for (; e + 4 <= e1; e += 4) {
        int d0 = edat[e], d1 = edat[e + 1], d2 = edat[e + 2], d3 = edat[e + 3];
        u32x2 v0 = *(const u32x2*)(hc + ((size_t)(d0 & 0xFFFFF) << 10) + ((d0 >> 20) << 8));
        u32x2 v1 = *(const u32x2*)(hc + ((size_t)(d1 & 0xFFFFF) << 10) + ((d1 >> 20) << 8));
        u32x2 v2 = *(const u32x2*)(hc + ((size_t)(d2 & 0xFFFFF) << 10) + ((d2 >> 20) << 8));
        u32x2 v3 = *(const u32x2*)(hc + ((size_t)(d3 & 0xFFFFF) << 10) + ((d3 >> 20) << 8));
        a0 += bf2f(v0.x & 0xFFFFu) + bf2f(v1.x & 0xFFFFu) + bf2f(v2.x & 0xFFFFu) + bf2f(v3.x & 0xFFFFu);
        a1 += bf2f(v0.x >> 16) + bf2f(v1.x >> 16) + bf2f(v2.x >> 16) + bf2f(v3.x >> 16);
        a2 += bf2f(v0.y & 0xFFFFu) + bf2f(v1.y & 0xFFFFu) + bf2f(v2.y & 0xFFFFu) + bf2f(v3.y & 0xFFFFu);
        a3 += bf2f(v0.y >> 16) + bf2f(v1.y >> 16) + bf2f(v2.y >> 16) + bf2f(v3.y >> 16);
    }
    for (; e < e1; e++) {
        int d = edat[e];
        u32x2 v = *(const u32x2*)(hc + ((size_t)(d & 0xFFFFF) << 10) + ((d >> 20) << 8));
        a0 += bf2f(v.x & 0xFFFFu); a1 += bf2f(v.x >> 16);
        a2 += bf2f(v.y & 0xFFFFu); a3 += bf2f(v.y >> 16);
    }
    u32x2 p; p.x = pk2(a0, a1); p.y = pk2(a2, a3);
    *(u32x2*)(Aonly + (size_t)n * 256 + (lane << 2)) = p;
}

// ---- BK=64 staging helpers: tile stored as two stacked 32-K halves so
// global_load_lds lane-contiguity holds and ds_read pattern matches BK=32.
// Thread issues 4 gld16; chunk c = wave + p*4; half = c>>3.
#define STAGE_COORDS                                            \
    int srow[4], scb[4], soff[4];                               \
    _Pragma("unroll")                                           \
    for (int p = 0; p < 4; p++) {                               \
        int c = wave + p * 4;                                   \
        int half = c >> 3, cc = c & 7;                          \
        srow[p] = cc * 16 + (lane >> 2);                        \
        scb[p] = ((lane & 3) + half * 4) * 8;                   \
        soff[p] = half * 4096 + cc * 512;                       \
    }

// MFMA over one 64-K LDS tile pair (two 32-K halves), swapped operands
#define MFMA64(AS, BS)                                                        \
    _Pragma("unroll")                                                         \
    for (int h = 0; h < 2; h++) {                                             \
        bf16x8 af[4], bfr[4];                                                 \
        _Pragma("unroll")                                                     \
        for (int i = 0; i < 4; i++)                                           \
            af[i] = *(const bf16x8*)(&AS[h * 4096 + (qm + i * 16 + fm) * 32 + fkv * 8]); \
        _Pragma("unroll")                                                     \
        for (int i = 0; i < 4; i++)                                           \
            bfr[i] = *(const bf16x8*)(&BS[h * 4096 + (qn + i * 16 + fm) * 32 + fkv * 8]); \
        _Pragma("unroll")                                                     \
        for (int i = 0; i < 4; i++)                                           \
            _Pragma("unroll")                                                 \
            for (int j = 0; j < 4; j++)                                       \
                acc[i][j] = __builtin_amdgcn_mfma_f32_16x16x32_bf16(bfr[j], af[i], acc[i][j], 0, 0, 0); \
    }

// bf16 GEMM, B pre-transposed [N,K]; 128x128 tile, BK=64, 4 waves,
// global_load_lds staging, swapped MFMA (lane holds 4 consecutive N elems).
__global__ __launch_bounds__(256) void gemm_bt(
    const unsigned short* __restrict__ A, int lda,
    const unsigned short* __restrict__ Bt,
    unsigned short* __restrict__ Cb, int ldcb,
    const float* __restrict__ bias,
    int N, int K, int swz, int relu)
{
    __shared__ __align__(16) unsigned short As[128 * 64];
    __shared__ __align__(16) unsigned short Bs[128 * 64];
    const int tid = threadIdx.x;
    int id = blockIdx.x;
    if (swz) { int per = gridDim.x >> 3; id = (id & 7) * per + (id >> 3); }
    const int nb = N >> 7;
    const int bm = id / nb, bn = id - bm * nb;
    const int wave = tid >> 6, lane = tid & 63;
    const unsigned short* Ag = A + (size_t)(bm * 128) * lda;
    const unsigned short* Bg = Bt + (size_t)(bn * 128) * K;
    const int qm = (wave & 1) << 6, qn = (wave >> 1) << 6;
    const int fm = lane & 15, fkv = lane >> 4;
    STAGE_COORDS

    f32x4 acc[4][4] = {};

    for (int kb = 0; kb < K; kb += 64) {
        __syncthreads();
        #pragma unroll
        for (int p = 0; p < 4; p++)
            gld16(Ag + (size_t)srow[p] * lda + kb + scb[p], As + soff[p]);
        #pragma unroll
        for (int p = 0; p < 4; p++)
            gld16(Bg + (size_t)srow[p] * K + kb + scb[p], Bs + soff[p]);
        __syncthreads();
        MFMA64(As, Bs)
    }

    const int m0 = bm * 128 + qm + fm;
    const int n0 = bn * 128 + qn + (fkv << 2);
    #pragma unroll
    for (int i = 0; i < 4; i++) {
        int row = m0 + i * 16;
        #pragma unroll
        for (int j = 0; j < 4; j++) {
            int col = n0 + j * 16;
            float v0 = acc[i][j][0], v1 = acc[i][j][1],
                  v2 = acc[i][j][2], v3 = acc[i][j][3];
            if (bias) {
                float4 bv = *(const float4*)(bias + col);
                v0 += bv.x; v1 += bv.y; v2 += bv.z; v3 += bv.w;
            }
            if (relu) {
                v0 = fmaxf(v0, 0.f); v1 = fmaxf(v1, 0.f);
                v2 = fmaxf(v2, 0.f); v3 = fmaxf(v3, 0.f);
            }
            u32x2 p; p.x = pk2(v0, v1); p.y = pk2(v2, v3);
            *(u32x2*)(Cb + (size_t)row * ldcb + col) = p;
        }
    }
}

// conv1 as single K-extended GEMM: C[l,:] = relu(sum_k A[l+k,:] @ Wk + b)
// K layout: kb<768 -> h chunks (lda 256, shift kb>>8), kb>=768 -> f chunks
// (lda 128, shift (kb-768)>>7). BK=64 (divides both 256 and 128 chunks).
__global__ __launch_bounds__(256) void gemm_conv(
    const unsigned short* __restrict__ Ah,
    const unsigned short* __restrict__ Af,
    const unsigned short* __restrict__ Bt,
    unsigned short* __restrict__ Cb, int ldcb,
    const float* __restrict__ bias,
    int N, int K)
{
    __shared__ __align__(16) unsigned short As[128 * 64];
    __shared__ __align__(16) unsigned short Bs[128 * 64];
    const int tid = threadIdx.x;
    int id = blockIdx.x;
    { int per = gridDim.x >> 3; id = (id & 7) * per + (id >> 3); }
    const int nb = N >> 7;
    const int bm = id / nb, bn = id - bm * nb;
    const int wave = tid >> 6, lane = tid & 63;
    const unsigned short* Bg = Bt + (size_t)(bn * 128) * K;
    const int qm = (wave & 1) << 6, qn = (wave >> 1) << 6;
    const int fm = lane & 15, fkv = lane >> 4;
    STAGE_COORDS

    f32x4 acc[4][4] = {};

    for (int kb = 0; kb < K; kb += 64) {
        const unsigned short* base; int ldA, col, shift;
        if (kb < 768) { base = Ah; ldA = 256; shift = kb >> 8; col = kb & 255; }
        else { int r = kb - 768; base = Af; ldA = 128; shift = r >> 7; col = r & 127; }
        const unsigned short* Ag = base + (size_t)(bm * 128 + shift) * ldA + col;
        __syncthreads();
        #pragma unroll
        for (int p = 0; p < 4; p++)
            gld16(Ag + (size_t)srow[p] * ldA + scb[p], As + soff[p]);
        #pragma unroll
        for (int p = 0; p < 4; p++)
            gld16(Bg + (size_t)srow[p] * K + kb + scb[p], Bs + soff[p]);
        __syncthreads();
        MFMA64(As, Bs)
    }

    const int m0 = bm * 128 + qm + fm;
    const int n0 = bn * 128 + qn + (fkv << 2);
    #pragma unroll
    for (int i = 0; i < 4; i++) {
        int row = m0 + i * 16;
        #pragma unroll
        for (int j = 0; j < 4; j++) {
            int col = n0 + j * 16;
            float4 bv = *(const float4*)(bias + col);
            float v0 = fmaxf(acc[i][j][0] + bv.x, 0.f);
            float v1 = fmaxf(acc[i][j][1] + bv.y, 0.f);
            float v2 = fmaxf(acc[i][j][2] + bv.z, 0.f);
            float v3 = fmaxf(acc[i][j][3] + bv.w, 0.f);
            u32x2 p; p.x = pk2(v0, v1); p.y = pk2(v2, v3);
            *(u32x2*)(Cb + (size_t)row * ldcb + col) = p;
        }
    }
}

// GRU GEMM + fused gate epilogue (swapped MFMA, BK=64, fully unrolled K=512).
// A = [a|h] from Aonly / hbc (both [Nn,256] bf16); Bt [1024,512]
// gate-interleaved. gate g = j-frag, channel = band*16 + fkv*4 + r.
__global__ __launch_bounds__(256) void gemm_gru(
    const unsigned short* __restrict__ Aonly,
    const unsigned short* __restrict__ hbc,
    const unsigned short* __restrict__ Bt,
    const float* __restrict__ b2p,
    unsigned short* __restrict__ hbn)
{
    __shared__ __align__(16) unsigned short As[128 * 64];
    __shared__ __align__(16) unsigned short Bs[128 * 64];
    const int tid = threadIdx.x;
    int id = blockIdx.x;                        // 2048
    { int per = gridDim.x >> 3; id = (id & 7) * per + (id >> 3); }
    const int bm = id >> 3;
    const int bn = id & 7;
    const int wave = tid >> 6, lane = tid & 63;
    const unsigned short* Bg = Bt + (size_t)(bn * 128) * 512;
    const int qm = (wave & 1) << 6, qn = (wave >> 1) << 6;
    const int fm = lane & 15, fkv = lane >> 4;
    STAGE_COORDS

    f32x4 acc[4][4] = {};

    #pragma unroll
    for (int kb = 0; kb < 512; kb += 64) {
        const unsigned short* base = (kb < 256) ? Aonly : hbc;
        const unsigned short* Ag = base + (size_t)(bm * 128) * 256 + (kb & 255);
        __syncthreads();
        #pragma unroll
        for (int p = 0; p < 4; p++)
            gld16(Ag + (size_t)srow[p] * 256 + scb[p], As + soff[p]);
        #pragma unroll
        for (int p = 0; p < 4; p++)
            gld16(Bg + (size_t)srow[p] * 512 + kb + scb[p], Bs + soff[p]);
        __syncthreads();
        MFMA64(As, Bs)
    }

    // fused GRU gate epilogue (bf16 state, 8B vector I/O)
    const int band = (bn << 1) + (qn >> 6);
    const int chb = (band << 4) + (fkv << 2);
    const float4 brv = *(const float4*)(b2p + (band << 6) + 0  + (fkv << 2));
    const float4 bzv = *(const float4*)(b2p + (band << 6) + 16 + (fkv << 2));
    const float4 bgv = *(const float4*)(b2p + (band << 6) + 32 + (fkv << 2));
    const float4 bhv = *(const float4*)(b2p + (band << 6) + 48 + (fkv << 2));
    const float br_[4] = {brv.x, brv.y, brv.z, brv.w};
    const float bz_[4] = {bzv.x, bzv.y, bzv.z, bzv.w};
    const float bg_[4] = {bgv.x, bgv.y, bgv.z, bgv.w};
    const float bh_[4] = {bhv.x, bhv.y, bhv.z, bhv.w};
    const int m0 = bm * 128 + qm + fm;
    #pragma unroll
    for (int i = 0; i < 4; i++) {
        int row = m0 + i * 16;
        u32x2 hv = *(const u32x2*)(hbc + (size_t)row * 256 + chb);
        float hp[4] = {bf2f(hv.x & 0xFFFFu), bf2f(hv.x >> 16),
                       bf2f(hv.y & 0xFFFFu), bf2f(hv.y >> 16)};
        float hn[4];
        #pragma unroll
        for (int r = 0; r < 4; r++) {
            float rg = sigf(acc[i][0][r] + br_[r]);
            float zz = sigf(acc[i][1][r] + bz_[r]);
            float pre = acc[i][2][r] + bg_[r] + rg * (acc[i][3][r] + bh_[r]);
            pre = fminf(fmaxf(pre, -15.f), 15.f);
            float t = __expf(2.f * pre);
            float gq = (t - 1.f) / (t + 1.f);
            hn[r] = (1.f - zz) * gq + zz * hp[r];
        }
        u32x2 p; p.x = pk2(hn[0], hn[1]); p.y = pk2(hn[2], hn[3]);
        *(u32x2*)(hbn + (size_t)row * 256 + chb) = p;
    }
}

// maxpool over l (window win, stride 2), bf16 input (relu pre-applied)
__global__ __launch_bounds__(256) void pool_k(
    const unsigned short* __restrict__ in, int ldin, int Lb_in, int L_out,
    int win, int C,
    unsigned short* __restrict__ ob, float* __restrict__ of, int ldo)
{
    int idx = blockIdx.x * 256 + threadIdx.x;
    int c = idx % C;
    int row = idx / C;
    int b = row / L_out, lp = row - b * L_out;
    const unsigned short* p = in + (size_t)(b * Lb_in + 2 * lp) * ldin + c;
    float m = bf2f(p[0]);
    for (int d = 1; d < win; d++) m = fmaxf(m, bf2f(p[(size_t)d * ldin]));
    if (ob) ob[(size_t)row * ldo + c] = f2bf(m);
    else    of[(size_t)row * ldo + c] = m;
}

__global__ __launch_bounds__(64) void final_k(
    const float* __restrict__ Y2, const float* __restrict__ Z2,
    const float* __restrict__ wy, const float* __restrict__ by,
    const float* __restrict__ wz, const float* __restrict__ bz,
    float* __restrict__ out)
{
    int b = blockIdx.x, lane = threadIdx.x;
    float val = 0.f;
    if (lane < 63) {
        const float* yr = Y2 + (size_t)(b * 63 + lane) * 256;
        float y = 0.f;
        for (int o = 0; o < 256; o += 4) {
            float4 a = *(const float4*)(yr + o);
            float4 wv = *(const float4*)(wy + o);
            y += a.x * wv.x + a.y * wv.y + a.z * wv.z + a.w * wv.w;
        }
        y += by[0];
        const float* zr = Z2 + (size_t)(b * 63 + lane) * 384;
        float z = 0.f;
        for (int o = 0; o < 384; o += 4) {
            float4 a = *(const float4*)(zr + o);
            float4 wv = *(const float4*)(wz + o);
            z += a.x * wv.x + a.y * wv.y + a.z * wv.z + a.w * wv.w;
        }
        z += bz[0];
        val = y * z;
    }
    for (int off = 32; off > 0; off >>= 1) val += __shfl_down(val, off, 64);
    if (lane == 0) out[b] = sigf(val * (1.f / 63.f));
}

// ---------------- launch ----------------

extern "C" void kernel_launch(void* const* d_in, const int* in_sizes, int n_in,
                              void* d_out, int out_size, void* d_ws, size_t ws_size,
                              hipStream_t stream)
{
    const float* feat = (const float*)d_in[0];
    const int* src = (const int*)d_in[1];
    const int* dst = (const int*)d_in[2];
    const int* et  = (const int*)d_in[3];
    const float* Wm  = (const float*)d_in[4];
    const float* bm  = (const float*)d_in[5];
    const float* Wi  = (const float*)d_in[6];
    const float* Wh  = (const float*)d_in[7];
    const float* bi  = (const float*)d_in[8];
    const float* bh  = (const float*)d_in[9];
    const float* c1w = (const float*)d_in[10];
    const float* c1b = (const float*)d_in[11];
    const float* c2w = (const float*)d_in[12];
    const float* c2b = (const float*)d_in[13];
    const float* cc1w = (const float*)d_in[14];
    const float* cc1b = (const float*)d_in[15];
    const float* cc2w = (const float*)d_in[16];
    const float* cc2b = (const float*)d_in[17];
    const float* wy = (const float*)d_in[18];
    const float* by = (const float*)d_in[19];
    const float* wz = (const float*)d_in[20];
    const float* bz = (const float*)d_in[21];
    float* out = (float*)d_out;

    char* w = (char*)d_ws;
    size_t off = 0;
    auto alloc = [&](size_t bytes) -> char* {
        char* p = w + off; off += (bytes + 255) & ~(size_t)255; return p;
    };
    unsigned short* hb0 = (unsigned short*)alloc((size_t)(NNODE + 8) * 256 * 2);
    unsigned short* hb1 = (unsigned short*)alloc((size_t)(NNODE + 8) * 256 * 2);
    unsigned short* fb  = (unsigned short*)alloc((size_t)(NNODE + 8) * 128 * 2);
    unsigned short* Aonly = (unsigned short*)alloc((size_t)NNODE * 256 * 2);
    char* R = alloc((size_t)NNODE * 1024 * 2);          // Hmsg / conv1-out overlay
    unsigned short* Hmsg = (unsigned short*)R;          // [Nn,1024] bf16
    unsigned short* CbY  = (unsigned short*)R;          // [Nn,256] bf16 (conv1 Y)
    unsigned short* CbZ  = (unsigned short*)(R + (size_t)NNODE * 256 * 2); // [Nn,384]
    unsigned short* P    = (unsigned short*)alloc((size_t)16128 * 384 * 2);
    unsigned short* Cb2  = (unsigned short*)alloc((size_t)16128 * 384 * 2); // conv2 out
    float* Y2 = (float*)alloc((size_t)8064 * 256 * 4);
    float* Z2 = (float*)alloc((size_t)8064 * 384 * 4);
    unsigned short* WT   = (unsigned short*)alloc(1024 * 256 * 2);
    unsigned short* B2T  = (unsigned short*)alloc(1024 * 512 * 2);
    float* b2            = (float*)alloc(1024 * 4);
    unsigned short* BTY  = (unsigned short*)alloc(256 * 768 * 2);
    unsigned short* BT2  = (unsigned short*)alloc(256 * 256 * 2);
    unsigned short* BTZ  = (unsigned short*)alloc(384 * 1152 * 2);
    unsigned short* BTc2 = (unsigned short*)alloc(384 * 384 * 2);
    int* rp     = (int*)alloc((NNODE + 1) * 4);
    int* pos    = (int*)alloc(NNODE * 4);
    int* cnt    = (int*)alloc(NNODE * 4);
    int* bsum   = (int*)alloc(32 * 4);
    int* boff   = (int*)alloc(32 * 4);
    int* edat   = (int*)alloc(NEDGE * 4);

    // setup
    hipLaunchKernelGGL(init_k, dim3(NNODE + 8), dim3(256), 0, stream, feat, hb0, hb1, fb);
    hipLaunchKernelGGL(prep_wmsg_k, dim3(1024), dim3(256), 0, stream, Wm, WT);
    hipLaunchKernelGGL(prep_gru_k, dim3(2048), dim3(256), 0, stream, Wi, Wh, B2T);
    hipLaunchKernelGGL(prep_bias2_k, dim3(4), dim3(256), 0, stream, bi, bh, b2);
    hipLaunchKernelGGL(prep_conv_k, dim3(3328), dim3(256), 0, stream,
                       c1w, c2w, cc1w, cc2w, BTY, BT2, BTZ, BTc2);
    hipMemsetAsync(pos, 0, NNODE * 4, stream);
    hipMemsetAsync(cnt, 0, NNODE * 4, stream);
    hipLaunchKernelGGL(count_k, dim3(NEDGE / 256), dim3(256), 0, stream, dst, cnt);
    hipLaunchKernelGGL(scan1_k, dim3(32), dim3(1024), 0, stream, cnt, rp, bsum);
    hipLaunchKernelGGL(scan2_k, dim3(1), dim3(64), 0, stream, bsum, boff, rp);
    hipLaunchKernelGGL(scan3_k, dim3(32), dim3(1024), 0, stream, rp, boff);
    hipLaunchKernelGGL(fill_k, dim3(NEDGE / 256), dim3(256), 0, stream, src, dst, et, rp, pos, edat);

    // 8 GGNN steps; bf16 state double-buffered (hb0 -> hb1 -> hb0 ...)
    // per step: Hmsg = hb@WT + bm  ->  Aonly[dst] = sum Hmsg[src, et]  ->  GRU
    unsigned short* hbuf[2] = {hb0, hb1};
    for (int step = 0; step < 8; step++) {
        unsigned short* cur = hbuf[step & 1];
        unsigned short* nxt = hbuf[(step + 1) & 1];
        hipLaunchKernelGGL(gemm_bt, dim3(2048), dim3(256), 0, stream,
            cur, 256, WT, Hmsg, 1024, bm, 1024, 256, 1, 0);
        hipLaunchKernelGGL(agg2_k, dim3(NNODE / 4), dim3(256), 0, stream, rp, edat, Hmsg, Aonly);
        hipLaunchKernelGGL(gemm_gru, dim3(2048), dim3(256), 0, stream,
            Aonly, cur, B2T, b2, nxt);
    }
    // final state is in hb0 (after 8 flips)

    // readout: Y path (relu fused in GEMMs, bf16 intermediates)
    hipLaunchKernelGGL(gemm_conv, dim3(512), dim3(256), 0, stream,
        hb0, (const unsigned short*)nullptr, BTY, CbY, 256, c1b, 256, 768);
    hipLaunchKernelGGL(pool_k, dim3(16128), dim3(256), 0, stream,
        CbY, 256, 256, 126, 3, 256, P, (float*)nullptr, 256);
    hipLaunchKernelGGL(gemm_bt, dim3(252), dim3(256), 0, stream,
        P, 256, BT2, Cb2, 256, c2b, 256, 256, 0, 1);
    hipLaunchKernelGGL(pool_k, dim3(8064), dim3(256), 0, stream,
        Cb2, 256, 126, 63, 2, 256, (unsigned short*)nullptr, Y2, 256);

    // Z path
    hipLaunchKernelGGL(gemm_conv, dim3(768), dim3(256), 0, stream,
        hb0, fb, BTZ, CbZ, 384, cc1b, 384, 1152);
    hipLaunchKernelGGL(pool_k, dim3(24192), dim3(256), 0, stream,
        CbZ, 384, 256, 126, 3, 384, P, (float*)nullptr, 384);
    hipLaunchKernelGGL(gemm_bt, dim3(378), dim3(256), 0, stream,
        P, 384, BTc2, Cb2, 384, cc2b, 384, 384, 0, 1);
    hipLaunchKernelGGL(pool_k, dim3(12096), dim3(256), 0, stream,
        Cb2, 384, 126, 63, 2, 384, (unsigned short*)nullptr, Z2, 384);

    hipLaunchKernelGGL(final_k, dim3(128), dim3(64), 0, stream, Y2, Z2, wy, by, wz, bz, out);
}